// Round 1
// baseline (2370.513 us; speedup 1.0000x reference)
//
#include <hip/hip_runtime.h>

// Problem constants
constexpr int cB = 4, cS = 2048, cD = 1024, cH = 16, cE = 8, cF = 4096;
constexpr int cN = cB * cS;          // 8192 tokens
constexpr int cDH = 64;
constexpr int cCAP = 1280;           // int(1.25 * 8192 / 8)

typedef __attribute__((ext_vector_type(8))) short bf16x8;
typedef __attribute__((ext_vector_type(4))) float f32x4;
typedef __attribute__((ext_vector_type(4))) unsigned short u16x4;

__device__ inline unsigned short bf16_rne(float x) {
  unsigned u = __float_as_uint(x);
  u += 0x7FFF + ((u >> 16) & 1);
  return (unsigned short)(u >> 16);
}
__device__ inline float bf16_f(unsigned short h) {
  return __uint_as_float(((unsigned)h) << 16);
}

// ---------------------------------------------------------------------------
// LayerNorm fp32 (LN2): one block per token.
// ---------------------------------------------------------------------------
__global__ __launch_bounds__(256) void ln_kernel(const float* __restrict__ x,
                                                 const float* __restrict__ g,
                                                 const float* __restrict__ bb,
                                                 float* __restrict__ y) {
  __shared__ float red[8];
  const int row = blockIdx.x;
  const int t = threadIdx.x;
  const float4 v = ((const float4*)(x + (size_t)row * cD))[t];
  float s = v.x + v.y + v.z + v.w;
#pragma unroll
  for (int m = 32; m >= 1; m >>= 1) s += __shfl_xor(s, m, 64);
  if ((t & 63) == 0) red[t >> 6] = s;
  __syncthreads();
  const float mean = (red[0] + red[1] + red[2] + red[3]) * (1.0f / cD);
  const float dx = v.x - mean, dy = v.y - mean, dz = v.z - mean, dw = v.w - mean;
  float ss = dx * dx + dy * dy + dz * dz + dw * dw;
#pragma unroll
  for (int m = 32; m >= 1; m >>= 1) ss += __shfl_xor(ss, m, 64);
  if ((t & 63) == 0) red[4 + (t >> 6)] = ss;
  __syncthreads();
  const float var = (red[4] + red[5] + red[6] + red[7]) * (1.0f / cD);
  const float inv = rsqrtf(var + 1e-5f);
  const float4 gg = ((const float4*)g)[t];
  const float4 b4 = ((const float4*)bb)[t];
  float4 o;
  o.x = dx * inv * gg.x + b4.x;
  o.y = dy * inv * gg.y + b4.y;
  o.z = dz * inv * gg.z + b4.z;
  o.w = dw * inv * gg.w + b4.w;
  ((float4*)(y + (size_t)row * cD))[t] = o;
}

// ---------------------------------------------------------------------------
// LayerNorm with split-bf16 output (LN1 -> QKV GEMM A operand).
// ---------------------------------------------------------------------------
__global__ __launch_bounds__(256) void ln_split_kernel(
    const float* __restrict__ x, const float* __restrict__ g,
    const float* __restrict__ bb, unsigned short* __restrict__ yh,
    unsigned short* __restrict__ yl) {
  __shared__ float red[8];
  const int row = blockIdx.x;
  const int t = threadIdx.x;
  const float4 v = ((const float4*)(x + (size_t)row * cD))[t];
  float s = v.x + v.y + v.z + v.w;
#pragma unroll
  for (int m = 32; m >= 1; m >>= 1) s += __shfl_xor(s, m, 64);
  if ((t & 63) == 0) red[t >> 6] = s;
  __syncthreads();
  const float mean = (red[0] + red[1] + red[2] + red[3]) * (1.0f / cD);
  const float dx = v.x - mean, dy = v.y - mean, dz = v.z - mean, dw = v.w - mean;
  float ss = dx * dx + dy * dy + dz * dz + dw * dw;
#pragma unroll
  for (int m = 32; m >= 1; m >>= 1) ss += __shfl_xor(ss, m, 64);
  if ((t & 63) == 0) red[4 + (t >> 6)] = ss;
  __syncthreads();
  const float var = (red[4] + red[5] + red[6] + red[7]) * (1.0f / cD);
  const float inv = rsqrtf(var + 1e-5f);
  const float4 gg = ((const float4*)g)[t];
  const float4 b4 = ((const float4*)bb)[t];
  const float oa[4] = {dx * inv * gg.x + b4.x, dy * inv * gg.y + b4.y,
                       dz * inv * gg.z + b4.z, dw * inv * gg.w + b4.w};
  u16x4 hh, ll;
#pragma unroll
  for (int i = 0; i < 4; i++) {
    const unsigned short h16 = bf16_rne(oa[i]);
    hh[i] = h16;
    ll[i] = bf16_rne(oa[i] - bf16_f(h16));
  }
  *(u16x4*)(yh + (size_t)row * cD + t * 4) = hh;
  *(u16x4*)(yl + (size_t)row * cD + t * 4) = ll;
}

// ---------------------------------------------------------------------------
// Weight split: fp32 -> bf16 hi/lo, same layout. n4 = element_count/4.
// ---------------------------------------------------------------------------
__global__ __launch_bounds__(256) void wsplit_kernel(const float* __restrict__ in,
                                                     unsigned short* __restrict__ hi,
                                                     unsigned short* __restrict__ lo,
                                                     int n4) {
  const int i = blockIdx.x * 256 + threadIdx.x;
  if (i >= n4) return;
  const float4 v = ((const float4*)in)[i];
  const float a[4] = {v.x, v.y, v.z, v.w};
  u16x4 hh, ll;
#pragma unroll
  for (int j = 0; j < 4; j++) {
    const unsigned short h16 = bf16_rne(a[j]);
    hh[j] = h16;
    ll[j] = bf16_rne(a[j] - bf16_f(h16));
  }
  *(u16x4*)(hi + (size_t)i * 4) = hh;
  *(u16x4*)(lo + (size_t)i * 4) = ll;
}

// ---------------------------------------------------------------------------
// Pad mask precompute: byte -> float (-1e30 for pad, 0 otherwise).
// ---------------------------------------------------------------------------
__global__ __launch_bounds__(256) void padmask_kernel(
    const unsigned char* __restrict__ pad, float* __restrict__ mkf) {
  const int i = blockIdx.x * 256 + threadIdx.x;
  mkf[i] = pad[i] ? -1e30f : 0.0f;
}

// ---------------------------------------------------------------------------
// Transpose + bf16 convert: in fp32 [z][R][C] -> out bf16 [z][C][R].
// ---------------------------------------------------------------------------
__global__ __launch_bounds__(256) void transpose_bf16_kernel(
    const float* __restrict__ in, unsigned short* __restrict__ outp, int Rr,
    int Cc) {
  __shared__ float T[64][65];
  const int z = blockIdx.z;
  in += (size_t)z * Rr * Cc;
  outp += (size_t)z * Rr * Cc;
  const int c0 = blockIdx.x * 64, r0 = blockIdx.y * 64;
  const int tid = threadIdx.x;
#pragma unroll
  for (int u = 0; u < 4; u++) {
    const int a = tid + u * 256;
    const int r = a >> 4, c4 = (a & 15) << 2;
    const float4 v = *(const float4*)(in + (size_t)(r0 + r) * Cc + c0 + c4);
    T[r][c4 + 0] = v.x;
    T[r][c4 + 1] = v.y;
    T[r][c4 + 2] = v.z;
    T[r][c4 + 3] = v.w;
  }
  __syncthreads();
#pragma unroll
  for (int u = 0; u < 4; u++) {
    const int a = tid + u * 256;
    const int c = a >> 4, r4 = (a & 15) << 2;
    u16x4 o;
#pragma unroll
    for (int i = 0; i < 4; i++) o[i] = bf16_rne(T[r4 + i][c]);
    *(u16x4*)(outp + (size_t)(c0 + c) * Rr + r0 + r4) = o;
  }
}

// ---------------------------------------------------------------------------
// bf16 MFMA GEMM: C[M,N] = A[M,K] * B[N,K]^T + bias.
// OUT: 0 = fp32 C (+RELU/+RESID), 1 = bf16 C, 2 = fused QKV-split epilogue
// (writes Qh/Ql/Kh/Kl [b,h,s,d] and Vth/Vtl [b,h,d,s] split-bf16 directly).
// 128x128 tile, BK=32, 4 waves x (4x4 of 16x16x32 MFMA), LDS stride 40 u16.
// ---------------------------------------------------------------------------
template <bool SPLIT, bool RELU, bool RESID, int OUT>
__global__ __launch_bounds__(256) void gemm_bf16(
    const unsigned short* __restrict__ Ah, const unsigned short* __restrict__ Al,
    size_t sA,
    const unsigned short* __restrict__ Bh, const unsigned short* __restrict__ Bl,
    size_t sB,
    const float* __restrict__ bias, size_t sBias,
    const float* __restrict__ R,
    void* __restrict__ Cv, size_t sC,
    int K, int lda, int ldb, int ldc,
    unsigned short* __restrict__ Qh, unsigned short* __restrict__ Ql,
    unsigned short* __restrict__ Kh, unsigned short* __restrict__ Kl,
    unsigned short* __restrict__ Vth, unsigned short* __restrict__ Vtl) {
  __shared__ unsigned short AsH[128 * 40];
  __shared__ unsigned short BsH[128 * 40];
  __shared__ unsigned short AsL[SPLIT ? 128 * 40 : 8];
  __shared__ unsigned short BsL[SPLIT ? 128 * 40 : 8];
  const int z = blockIdx.z;
  Ah += (size_t)z * sA;
  Bh += (size_t)z * sB;
  if constexpr (SPLIT) {
    Al += (size_t)z * sA;
    Bl += (size_t)z * sB;
  }
  bias += (size_t)z * sBias;
  const int n0 = blockIdx.x * 128, m0 = blockIdx.y * 128;
  const int tid = threadIdx.x;
  const int wid = tid >> 6, lane = tid & 63;
  const int ln = lane & 15, quad = lane >> 4;
  const int wm = (wid >> 1) * 64, wn = (wid & 1) * 64;

  f32x4 acc[4][4];
#pragma unroll
  for (int i = 0; i < 4; i++)
#pragma unroll
    for (int j = 0; j < 4; j++) acc[i][j] = (f32x4){0.f, 0.f, 0.f, 0.f};

  for (int k0 = 0; k0 < K; k0 += 32) {
    __syncthreads();
#pragma unroll
    for (int u = 0; u < 2; u++) {
      const int c = tid + u * 256;           // 0..511
      const int row = c >> 2, ko = (c & 3) << 3;
      const int ld = row * 40 + ko;
      *(uint4*)&AsH[ld] = *(const uint4*)(Ah + (size_t)(m0 + row) * lda + k0 + ko);
      *(uint4*)&BsH[ld] = *(const uint4*)(Bh + (size_t)(n0 + row) * ldb + k0 + ko);
      if constexpr (SPLIT) {
        *(uint4*)&AsL[ld] = *(const uint4*)(Al + (size_t)(m0 + row) * lda + k0 + ko);
        *(uint4*)&BsL[ld] = *(const uint4*)(Bl + (size_t)(n0 + row) * ldb + k0 + ko);
      }
    }
    __syncthreads();
    bf16x8 bh[4], bl[4];
#pragma unroll
    for (int nt = 0; nt < 4; nt++) {
      bh[nt] = *(const bf16x8*)&BsH[(wn + nt * 16 + ln) * 40 + quad * 8];
      if constexpr (SPLIT)
        bl[nt] = *(const bf16x8*)&BsL[(wn + nt * 16 + ln) * 40 + quad * 8];
    }
#pragma unroll
    for (int mt = 0; mt < 4; mt++) {
      const bf16x8 ah = *(const bf16x8*)&AsH[(wm + mt * 16 + ln) * 40 + quad * 8];
      bf16x8 al;
      if constexpr (SPLIT)
        al = *(const bf16x8*)&AsL[(wm + mt * 16 + ln) * 40 + quad * 8];
#pragma unroll
      for (int nt = 0; nt < 4; nt++) {
        acc[mt][nt] =
            __builtin_amdgcn_mfma_f32_16x16x32_bf16(ah, bh[nt], acc[mt][nt], 0, 0, 0);
        if constexpr (SPLIT) {
          acc[mt][nt] =
              __builtin_amdgcn_mfma_f32_16x16x32_bf16(al, bh[nt], acc[mt][nt], 0, 0, 0);
          acc[mt][nt] =
              __builtin_amdgcn_mfma_f32_16x16x32_bf16(ah, bl[nt], acc[mt][nt], 0, 0, 0);
        }
      }
    }
  }
  // ---- epilogue ----
  if constexpr (OUT == 2) {
    // fused QKV split: col -> (sec,h,d); row -> (b,s). sec/h wave-uniform.
#pragma unroll
    for (int mt = 0; mt < 4; mt++) {
      const int row0 = m0 + wm + mt * 16 + quad * 4;
      const int b_ = row0 >> 11, s0_ = row0 & 2047;
      const size_t bbase = (size_t)b_ * cH * cS * cDH;
#pragma unroll
      for (int nt = 0; nt < 4; nt++) {
        const int col = n0 + wn + nt * 16 + ln;
        const float bv = bias[col];
        const int sec = col >> 10;
        const int f = col & 1023;
        const int hh = f >> 6, d = f & 63;
        const size_t bh_off = bbase + (size_t)hh * cS * cDH;
        float vals[4];
#pragma unroll
        for (int r = 0; r < 4; r++) vals[r] = acc[mt][nt][r] + bv;
        if (sec == 2) {
          u16x4 hi4, lo4;
#pragma unroll
          for (int r = 0; r < 4; r++) {
            const unsigned short h16 = bf16_rne(vals[r]);
            hi4[r] = h16;
            lo4[r] = bf16_rne(vals[r] - bf16_f(h16));
          }
          const size_t idx = bh_off + (size_t)d * cS + s0_;
          *(u16x4*)(Vth + idx) = hi4;
          *(u16x4*)(Vtl + idx) = lo4;
        } else {
          unsigned short* dsth = (sec == 0) ? Qh : Kh;
          unsigned short* dstl = (sec == 0) ? Ql : Kl;
#pragma unroll
          for (int r = 0; r < 4; r++) {
            const unsigned short h16 = bf16_rne(vals[r]);
            const size_t idx = bh_off + (size_t)(s0_ + r) * cDH + d;
            dsth[idx] = h16;
            dstl[idx] = bf16_rne(vals[r] - bf16_f(h16));
          }
        }
      }
    }
  } else {
    float* Cf = nullptr;
    unsigned short* Cb = nullptr;
    if constexpr (OUT == 1)
      Cb = (unsigned short*)Cv + (size_t)z * sC;
    else
      Cf = (float*)Cv + (size_t)z * sC;
#pragma unroll
    for (int mt = 0; mt < 4; mt++) {
#pragma unroll
      for (int nt = 0; nt < 4; nt++) {
        const int col = n0 + wn + nt * 16 + ln;
        const float bv = bias[col];
#pragma unroll
        for (int r = 0; r < 4; r++) {
          const int row = m0 + wm + mt * 16 + quad * 4 + r;
          float v = acc[mt][nt][r] + bv;
          if constexpr (RELU) v = fmaxf(v, 0.f);
          if constexpr (RESID) v += R[(size_t)row * ldc + col];
          if constexpr (OUT == 1)
            Cb[(size_t)row * ldc + col] = bf16_rne(v);
          else
            Cf[(size_t)row * ldc + col] = v;
        }
      }
    }
  }
}

// ---------------------------------------------------------------------------
// Flash attention v2: ZERO-LDS dataflow.
//   K [b,h,s,d] and V^T [b,h,d,s] are already in fragment-friendly global
//   layouts, and fragment addresses are wave-invariant -> read fragments
//   DIRECTLY from global (L1/L2-served; 16KB tile/iter). No staging, no
//   barriers, no bank conflicts.
//   P never leaves registers: MFMA's k-dim is just a reduction index, so we
//   permute keys so the PV B-fragment is the lane's own softmax packs:
//     k-slot (quad,j) of frag ks  <->  key 32ks + 16*(j>>2) + quad*4 + (j&3)
//   The matching V A-fragment is two b64 loads per row (+0B, +32B).
// ---------------------------------------------------------------------------
__device__ inline bf16x8 cat44(const u16x4 a, const u16x4 b) {
  bf16x8 r;
  r[0] = (short)a[0]; r[1] = (short)a[1]; r[2] = (short)a[2]; r[3] = (short)a[3];
  r[4] = (short)b[0]; r[5] = (short)b[1]; r[6] = (short)b[2]; r[7] = (short)b[3];
  return r;
}

__global__ __launch_bounds__(256) void attn_mfma_kernel(
    const unsigned short* __restrict__ Qh, const unsigned short* __restrict__ Ql,
    const unsigned short* __restrict__ Kh, const unsigned short* __restrict__ Kl,
    const unsigned short* __restrict__ Vth, const unsigned short* __restrict__ Vtl,
    const float* __restrict__ mkf, unsigned short* __restrict__ Oh,
    unsigned short* __restrict__ Ol) {
  const int q0 = blockIdx.x << 6;
  const int h = blockIdx.y, b = blockIdx.z;
  const int tid = threadIdx.x;
  const int wid = tid >> 6, lane = tid & 63;
  const int ln = lane & 15, quad = lane >> 4;
  constexpr float SC2 = 0.125f * 1.4426950408889634f;  // 1/sqrt(64) * log2(e)

  const size_t bh = (size_t)(b * cH + h);
  const unsigned short* gKh = Kh + bh * cS * cDH;
  const unsigned short* gKl = Kl + bh * cS * cDH;
  const unsigned short* gVh = Vth + bh * cDH * cS;
  const unsigned short* gVl = Vtl + bh * cDH * cS;
  const float* gM = mkf + (size_t)b * cS;

  // Q fragment (B-operand): lane q = ln, k = quad*8+j
  const size_t qbase = (bh * cS + q0 + wid * 16 + ln) * cDH;
  bf16x8 qh[2], ql[2];
#pragma unroll
  for (int ks = 0; ks < 2; ks++) {
    qh[ks] = *(const bf16x8*)(Qh + qbase + ks * 32 + quad * 8);
    ql[ks] = *(const bf16x8*)(Ql + qbase + ks * 32 + quad * 8);
  }

  f32x4 Oc[4];  // O^T: rows d (dt*16+quad*4+r), col q=ln
#pragma unroll
  for (int dt = 0; dt < 4; dt++) Oc[dt] = (f32x4){0.f, 0.f, 0.f, 0.f};
  float mprev = -1e30f, lrun = 0.f;  // per-lane (its q)

  for (int kt = 0; kt < cS / 64; kt++) {
    const int k0 = kt << 6;
    // ---- S^T = K Q^T (split 3-term). Lane: keys st*16+quad*4+r, q=ln ----
    float sf[4][4];
#pragma unroll
    for (int st = 0; st < 4; st++) {
      f32x4 acc = (f32x4){0.f, 0.f, 0.f, 0.f};
      const unsigned short* krH = gKh + (size_t)(k0 + st * 16 + ln) * cDH + quad * 8;
      const unsigned short* krL = gKl + (size_t)(k0 + st * 16 + ln) * cDH + quad * 8;
#pragma unroll
      for (int ks = 0; ks < 2; ks++) {
        const bf16x8 kh = *(const bf16x8*)(krH + ks * 32);
        const bf16x8 kl = *(const bf16x8*)(krL + ks * 32);
        acc = __builtin_amdgcn_mfma_f32_16x16x32_bf16(kh, qh[ks], acc, 0, 0, 0);
        acc = __builtin_amdgcn_mfma_f32_16x16x32_bf16(kl, qh[ks], acc, 0, 0, 0);
        acc = __builtin_amdgcn_mfma_f32_16x16x32_bf16(kh, ql[ks], acc, 0, 0, 0);
      }
      const float4 mkv = *(const float4*)(gM + k0 + st * 16 + quad * 4);
      sf[st][0] = acc[0] * SC2 + mkv.x;
      sf[st][1] = acc[1] * SC2 + mkv.y;
      sf[st][2] = acc[2] * SC2 + mkv.z;
      sf[st][3] = acc[3] * SC2 + mkv.w;
    }
    // ---- online softmax: one q per lane ----
    float vm = -1e30f;
#pragma unroll
    for (int st = 0; st < 4; st++)
#pragma unroll
      for (int r = 0; r < 4; r++) vm = fmaxf(vm, sf[st][r]);
    vm = fmaxf(vm, __shfl_xor(vm, 16, 64));
    vm = fmaxf(vm, __shfl_xor(vm, 32, 64));
    const float mnew = fmaxf(mprev, vm);
    const float alpha = exp2f(mprev - mnew);
    float rs = 0.f;
    // P packed directly into PV B-fragments (key permutation, see header)
    bf16x8 pbh[2], pbl[2];
#pragma unroll
    for (int st = 0; st < 4; st++) {
#pragma unroll
      for (int r = 0; r < 4; r++) {
        const float p = exp2f(sf[st][r] - mnew);
        rs += p;
        const unsigned short h16 = bf16_rne(p);
        pbh[st >> 1][(st & 1) * 4 + r] = (short)h16;
        pbl[st >> 1][(st & 1) * 4 + r] = (short)bf16_rne(p - bf16_f(h16));
      }
    }
    rs += __shfl_xor(rs, 16, 64);
    rs += __shfl_xor(rs, 32, 64);
    lrun = lrun * alpha + rs;
    mprev = mnew;
#pragma unroll
    for (int dt = 0; dt < 4; dt++) {
      Oc[dt][0] *= alpha;
      Oc[dt][1] *= alpha;
      Oc[dt][2] *= alpha;
      Oc[dt][3] *= alpha;
    }
    // ---- O^T += V^T P^T (split 3-term), V frags direct from global ----
#pragma unroll
    for (int dt = 0; dt < 4; dt++) {
      f32x4 acc = Oc[dt];
      const unsigned short* vrH = gVh + (size_t)(dt * 16 + ln) * cS + k0 + quad * 4;
      const unsigned short* vrL = gVl + (size_t)(dt * 16 + ln) * cS + k0 + quad * 4;
#pragma unroll
      for (int ks = 0; ks < 2; ks++) {
        const bf16x8 vh = cat44(*(const u16x4*)(vrH + ks * 32),
                                *(const u16x4*)(vrH + ks * 32 + 16));
        const bf16x8 vl = cat44(*(const u16x4*)(vrL + ks * 32),
                                *(const u16x4*)(vrL + ks * 32 + 16));
        acc = __builtin_amdgcn_mfma_f32_16x16x32_bf16(vh, pbh[ks], acc, 0, 0, 0);
        acc = __builtin_amdgcn_mfma_f32_16x16x32_bf16(vh, pbl[ks], acc, 0, 0, 0);
        acc = __builtin_amdgcn_mfma_f32_16x16x32_bf16(vl, pbh[ks], acc, 0, 0, 0);
      }
      Oc[dt] = acc;
    }
  }
  // ---- epilogue: normalize, split-bf16 store (u16x4 per dt) ----
  const float inv = 1.0f / lrun;
  const int tok = b * cS + q0 + wid * 16 + ln;
#pragma unroll
  for (int dt = 0; dt < 4; dt++) {
    u16x4 oh4, ol4;
#pragma unroll
    for (int r = 0; r < 4; r++) {
      const float v = Oc[dt][r] * inv;
      const unsigned short h16 = bf16_rne(v);
      oh4[r] = h16;
      ol4[r] = bf16_rne(v - bf16_f(h16));
    }
    const size_t idx = (size_t)tok * cD + h * cDH + dt * 16 + quad * 4;
    *(u16x4*)(Oh + idx) = oh4;
    *(u16x4*)(Ol + idx) = ol4;
  }
}

// ---------------------------------------------------------------------------
// Router (fp32 exact — feeds the discontinuous argmax).
// ---------------------------------------------------------------------------
__global__ __launch_bounds__(256) void router_kernel(
    const float* __restrict__ x2, const float* __restrict__ rw,
    const float* __restrict__ rb, const unsigned char* __restrict__ pad,
    float* __restrict__ gate, int* __restrict__ eidx, float* __restrict__ Psum,
    float* __restrict__ zsum) {
  __shared__ float Pacc[8];
  __shared__ float Zacc;
  if (threadIdx.x < 8) Pacc[threadIdx.x] = 0.f;
  if (threadIdx.x == 8) Zacc = 0.f;
  __syncthreads();
  const int tid = threadIdx.x, wid = tid >> 6, lane = tid & 63;
  const int e = lane & 7, dbase = lane >> 3;
  for (int tok = blockIdx.x * 4 + wid; tok < cN; tok += gridDim.x * 4) {
    const float* xr = x2 + (size_t)tok * cD;
    float partial = 0.f;
#pragma unroll 8
    for (int i = 0; i < cD / 8; i++) {
      const int d = dbase + i * 8;
      partial += xr[d] * rw[d * 8 + e];
    }
    partial += __shfl_xor(partial, 8, 64);
    partial += __shfl_xor(partial, 16, 64);
    partial += __shfl_xor(partial, 32, 64);
    const float logit = partial + rb[e];
    float mx = logit;
    mx = fmaxf(mx, __shfl_xor(mx, 1, 64));
    mx = fmaxf(mx, __shfl_xor(mx, 2, 64));
    mx = fmaxf(mx, __shfl_xor(mx, 4, 64));
    const float ex = __expf(logit - mx);
    float sm = ex;
    sm += __shfl_xor(sm, 1, 64);
    sm += __shfl_xor(sm, 2, 64);
    sm += __shfl_xor(sm, 4, 64);
    const float prob = ex / sm;
    float bv = logit;
    int bi = e;
#pragma unroll
    for (int m = 1; m < 8; m <<= 1) {
      const float ov = __shfl_xor(bv, m, 64);
      const int oi = __shfl_xor(bi, m, 64);
      if (ov > bv || (ov == bv && oi < bi)) {
        bv = ov;
        bi = oi;
      }
    }
    const float g = __shfl(prob, (lane & 0x38) | bi, 64);
    const bool valid = (pad[tok] == 0);
    if (lane == 0) {
      eidx[tok] = bi;
      gate[tok] = g;
    }
    if (valid) {
      if (lane < 8) atomicAdd(&Pacc[lane], prob);
      if (lane == 0) {
        const float lse = mx + logf(sm);
        atomicAdd(&Zacc, lse * lse);
      }
    }
  }
  __syncthreads();
  if (threadIdx.x < 8) atomicAdd(&Psum[threadIdx.x], Pacc[threadIdx.x]);
  if (threadIdx.x == 8) atomicAdd(zsum, Zacc);
}

// ---------------------------------------------------------------------------
// Capacity scan (unchanged).
// ---------------------------------------------------------------------------
__global__ __launch_bounds__(256) void scan_kernel(const int* __restrict__ eidx,
                                                   const unsigned char* __restrict__ pad,
                                                   int* __restrict__ slot,
                                                   int* __restrict__ counts) {
  __shared__ int cnt[256][8];
  const int t = threadIdx.x;
  int lc[8] = {0, 0, 0, 0, 0, 0, 0, 0};
  const int base = t * 32;
  for (int i = 0; i < 32; i++) {
    const int tok = base + i;
    if (!pad[tok]) lc[eidx[tok]]++;
  }
#pragma unroll
  for (int e2 = 0; e2 < 8; e2++) cnt[t][e2] = lc[e2];
  __syncthreads();
  if (t < 8) {
    int run = 0;
    for (int i = 0; i < 256; i++) {
      const int v = cnt[i][t];
      cnt[i][t] = run;
      run += v;
    }
    counts[t] = run;
  }
  __syncthreads();
  int off[8];
#pragma unroll
  for (int e2 = 0; e2 < 8; e2++) off[e2] = cnt[t][e2];
  for (int i = 0; i < 32; i++) {
    const int tok = base + i;
    if (!pad[tok]) {
      const int e2 = eidx[tok];
      const int p = off[e2]++;
      slot[tok] = (p < cCAP) ? (e2 * cCAP + p) : -1;
    } else {
      slot[tok] = -1;
    }
  }
}

__global__ __launch_bounds__(256) void dispatch_bf16_kernel(
    const float* __restrict__ x2, const int* __restrict__ slot,
    unsigned short* __restrict__ disp) {
  const int tok = blockIdx.x;
  const int s = slot[tok];
  if (s < 0) return;
  const float4 v = ((const float4*)(x2 + (size_t)tok * cD))[threadIdx.x];
  u16x4 o;
  o[0] = bf16_rne(v.x);
  o[1] = bf16_rne(v.y);
  o[2] = bf16_rne(v.z);
  o[3] = bf16_rne(v.w);
  *(u16x4*)(disp + (size_t)s * cD + threadIdx.x * 4) = o;
}

__global__ __launch_bounds__(256) void gather_kernel(const float* __restrict__ src1,
                                                     const float* __restrict__ o,
                                                     const int* __restrict__ slot,
                                                     const float* __restrict__ gate,
                                                     float* __restrict__ out) {
  const int tok = blockIdx.x;
  float4 r = ((const float4*)(src1 + (size_t)tok * cD))[threadIdx.x];
  const int s = slot[tok];
  if (s >= 0) {
    const float g = gate[tok];
    const float4 ov = ((const float4*)(o + (size_t)s * cD))[threadIdx.x];
    r.x += g * ov.x;
    r.y += g * ov.y;
    r.z += g * ov.z;
    r.w += g * ov.w;
  }
  ((float4*)(out + (size_t)tok * cD))[threadIdx.x] = r;
}

__global__ void loss_kernel(const int* __restrict__ counts,
                            const float* __restrict__ Psum,
                            const float* __restrict__ zsum,
                            float* __restrict__ out) {
  if (threadIdx.x == 0) {
    int tot = 0;
    for (int e2 = 0; e2 < 8; e2++) tot += counts[e2];
    const float denom = fmaxf((float)tot, 1.0f);
    float lp = 0.f;
    for (int e2 = 0; e2 < 8; e2++)
      lp += ((float)counts[e2] / denom) * (Psum[e2] / denom);
    out[0] = 8.0f * lp;
    out[1] = zsum[0] / denom;
  }
}

// ---------------------------------------------------------------------------
// Workspace layout (float units), sequential lifetimes:
// R_A: w1t bf16 (->FFN1) / w2t bf16 (->FFN2)   (qkv fp32 no longer exists)
// R_B: Q..Vt splits (QKV gemm->attn) / h bf16 (FFN1->FFN2)
// R_XHL: xh+xl (LN1->QKV) / Oh+Ol (attn->out_proj) / disp bf16 (->FFN1)
// R_X2O: mkf (padmask->attn) / x2 (LN2->dispatch) / obuf fp32 (FFN2->gather)
// ---------------------------------------------------------------------------
constexpr size_t OFF_A = 0;              // 25,165,824 floats
constexpr size_t OFF_B = 25165824;       // 25,165,824
constexpr size_t OFF_XHL = 50331648;     // 8,388,608
constexpr size_t OFF_SRC1 = 58720256;    // 8,388,608
constexpr size_t OFF_X2O = 67108864;     // 10,485,760
constexpr size_t OFF_IPW = 77594624;     // 3,145,728
constexpr size_t OFF_OPW = 80740352;     // 1,048,576
constexpr size_t OFF_MISC = 81788928;

extern "C" void kernel_launch(void* const* d_in, const int* in_sizes, int n_in,
                              void* d_out, int out_size, void* d_ws, size_t ws_size,
                              hipStream_t stream) {
  (void)in_sizes; (void)n_in; (void)out_size; (void)ws_size;
  const float* src = (const float*)d_in[0];
  const unsigned char* pad = (const unsigned char*)d_in[1];
  const float* ln1_g = (const float*)d_in[2];
  const float* ln1_b = (const float*)d_in[3];
  const float* in_proj_w = (const float*)d_in[4];
  const float* in_proj_b = (const float*)d_in[5];
  const float* out_proj_w = (const float*)d_in[6];
  const float* out_proj_b = (const float*)d_in[7];
  const float* ln2_g = (const float*)d_in[8];
  const float* ln2_b = (const float*)d_in[9];
  const float* router_w = (const float*)d_in[10];
  const float* router_b = (const float*)d_in[11];
  const float* w1 = (const float*)d_in[12];
  const float* b1 = (const float*)d_in[13];
  const float* w2 = (const float*)d_in[14];
  const float* b2 = (const float*)d_in[15];
  float* out = (float*)d_out;
  float* w = (float*)d_ws;

  unsigned short* w1t = (unsigned short*)(w + OFF_A);
  unsigned short* w2t = (unsigned short*)(w + OFF_A);   // after w1t dead
  unsigned short* usB = (unsigned short*)(w + OFF_B);
  constexpr size_t SPN = (size_t)cN * cD;               // 8,388,608 u16
  unsigned short* Qh = usB + 0 * SPN;
  unsigned short* Ql = usB + 1 * SPN;
  unsigned short* Kh = usB + 2 * SPN;
  unsigned short* Kl = usB + 3 * SPN;
  unsigned short* Vth = usB + 4 * SPN;
  unsigned short* Vtl = usB + 5 * SPN;
  unsigned short* hbuf16 = usB;                          // after splits dead
  unsigned short* xh = (unsigned short*)(w + OFF_XHL);
  unsigned short* xl = xh + SPN;
  unsigned short* Oh = xh;                               // after xh/xl dead
  unsigned short* Ol = xh + SPN;
  unsigned short* disp16 = xh;                           // after Oh/Ol dead
  float* src1 = w + OFF_SRC1;
  float* mkf = w + OFF_X2O;                              // dead before x2 written
  float* x2 = w + OFF_X2O;
  float* obuf = w + OFF_X2O;                             // after x2 dead
  unsigned short* ipwh = (unsigned short*)(w + OFF_IPW);
  unsigned short* ipwl = ipwh + (size_t)3 * cD * cD;
  unsigned short* opwh = (unsigned short*)(w + OFF_OPW);
  unsigned short* opwl = opwh + (size_t)cD * cD;
  float* gate = w + OFF_MISC;
  int* eidx = (int*)(w + OFF_MISC + 8192);
  int* slot = (int*)(w + OFF_MISC + 16384);
  float* Psum = w + OFF_MISC + 24576;
  float* zsum = Psum + 8;
  int* counts = (int*)(Psum + 16);

  hipMemsetAsync(Psum, 0, 9 * sizeof(float), stream);

  // 1) LN1 -> split bf16
  ln_split_kernel<<<cN, 256, 0, stream>>>(src, ln1_g, ln1_b, xh, xl);
  // 1.2) pad mask -> float additive mask (read by attn as float4)
  padmask_kernel<<<cN / 256, 256, 0, stream>>>(pad, mkf);
  // 1.5) weight splits
  wsplit_kernel<<<3072, 256, 0, stream>>>(in_proj_w, ipwh, ipwl, 786432);
  wsplit_kernel<<<1024, 256, 0, stream>>>(out_proj_w, opwh, opwl, 262144);
  // 2) QKV projection (split 3-term) with FUSED qkv-split epilogue
  gemm_bf16<true, false, false, 2><<<dim3(24, 64, 1), 256, 0, stream>>>(
      xh, xl, 0, ipwh, ipwl, 0, in_proj_b, 0, nullptr, nullptr, 0,
      cD, cD, cD, 0, Qh, Ql, Kh, Kl, Vth, Vtl);
  // 2.5) w1 transpose+convert: [e][d][f] -> [e][f][d] bf16
  transpose_bf16_kernel<<<dim3(64, 16, 8), 256, 0, stream>>>(w1, w1t, cD, cF);
  // 3) MFMA flash attention (zero-LDS direct-global dataflow) -> Oh/Ol
  attn_mfma_kernel<<<dim3(cS / 64, cH, cB), 256, 0, stream>>>(
      Qh, Ql, Kh, Kl, Vth, Vtl, mkf, Oh, Ol);
  // 4) out_proj (split 3-term) + residual(src) -> src1 fp32
  gemm_bf16<true, false, true, 0><<<dim3(8, 64, 1), 256, 0, stream>>>(
      Oh, Ol, 0, opwh, opwl, 0, out_proj_b, 0, src, src1, 0,
      cD, cD, cD, cD, nullptr, nullptr, nullptr, nullptr, nullptr, nullptr);
  // 5) LN2 (fp32 exact)
  ln_kernel<<<cN, 256, 0, stream>>>(src1, ln2_g, ln2_b, x2);
  // 6) router
  router_kernel<<<256, 256, 0, stream>>>(x2, router_w, router_b, pad, gate, eidx,
                                         Psum, zsum);
  // 7) capacity scan
  scan_kernel<<<1, 256, 0, stream>>>(eidx, pad, slot, counts);
  // 8) dispatch scatter -> bf16
  dispatch_bf16_kernel<<<cN, 256, 0, stream>>>(x2, slot, disp16);
  // 9) FFN1: relu(disp @ w1 + b1) -> h bf16 (plain bf16 MFMA)
  gemm_bf16<false, true, false, 1><<<dim3(32, 10, 8), 256, 0, stream>>>(
      disp16, nullptr, (size_t)cCAP * cD, w1t, nullptr, (size_t)cD * cF,
      b1, cF, nullptr, hbuf16, (size_t)cCAP * cF, cD, cD, cD, cF,
      nullptr, nullptr, nullptr, nullptr, nullptr, nullptr);
  // 9.5) w2 transpose+convert: [e][f][d] -> [e][d][f] bf16 (w1t dead)
  transpose_bf16_kernel<<<dim3(16, 64, 8), 256, 0, stream>>>(w2, w2t, cF, cD);
  // 10) FFN2: h @ w2 + b2 -> obuf fp32
  gemm_bf16<false, false, false, 0><<<dim3(8, 10, 8), 256, 0, stream>>>(
      hbuf16, nullptr, (size_t)cCAP * cF, w2t, nullptr, (size_t)cF * cD,
      b2, cD, nullptr, obuf, (size_t)cCAP * cD, cF, cF, cF, cD,
      nullptr, nullptr, nullptr, nullptr, nullptr, nullptr);
  // 11) gather + residual -> out
  gather_kernel<<<cN, 256, 0, stream>>>(src1, obuf, slot, gate, out);
  // 12) losses
  loss_kernel<<<1, 64, 0, stream>>>(counts, Psum, zsum, out + (size_t)cN * cD);
}

// Round 2
// 1579.465 us; speedup vs baseline: 1.5008x; 1.5008x over previous
//
#include <hip/hip_runtime.h>

// Problem constants
constexpr int cB = 4, cS = 2048, cD = 1024, cH = 16, cE = 8, cF = 4096;
constexpr int cN = cB * cS;          // 8192 tokens
constexpr int cDH = 64;
constexpr int cCAP = 1280;           // int(1.25 * 8192 / 8)

typedef __attribute__((ext_vector_type(8))) short bf16x8;
typedef __attribute__((ext_vector_type(4))) float f32x4;
typedef __attribute__((ext_vector_type(4))) unsigned short u16x4;

__device__ inline unsigned short bf16_rne(float x) {
  unsigned u = __float_as_uint(x);
  u += 0x7FFF + ((u >> 16) & 1);
  return (unsigned short)(u >> 16);
}
__device__ inline float bf16_f(unsigned short h) {
  return __uint_as_float(((unsigned)h) << 16);
}

// ---------------------------------------------------------------------------
// LayerNorm fp32 (LN2): one block per token.
// ---------------------------------------------------------------------------
__global__ __launch_bounds__(256) void ln_kernel(const float* __restrict__ x,
                                                 const float* __restrict__ g,
                                                 const float* __restrict__ bb,
                                                 float* __restrict__ y) {
  __shared__ float red[8];
  const int row = blockIdx.x;
  const int t = threadIdx.x;
  const float4 v = ((const float4*)(x + (size_t)row * cD))[t];
  float s = v.x + v.y + v.z + v.w;
#pragma unroll
  for (int m = 32; m >= 1; m >>= 1) s += __shfl_xor(s, m, 64);
  if ((t & 63) == 0) red[t >> 6] = s;
  __syncthreads();
  const float mean = (red[0] + red[1] + red[2] + red[3]) * (1.0f / cD);
  const float dx = v.x - mean, dy = v.y - mean, dz = v.z - mean, dw = v.w - mean;
  float ss = dx * dx + dy * dy + dz * dz + dw * dw;
#pragma unroll
  for (int m = 32; m >= 1; m >>= 1) ss += __shfl_xor(ss, m, 64);
  if ((t & 63) == 0) red[4 + (t >> 6)] = ss;
  __syncthreads();
  const float var = (red[4] + red[5] + red[6] + red[7]) * (1.0f / cD);
  const float inv = rsqrtf(var + 1e-5f);
  const float4 gg = ((const float4*)g)[t];
  const float4 b4 = ((const float4*)bb)[t];
  float4 o;
  o.x = dx * inv * gg.x + b4.x;
  o.y = dy * inv * gg.y + b4.y;
  o.z = dz * inv * gg.z + b4.z;
  o.w = dw * inv * gg.w + b4.w;
  ((float4*)(y + (size_t)row * cD))[t] = o;
}

// ---------------------------------------------------------------------------
// LayerNorm with split-bf16 output (LN1 -> QKV GEMM A operand).
// ---------------------------------------------------------------------------
__global__ __launch_bounds__(256) void ln_split_kernel(
    const float* __restrict__ x, const float* __restrict__ g,
    const float* __restrict__ bb, unsigned short* __restrict__ yh,
    unsigned short* __restrict__ yl) {
  __shared__ float red[8];
  const int row = blockIdx.x;
  const int t = threadIdx.x;
  const float4 v = ((const float4*)(x + (size_t)row * cD))[t];
  float s = v.x + v.y + v.z + v.w;
#pragma unroll
  for (int m = 32; m >= 1; m >>= 1) s += __shfl_xor(s, m, 64);
  if ((t & 63) == 0) red[t >> 6] = s;
  __syncthreads();
  const float mean = (red[0] + red[1] + red[2] + red[3]) * (1.0f / cD);
  const float dx = v.x - mean, dy = v.y - mean, dz = v.z - mean, dw = v.w - mean;
  float ss = dx * dx + dy * dy + dz * dz + dw * dw;
#pragma unroll
  for (int m = 32; m >= 1; m >>= 1) ss += __shfl_xor(ss, m, 64);
  if ((t & 63) == 0) red[4 + (t >> 6)] = ss;
  __syncthreads();
  const float var = (red[4] + red[5] + red[6] + red[7]) * (1.0f / cD);
  const float inv = rsqrtf(var + 1e-5f);
  const float4 gg = ((const float4*)g)[t];
  const float4 b4 = ((const float4*)bb)[t];
  const float oa[4] = {dx * inv * gg.x + b4.x, dy * inv * gg.y + b4.y,
                       dz * inv * gg.z + b4.z, dw * inv * gg.w + b4.w};
  u16x4 hh, ll;
#pragma unroll
  for (int i = 0; i < 4; i++) {
    const unsigned short h16 = bf16_rne(oa[i]);
    hh[i] = h16;
    ll[i] = bf16_rne(oa[i] - bf16_f(h16));
  }
  *(u16x4*)(yh + (size_t)row * cD + t * 4) = hh;
  *(u16x4*)(yl + (size_t)row * cD + t * 4) = ll;
}

// ---------------------------------------------------------------------------
// Weight split: fp32 -> bf16 hi/lo, same layout. n4 = element_count/4.
// ---------------------------------------------------------------------------
__global__ __launch_bounds__(256) void wsplit_kernel(const float* __restrict__ in,
                                                     unsigned short* __restrict__ hi,
                                                     unsigned short* __restrict__ lo,
                                                     int n4) {
  const int i = blockIdx.x * 256 + threadIdx.x;
  if (i >= n4) return;
  const float4 v = ((const float4*)in)[i];
  const float a[4] = {v.x, v.y, v.z, v.w};
  u16x4 hh, ll;
#pragma unroll
  for (int j = 0; j < 4; j++) {
    const unsigned short h16 = bf16_rne(a[j]);
    hh[j] = h16;
    ll[j] = bf16_rne(a[j] - bf16_f(h16));
  }
  *(u16x4*)(hi + (size_t)i * 4) = hh;
  *(u16x4*)(lo + (size_t)i * 4) = ll;
}

// ---------------------------------------------------------------------------
// Pad mask precompute: byte -> float (-1e30 for pad, 0 otherwise).
// ---------------------------------------------------------------------------
__global__ __launch_bounds__(256) void padmask_kernel(
    const unsigned char* __restrict__ pad, float* __restrict__ mkf) {
  const int i = blockIdx.x * 256 + threadIdx.x;
  mkf[i] = pad[i] ? -1e30f : 0.0f;
}

// ---------------------------------------------------------------------------
// Transpose + bf16 convert: in fp32 [z][R][C] -> out bf16 [z][C][R].
// ---------------------------------------------------------------------------
__global__ __launch_bounds__(256) void transpose_bf16_kernel(
    const float* __restrict__ in, unsigned short* __restrict__ outp, int Rr,
    int Cc) {
  __shared__ float T[64][65];
  const int z = blockIdx.z;
  in += (size_t)z * Rr * Cc;
  outp += (size_t)z * Rr * Cc;
  const int c0 = blockIdx.x * 64, r0 = blockIdx.y * 64;
  const int tid = threadIdx.x;
#pragma unroll
  for (int u = 0; u < 4; u++) {
    const int a = tid + u * 256;
    const int r = a >> 4, c4 = (a & 15) << 2;
    const float4 v = *(const float4*)(in + (size_t)(r0 + r) * Cc + c0 + c4);
    T[r][c4 + 0] = v.x;
    T[r][c4 + 1] = v.y;
    T[r][c4 + 2] = v.z;
    T[r][c4 + 3] = v.w;
  }
  __syncthreads();
#pragma unroll
  for (int u = 0; u < 4; u++) {
    const int a = tid + u * 256;
    const int c = a >> 4, r4 = (a & 15) << 2;
    u16x4 o;
#pragma unroll
    for (int i = 0; i < 4; i++) o[i] = bf16_rne(T[r4 + i][c]);
    *(u16x4*)(outp + (size_t)(c0 + c) * Rr + r0 + r4) = o;
  }
}

// ---------------------------------------------------------------------------
// bf16 MFMA GEMM: C[M,N] = A[M,K] * B[N,K]^T + bias.
// OUT: 0 = fp32 C (+RELU/+RESID), 1 = bf16 C, 2 = fused QKV-split epilogue
// (writes Qh/Ql/Kh/Kl [b,h,s,d] and Vth/Vtl [b,h,d,s] split-bf16 directly).
// 128x128 tile, BK=32, 4 waves x (4x4 of 16x16x32 MFMA), LDS stride 40 u16.
// ---------------------------------------------------------------------------
template <bool SPLIT, bool RELU, bool RESID, int OUT>
__global__ __launch_bounds__(256) void gemm_bf16(
    const unsigned short* __restrict__ Ah, const unsigned short* __restrict__ Al,
    size_t sA,
    const unsigned short* __restrict__ Bh, const unsigned short* __restrict__ Bl,
    size_t sB,
    const float* __restrict__ bias, size_t sBias,
    const float* __restrict__ R,
    void* __restrict__ Cv, size_t sC,
    int K, int lda, int ldb, int ldc,
    unsigned short* __restrict__ Qh, unsigned short* __restrict__ Ql,
    unsigned short* __restrict__ Kh, unsigned short* __restrict__ Kl,
    unsigned short* __restrict__ Vth, unsigned short* __restrict__ Vtl) {
  __shared__ unsigned short AsH[128 * 40];
  __shared__ unsigned short BsH[128 * 40];
  __shared__ unsigned short AsL[SPLIT ? 128 * 40 : 8];
  __shared__ unsigned short BsL[SPLIT ? 128 * 40 : 8];
  const int z = blockIdx.z;
  Ah += (size_t)z * sA;
  Bh += (size_t)z * sB;
  if constexpr (SPLIT) {
    Al += (size_t)z * sA;
    Bl += (size_t)z * sB;
  }
  bias += (size_t)z * sBias;
  const int n0 = blockIdx.x * 128, m0 = blockIdx.y * 128;
  const int tid = threadIdx.x;
  const int wid = tid >> 6, lane = tid & 63;
  const int ln = lane & 15, quad = lane >> 4;
  const int wm = (wid >> 1) * 64, wn = (wid & 1) * 64;

  f32x4 acc[4][4];
#pragma unroll
  for (int i = 0; i < 4; i++)
#pragma unroll
    for (int j = 0; j < 4; j++) acc[i][j] = (f32x4){0.f, 0.f, 0.f, 0.f};

  for (int k0 = 0; k0 < K; k0 += 32) {
    __syncthreads();
#pragma unroll
    for (int u = 0; u < 2; u++) {
      const int c = tid + u * 256;           // 0..511
      const int row = c >> 2, ko = (c & 3) << 3;
      const int ld = row * 40 + ko;
      *(uint4*)&AsH[ld] = *(const uint4*)(Ah + (size_t)(m0 + row) * lda + k0 + ko);
      *(uint4*)&BsH[ld] = *(const uint4*)(Bh + (size_t)(n0 + row) * ldb + k0 + ko);
      if constexpr (SPLIT) {
        *(uint4*)&AsL[ld] = *(const uint4*)(Al + (size_t)(m0 + row) * lda + k0 + ko);
        *(uint4*)&BsL[ld] = *(const uint4*)(Bl + (size_t)(n0 + row) * ldb + k0 + ko);
      }
    }
    __syncthreads();
    bf16x8 bh[4], bl[4];
#pragma unroll
    for (int nt = 0; nt < 4; nt++) {
      bh[nt] = *(const bf16x8*)&BsH[(wn + nt * 16 + ln) * 40 + quad * 8];
      if constexpr (SPLIT)
        bl[nt] = *(const bf16x8*)&BsL[(wn + nt * 16 + ln) * 40 + quad * 8];
    }
#pragma unroll
    for (int mt = 0; mt < 4; mt++) {
      const bf16x8 ah = *(const bf16x8*)&AsH[(wm + mt * 16 + ln) * 40 + quad * 8];
      bf16x8 al;
      if constexpr (SPLIT)
        al = *(const bf16x8*)&AsL[(wm + mt * 16 + ln) * 40 + quad * 8];
#pragma unroll
      for (int nt = 0; nt < 4; nt++) {
        acc[mt][nt] =
            __builtin_amdgcn_mfma_f32_16x16x32_bf16(ah, bh[nt], acc[mt][nt], 0, 0, 0);
        if constexpr (SPLIT) {
          acc[mt][nt] =
              __builtin_amdgcn_mfma_f32_16x16x32_bf16(al, bh[nt], acc[mt][nt], 0, 0, 0);
          acc[mt][nt] =
              __builtin_amdgcn_mfma_f32_16x16x32_bf16(ah, bl[nt], acc[mt][nt], 0, 0, 0);
        }
      }
    }
  }
  // ---- epilogue ----
  if constexpr (OUT == 2) {
    // fused QKV split: col -> (sec,h,d); row -> (b,s). sec/h wave-uniform.
#pragma unroll
    for (int mt = 0; mt < 4; mt++) {
      const int row0 = m0 + wm + mt * 16 + quad * 4;
      const int b_ = row0 >> 11, s0_ = row0 & 2047;
      const size_t bbase = (size_t)b_ * cH * cS * cDH;
#pragma unroll
      for (int nt = 0; nt < 4; nt++) {
        const int col = n0 + wn + nt * 16 + ln;
        const float bv = bias[col];
        const int sec = col >> 10;
        const int f = col & 1023;
        const int hh = f >> 6, d = f & 63;
        const size_t bh_off = bbase + (size_t)hh * cS * cDH;
        float vals[4];
#pragma unroll
        for (int r = 0; r < 4; r++) vals[r] = acc[mt][nt][r] + bv;
        if (sec == 2) {
          u16x4 hi4, lo4;
#pragma unroll
          for (int r = 0; r < 4; r++) {
            const unsigned short h16 = bf16_rne(vals[r]);
            hi4[r] = h16;
            lo4[r] = bf16_rne(vals[r] - bf16_f(h16));
          }
          const size_t idx = bh_off + (size_t)d * cS + s0_;
          *(u16x4*)(Vth + idx) = hi4;
          *(u16x4*)(Vtl + idx) = lo4;
        } else {
          unsigned short* dsth = (sec == 0) ? Qh : Kh;
          unsigned short* dstl = (sec == 0) ? Ql : Kl;
#pragma unroll
          for (int r = 0; r < 4; r++) {
            const unsigned short h16 = bf16_rne(vals[r]);
            const size_t idx = bh_off + (size_t)(s0_ + r) * cDH + d;
            dsth[idx] = h16;
            dstl[idx] = bf16_rne(vals[r] - bf16_f(h16));
          }
        }
      }
    }
  } else {
    float* Cf = nullptr;
    unsigned short* Cb = nullptr;
    if constexpr (OUT == 1)
      Cb = (unsigned short*)Cv + (size_t)z * sC;
    else
      Cf = (float*)Cv + (size_t)z * sC;
#pragma unroll
    for (int mt = 0; mt < 4; mt++) {
#pragma unroll
      for (int nt = 0; nt < 4; nt++) {
        const int col = n0 + wn + nt * 16 + ln;
        const float bv = bias[col];
#pragma unroll
        for (int r = 0; r < 4; r++) {
          const int row = m0 + wm + mt * 16 + quad * 4 + r;
          float v = acc[mt][nt][r] + bv;
          if constexpr (RELU) v = fmaxf(v, 0.f);
          if constexpr (RESID) v += R[(size_t)row * ldc + col];
          if constexpr (OUT == 1)
            Cb[(size_t)row * ldc + col] = bf16_rne(v);
          else
            Cf[(size_t)row * ldc + col] = v;
        }
      }
    }
  }
}

// ---------------------------------------------------------------------------
// Flash attention v3: LDS-staged K/V (XOR-swizzled, conflict-free) +
// in-register P (key-permuted PV fragments, verified in v2) + async staging
// (next tile's global loads issued before compute; write after barrier).
//   LDS layout: [64 rows][64 u16] with byte swizzle  b ^= (row&7)<<4.
//   Same involution on write and read (Guideline 4 / T2).
//   Per iter: 2 barriers; 32KB staged; no P/Mk LDS traffic.
// ---------------------------------------------------------------------------
__device__ inline bf16x8 cat44(const u16x4 a, const u16x4 b) {
  bf16x8 r;
  r[0] = (short)a[0]; r[1] = (short)a[1]; r[2] = (short)a[2]; r[3] = (short)a[3];
  r[4] = (short)b[0]; r[5] = (short)b[1]; r[6] = (short)b[2]; r[7] = (short)b[3];
  return r;
}

__global__ __launch_bounds__(256) void attn_mfma_kernel(
    const unsigned short* __restrict__ Qh, const unsigned short* __restrict__ Ql,
    const unsigned short* __restrict__ Kh, const unsigned short* __restrict__ Kl,
    const unsigned short* __restrict__ Vth, const unsigned short* __restrict__ Vtl,
    const float* __restrict__ mkf, unsigned short* __restrict__ Oh,
    unsigned short* __restrict__ Ol) {
  __shared__ alignas(16) unsigned short KsH[64 * 64];
  __shared__ alignas(16) unsigned short KsL[64 * 64];
  __shared__ alignas(16) unsigned short VsH[64 * 64];
  __shared__ alignas(16) unsigned short VsL[64 * 64];

  const int q0 = blockIdx.x << 6;
  const int h = blockIdx.y, b = blockIdx.z;
  const int tid = threadIdx.x;
  const int wid = tid >> 6, lane = tid & 63;
  const int ln = lane & 15, quad = lane >> 4;
  constexpr float SC2 = 0.125f * 1.4426950408889634f;  // 1/sqrt(64) * log2(e)

  const size_t bh = (size_t)(b * cH + h);
  const unsigned short* gKh = Kh + bh * cS * cDH;
  const unsigned short* gKl = Kl + bh * cS * cDH;
  const unsigned short* gVh = Vth + bh * cDH * cS;
  const unsigned short* gVl = Vtl + bh * cDH * cS;
  const float* gM = mkf + (size_t)b * cS;

  // staging map: thread covers rows tid>>3 and +32, 8 u16 (16B) each
  const int srow0 = tid >> 3;
  const int srow1 = srow0 + 32;
  const int scol = (tid & 7) << 3;          // u16 col
  const int sbyte = scol << 1;              // byte col
  const int wb0 = srow0 * 128 + (sbyte ^ ((srow0 & 7) << 4));
  const int wb1 = srow1 * 128 + (sbyte ^ ((srow1 & 7) << 4));

  // per-lane swizzled read byte offsets
  const int xs = (ln & 7) << 4;
  const int kc[2] = {(quad * 16) ^ xs, (quad * 16 + 64) ^ xs};          // K b128
  const int vc0[2] = {(quad * 8) ^ xs, (quad * 8 + 64) ^ xs};           // V b64 lo
  const int vc1[2] = {(quad * 8 + 32) ^ xs, (quad * 8 + 96) ^ xs};      // V b64 hi

  // Q fragment (B-operand): lane q = ln, k = quad*8+j
  const size_t qbase = (bh * cS + q0 + wid * 16 + ln) * cDH;
  bf16x8 qh[2], ql[2];
#pragma unroll
  for (int ks = 0; ks < 2; ks++) {
    qh[ks] = *(const bf16x8*)(Qh + qbase + ks * 32 + quad * 8);
    ql[ks] = *(const bf16x8*)(Ql + qbase + ks * 32 + quad * 8);
  }

  f32x4 Oc[4];  // O^T: rows d (dt*16+quad*4+r), col q=ln
#pragma unroll
  for (int dt = 0; dt < 4; dt++) Oc[dt] = (f32x4){0.f, 0.f, 0.f, 0.f};
  float mprev = -1e30f, lrun = 0.f;  // per-lane (its q)

  // prologue: stage tile 0
  *(uint4*)((char*)KsH + wb0) = *(const uint4*)(gKh + (size_t)srow0 * cDH + scol);
  *(uint4*)((char*)KsH + wb1) = *(const uint4*)(gKh + (size_t)srow1 * cDH + scol);
  *(uint4*)((char*)KsL + wb0) = *(const uint4*)(gKl + (size_t)srow0 * cDH + scol);
  *(uint4*)((char*)KsL + wb1) = *(const uint4*)(gKl + (size_t)srow1 * cDH + scol);
  *(uint4*)((char*)VsH + wb0) = *(const uint4*)(gVh + (size_t)srow0 * cS + scol);
  *(uint4*)((char*)VsH + wb1) = *(const uint4*)(gVh + (size_t)srow1 * cS + scol);
  *(uint4*)((char*)VsL + wb0) = *(const uint4*)(gVl + (size_t)srow0 * cS + scol);
  *(uint4*)((char*)VsL + wb1) = *(const uint4*)(gVl + (size_t)srow1 * cS + scol);
  __syncthreads();

  for (int kt = 0; kt < cS / 64; kt++) {
    const int k0 = kt << 6;
    const bool more = (kt + 1) < (cS / 64);
    // ---- issue next tile's global loads (latency hides under compute) ----
    uint4 nkh0, nkh1, nkl0, nkl1, nvh0, nvh1, nvl0, nvl1;
    if (more) {
      const int kn = k0 + 64;
      nkh0 = *(const uint4*)(gKh + (size_t)(kn + srow0) * cDH + scol);
      nkh1 = *(const uint4*)(gKh + (size_t)(kn + srow1) * cDH + scol);
      nkl0 = *(const uint4*)(gKl + (size_t)(kn + srow0) * cDH + scol);
      nkl1 = *(const uint4*)(gKl + (size_t)(kn + srow1) * cDH + scol);
      nvh0 = *(const uint4*)(gVh + (size_t)srow0 * cS + kn + scol);
      nvh1 = *(const uint4*)(gVh + (size_t)srow1 * cS + kn + scol);
      nvl0 = *(const uint4*)(gVl + (size_t)srow0 * cS + kn + scol);
      nvl1 = *(const uint4*)(gVl + (size_t)srow1 * cS + kn + scol);
    }
    // ---- S^T = K Q^T (split 3-term). Lane: keys st*16+quad*4+r, q=ln ----
    float sf[4][4];
#pragma unroll
    for (int st = 0; st < 4; st++) {
      f32x4 acc = (f32x4){0.f, 0.f, 0.f, 0.f};
      const char* rH = (const char*)KsH + (st * 16 + ln) * 128;
      const char* rL = (const char*)KsL + (st * 16 + ln) * 128;
#pragma unroll
      for (int ks = 0; ks < 2; ks++) {
        const bf16x8 kh = *(const bf16x8*)(rH + kc[ks]);
        const bf16x8 kl = *(const bf16x8*)(rL + kc[ks]);
        acc = __builtin_amdgcn_mfma_f32_16x16x32_bf16(kh, qh[ks], acc, 0, 0, 0);
        acc = __builtin_amdgcn_mfma_f32_16x16x32_bf16(kl, qh[ks], acc, 0, 0, 0);
        acc = __builtin_amdgcn_mfma_f32_16x16x32_bf16(kh, ql[ks], acc, 0, 0, 0);
      }
      const float4 mkv = *(const float4*)(gM + k0 + st * 16 + quad * 4);
      sf[st][0] = acc[0] * SC2 + mkv.x;
      sf[st][1] = acc[1] * SC2 + mkv.y;
      sf[st][2] = acc[2] * SC2 + mkv.z;
      sf[st][3] = acc[3] * SC2 + mkv.w;
    }
    // ---- online softmax: one q per lane ----
    float vm = -1e30f;
#pragma unroll
    for (int st = 0; st < 4; st++)
#pragma unroll
      for (int r = 0; r < 4; r++) vm = fmaxf(vm, sf[st][r]);
    vm = fmaxf(vm, __shfl_xor(vm, 16, 64));
    vm = fmaxf(vm, __shfl_xor(vm, 32, 64));
    const float mnew = fmaxf(mprev, vm);
    const float alpha = exp2f(mprev - mnew);
    float rs = 0.f;
    // P packed directly into PV B-fragments (key permutation, verified v2)
    bf16x8 pbh[2], pbl[2];
#pragma unroll
    for (int st = 0; st < 4; st++) {
#pragma unroll
      for (int r = 0; r < 4; r++) {
        const float p = exp2f(sf[st][r] - mnew);
        rs += p;
        const unsigned short h16 = bf16_rne(p);
        pbh[st >> 1][(st & 1) * 4 + r] = (short)h16;
        pbl[st >> 1][(st & 1) * 4 + r] = (short)bf16_rne(p - bf16_f(h16));
      }
    }
    rs += __shfl_xor(rs, 16, 64);
    rs += __shfl_xor(rs, 32, 64);
    lrun = lrun * alpha + rs;
    mprev = mnew;
#pragma unroll
    for (int dt = 0; dt < 4; dt++) {
      Oc[dt][0] *= alpha;
      Oc[dt][1] *= alpha;
      Oc[dt][2] *= alpha;
      Oc[dt][3] *= alpha;
    }
    // ---- O^T += V^T P^T (split 3-term), V frags from swizzled LDS ----
#pragma unroll
    for (int dt = 0; dt < 4; dt++) {
      f32x4 acc = Oc[dt];
      const char* vH = (const char*)VsH + (dt * 16 + ln) * 128;
      const char* vL = (const char*)VsL + (dt * 16 + ln) * 128;
#pragma unroll
      for (int ks = 0; ks < 2; ks++) {
        const bf16x8 vh = cat44(*(const u16x4*)(vH + vc0[ks]),
                                *(const u16x4*)(vH + vc1[ks]));
        const bf16x8 vl = cat44(*(const u16x4*)(vL + vc0[ks]),
                                *(const u16x4*)(vL + vc1[ks]));
        acc = __builtin_amdgcn_mfma_f32_16x16x32_bf16(vh, pbh[ks], acc, 0, 0, 0);
        acc = __builtin_amdgcn_mfma_f32_16x16x32_bf16(vh, pbl[ks], acc, 0, 0, 0);
        acc = __builtin_amdgcn_mfma_f32_16x16x32_bf16(vl, pbh[ks], acc, 0, 0, 0);
      }
      Oc[dt] = acc;
    }
    __syncthreads();  // all waves done reading current tile
    if (more) {
      *(uint4*)((char*)KsH + wb0) = nkh0;
      *(uint4*)((char*)KsH + wb1) = nkh1;
      *(uint4*)((char*)KsL + wb0) = nkl0;
      *(uint4*)((char*)KsL + wb1) = nkl1;
      *(uint4*)((char*)VsH + wb0) = nvh0;
      *(uint4*)((char*)VsH + wb1) = nvh1;
      *(uint4*)((char*)VsL + wb0) = nvl0;
      *(uint4*)((char*)VsL + wb1) = nvl1;
      __syncthreads();  // next tile ready
    }
  }
  // ---- epilogue: normalize, split-bf16 store (u16x4 per dt) ----
  const float inv = 1.0f / lrun;
  const int tok = b * cS + q0 + wid * 16 + ln;
#pragma unroll
  for (int dt = 0; dt < 4; dt++) {
    u16x4 oh4, ol4;
#pragma unroll
    for (int r = 0; r < 4; r++) {
      const float v = Oc[dt][r] * inv;
      const unsigned short h16 = bf16_rne(v);
      oh4[r] = h16;
      ol4[r] = bf16_rne(v - bf16_f(h16));
    }
    const size_t idx = (size_t)tok * cD + h * cDH + dt * 16 + quad * 4;
    *(u16x4*)(Oh + idx) = oh4;
    *(u16x4*)(Ol + idx) = ol4;
  }
}

// ---------------------------------------------------------------------------
// Router (fp32 exact — feeds the discontinuous argmax).
// ---------------------------------------------------------------------------
__global__ __launch_bounds__(256) void router_kernel(
    const float* __restrict__ x2, const float* __restrict__ rw,
    const float* __restrict__ rb, const unsigned char* __restrict__ pad,
    float* __restrict__ gate, int* __restrict__ eidx, float* __restrict__ Psum,
    float* __restrict__ zsum) {
  __shared__ float Pacc[8];
  __shared__ float Zacc;
  if (threadIdx.x < 8) Pacc[threadIdx.x] = 0.f;
  if (threadIdx.x == 8) Zacc = 0.f;
  __syncthreads();
  const int tid = threadIdx.x, wid = tid >> 6, lane = tid & 63;
  const int e = lane & 7, dbase = lane >> 3;
  for (int tok = blockIdx.x * 4 + wid; tok < cN; tok += gridDim.x * 4) {
    const float* xr = x2 + (size_t)tok * cD;
    float partial = 0.f;
#pragma unroll 8
    for (int i = 0; i < cD / 8; i++) {
      const int d = dbase + i * 8;
      partial += xr[d] * rw[d * 8 + e];
    }
    partial += __shfl_xor(partial, 8, 64);
    partial += __shfl_xor(partial, 16, 64);
    partial += __shfl_xor(partial, 32, 64);
    const float logit = partial + rb[e];
    float mx = logit;
    mx = fmaxf(mx, __shfl_xor(mx, 1, 64));
    mx = fmaxf(mx, __shfl_xor(mx, 2, 64));
    mx = fmaxf(mx, __shfl_xor(mx, 4, 64));
    const float ex = __expf(logit - mx);
    float sm = ex;
    sm += __shfl_xor(sm, 1, 64);
    sm += __shfl_xor(sm, 2, 64);
    sm += __shfl_xor(sm, 4, 64);
    const float prob = ex / sm;
    float bv = logit;
    int bi = e;
#pragma unroll
    for (int m = 1; m < 8; m <<= 1) {
      const float ov = __shfl_xor(bv, m, 64);
      const int oi = __shfl_xor(bi, m, 64);
      if (ov > bv || (ov == bv && oi < bi)) {
        bv = ov;
        bi = oi;
      }
    }
    const float g = __shfl(prob, (lane & 0x38) | bi, 64);
    const bool valid = (pad[tok] == 0);
    if (lane == 0) {
      eidx[tok] = bi;
      gate[tok] = g;
    }
    if (valid) {
      if (lane < 8) atomicAdd(&Pacc[lane], prob);
      if (lane == 0) {
        const float lse = mx + logf(sm);
        atomicAdd(&Zacc, lse * lse);
      }
    }
  }
  __syncthreads();
  if (threadIdx.x < 8) atomicAdd(&Psum[threadIdx.x], Pacc[threadIdx.x]);
  if (threadIdx.x == 8) atomicAdd(zsum, Zacc);
}

// ---------------------------------------------------------------------------
// Capacity scan (unchanged).
// ---------------------------------------------------------------------------
__global__ __launch_bounds__(256) void scan_kernel(const int* __restrict__ eidx,
                                                   const unsigned char* __restrict__ pad,
                                                   int* __restrict__ slot,
                                                   int* __restrict__ counts) {
  __shared__ int cnt[256][8];
  const int t = threadIdx.x;
  int lc[8] = {0, 0, 0, 0, 0, 0, 0, 0};
  const int base = t * 32;
  for (int i = 0; i < 32; i++) {
    const int tok = base + i;
    if (!pad[tok]) lc[eidx[tok]]++;
  }
#pragma unroll
  for (int e2 = 0; e2 < 8; e2++) cnt[t][e2] = lc[e2];
  __syncthreads();
  if (t < 8) {
    int run = 0;
    for (int i = 0; i < 256; i++) {
      const int v = cnt[i][t];
      cnt[i][t] = run;
      run += v;
    }
    counts[t] = run;
  }
  __syncthreads();
  int off[8];
#pragma unroll
  for (int e2 = 0; e2 < 8; e2++) off[e2] = cnt[t][e2];
  for (int i = 0; i < 32; i++) {
    const int tok = base + i;
    if (!pad[tok]) {
      const int e2 = eidx[tok];
      const int p = off[e2]++;
      slot[tok] = (p < cCAP) ? (e2 * cCAP + p) : -1;
    } else {
      slot[tok] = -1;
    }
  }
}

__global__ __launch_bounds__(256) void dispatch_bf16_kernel(
    const float* __restrict__ x2, const int* __restrict__ slot,
    unsigned short* __restrict__ disp) {
  const int tok = blockIdx.x;
  const int s = slot[tok];
  if (s < 0) return;
  const float4 v = ((const float4*)(x2 + (size_t)tok * cD))[threadIdx.x];
  u16x4 o;
  o[0] = bf16_rne(v.x);
  o[1] = bf16_rne(v.y);
  o[2] = bf16_rne(v.z);
  o[3] = bf16_rne(v.w);
  *(u16x4*)(disp + (size_t)s * cD + threadIdx.x * 4) = o;
}

__global__ __launch_bounds__(256) void gather_kernel(const float* __restrict__ src1,
                                                     const float* __restrict__ o,
                                                     const int* __restrict__ slot,
                                                     const float* __restrict__ gate,
                                                     float* __restrict__ out) {
  const int tok = blockIdx.x;
  float4 r = ((const float4*)(src1 + (size_t)tok * cD))[threadIdx.x];
  const int s = slot[tok];
  if (s >= 0) {
    const float g = gate[tok];
    const float4 ov = ((const float4*)(o + (size_t)s * cD))[threadIdx.x];
    r.x += g * ov.x;
    r.y += g * ov.y;
    r.z += g * ov.z;
    r.w += g * ov.w;
  }
  ((float4*)(out + (size_t)tok * cD))[threadIdx.x] = r;
}

__global__ void loss_kernel(const int* __restrict__ counts,
                            const float* __restrict__ Psum,
                            const float* __restrict__ zsum,
                            float* __restrict__ out) {
  if (threadIdx.x == 0) {
    int tot = 0;
    for (int e2 = 0; e2 < 8; e2++) tot += counts[e2];
    const float denom = fmaxf((float)tot, 1.0f);
    float lp = 0.f;
    for (int e2 = 0; e2 < 8; e2++)
      lp += ((float)counts[e2] / denom) * (Psum[e2] / denom);
    out[0] = 8.0f * lp;
    out[1] = zsum[0] / denom;
  }
}

// ---------------------------------------------------------------------------
// Workspace layout (float units), sequential lifetimes:
// R_A: w1t bf16 (->FFN1) / w2t bf16 (->FFN2)   (qkv fp32 no longer exists)
// R_B: Q..Vt splits (QKV gemm->attn) / h bf16 (FFN1->FFN2)
// R_XHL: xh+xl (LN1->QKV) / Oh+Ol (attn->out_proj) / disp bf16 (->FFN1)
// R_X2O: mkf (padmask->attn) / x2 (LN2->dispatch) / obuf fp32 (FFN2->gather)
// ---------------------------------------------------------------------------
constexpr size_t OFF_A = 0;              // 25,165,824 floats
constexpr size_t OFF_B = 25165824;       // 25,165,824
constexpr size_t OFF_XHL = 50331648;     // 8,388,608
constexpr size_t OFF_SRC1 = 58720256;    // 8,388,608
constexpr size_t OFF_X2O = 67108864;     // 10,485,760
constexpr size_t OFF_IPW = 77594624;     // 3,145,728
constexpr size_t OFF_OPW = 80740352;     // 1,048,576
constexpr size_t OFF_MISC = 81788928;

extern "C" void kernel_launch(void* const* d_in, const int* in_sizes, int n_in,
                              void* d_out, int out_size, void* d_ws, size_t ws_size,
                              hipStream_t stream) {
  (void)in_sizes; (void)n_in; (void)out_size; (void)ws_size;
  const float* src = (const float*)d_in[0];
  const unsigned char* pad = (const unsigned char*)d_in[1];
  const float* ln1_g = (const float*)d_in[2];
  const float* ln1_b = (const float*)d_in[3];
  const float* in_proj_w = (const float*)d_in[4];
  const float* in_proj_b = (const float*)d_in[5];
  const float* out_proj_w = (const float*)d_in[6];
  const float* out_proj_b = (const float*)d_in[7];
  const float* ln2_g = (const float*)d_in[8];
  const float* ln2_b = (const float*)d_in[9];
  const float* router_w = (const float*)d_in[10];
  const float* router_b = (const float*)d_in[11];
  const float* w1 = (const float*)d_in[12];
  const float* b1 = (const float*)d_in[13];
  const float* w2 = (const float*)d_in[14];
  const float* b2 = (const float*)d_in[15];
  float* out = (float*)d_out;
  float* w = (float*)d_ws;

  unsigned short* w1t = (unsigned short*)(w + OFF_A);
  unsigned short* w2t = (unsigned short*)(w + OFF_A);   // after w1t dead
  unsigned short* usB = (unsigned short*)(w + OFF_B);
  constexpr size_t SPN = (size_t)cN * cD;               // 8,388,608 u16
  unsigned short* Qh = usB + 0 * SPN;
  unsigned short* Ql = usB + 1 * SPN;
  unsigned short* Kh = usB + 2 * SPN;
  unsigned short* Kl = usB + 3 * SPN;
  unsigned short* Vth = usB + 4 * SPN;
  unsigned short* Vtl = usB + 5 * SPN;
  unsigned short* hbuf16 = usB;                          // after splits dead
  unsigned short* xh = (unsigned short*)(w + OFF_XHL);
  unsigned short* xl = xh + SPN;
  unsigned short* Oh = xh;                               // after xh/xl dead
  unsigned short* Ol = xh + SPN;
  unsigned short* disp16 = xh;                           // after Oh/Ol dead
  float* src1 = w + OFF_SRC1;
  float* mkf = w + OFF_X2O;                              // dead before x2 written
  float* x2 = w + OFF_X2O;
  float* obuf = w + OFF_X2O;                             // after x2 dead
  unsigned short* ipwh = (unsigned short*)(w + OFF_IPW);
  unsigned short* ipwl = ipwh + (size_t)3 * cD * cD;
  unsigned short* opwh = (unsigned short*)(w + OFF_OPW);
  unsigned short* opwl = opwh + (size_t)cD * cD;
  float* gate = w + OFF_MISC;
  int* eidx = (int*)(w + OFF_MISC + 8192);
  int* slot = (int*)(w + OFF_MISC + 16384);
  float* Psum = w + OFF_MISC + 24576;
  float* zsum = Psum + 8;
  int* counts = (int*)(Psum + 16);

  hipMemsetAsync(Psum, 0, 9 * sizeof(float), stream);

  // 1) LN1 -> split bf16
  ln_split_kernel<<<cN, 256, 0, stream>>>(src, ln1_g, ln1_b, xh, xl);
  // 1.2) pad mask -> float additive mask (read by attn as float4)
  padmask_kernel<<<cN / 256, 256, 0, stream>>>(pad, mkf);
  // 1.5) weight splits
  wsplit_kernel<<<3072, 256, 0, stream>>>(in_proj_w, ipwh, ipwl, 786432);
  wsplit_kernel<<<1024, 256, 0, stream>>>(out_proj_w, opwh, opwl, 262144);
  // 2) QKV projection (split 3-term) with FUSED qkv-split epilogue
  gemm_bf16<true, false, false, 2><<<dim3(24, 64, 1), 256, 0, stream>>>(
      xh, xl, 0, ipwh, ipwl, 0, in_proj_b, 0, nullptr, nullptr, 0,
      cD, cD, cD, 0, Qh, Ql, Kh, Kl, Vth, Vtl);
  // 2.5) w1 transpose+convert: [e][d][f] -> [e][f][d] bf16
  transpose_bf16_kernel<<<dim3(64, 16, 8), 256, 0, stream>>>(w1, w1t, cD, cF);
  // 3) MFMA flash attention (LDS-staged, swizzled, async prefetch) -> Oh/Ol
  attn_mfma_kernel<<<dim3(cS / 64, cH, cB), 256, 0, stream>>>(
      Qh, Ql, Kh, Kl, Vth, Vtl, mkf, Oh, Ol);
  // 4) out_proj (split 3-term) + residual(src) -> src1 fp32
  gemm_bf16<true, false, true, 0><<<dim3(8, 64, 1), 256, 0, stream>>>(
      Oh, Ol, 0, opwh, opwl, 0, out_proj_b, 0, src, src1, 0,
      cD, cD, cD, cD, nullptr, nullptr, nullptr, nullptr, nullptr, nullptr);
  // 5) LN2 (fp32 exact)
  ln_kernel<<<cN, 256, 0, stream>>>(src1, ln2_g, ln2_b, x2);
  // 6) router
  router_kernel<<<256, 256, 0, stream>>>(x2, router_w, router_b, pad, gate, eidx,
                                         Psum, zsum);
  // 7) capacity scan
  scan_kernel<<<1, 256, 0, stream>>>(eidx, pad, slot, counts);
  // 8) dispatch scatter -> bf16
  dispatch_bf16_kernel<<<cN, 256, 0, stream>>>(x2, slot, disp16);
  // 9) FFN1: relu(disp @ w1 + b1) -> h bf16 (plain bf16 MFMA)
  gemm_bf16<false, true, false, 1><<<dim3(32, 10, 8), 256, 0, stream>>>(
      disp16, nullptr, (size_t)cCAP * cD, w1t, nullptr, (size_t)cD * cF,
      b1, cF, nullptr, hbuf16, (size_t)cCAP * cF, cD, cD, cD, cF,
      nullptr, nullptr, nullptr, nullptr, nullptr, nullptr);
  // 9.5) w2 transpose+convert: [e][f][d] -> [e][d][f] bf16 (w1t dead)
  transpose_bf16_kernel<<<dim3(16, 64, 8), 256, 0, stream>>>(w2, w2t, cF, cD);
  // 10) FFN2: h @ w2 + b2 -> obuf fp32
  gemm_bf16<false, false, false, 0><<<dim3(8, 10, 8), 256, 0, stream>>>(
      hbuf16, nullptr, (size_t)cCAP * cF, w2t, nullptr, (size_t)cF * cD,
      b2, cD, nullptr, obuf, (size_t)cCAP * cD, cF, cF, cF, cD,
      nullptr, nullptr, nullptr, nullptr, nullptr, nullptr);
  // 11) gather + residual -> out
  gather_kernel<<<cN, 256, 0, stream>>>(src1, obuf, slot, gate, out);
  // 12) losses
  loss_kernel<<<1, 64, 0, stream>>>(counts, Psum, zsum, out + (size_t)cN * cD);
}

// Round 3
// 1427.411 us; speedup vs baseline: 1.6607x; 1.1065x over previous
//
#include <hip/hip_runtime.h>

// Problem constants
constexpr int cB = 4, cS = 2048, cD = 1024, cH = 16, cE = 8, cF = 4096;
constexpr int cN = cB * cS;          // 8192 tokens
constexpr int cDH = 64;
constexpr int cCAP = 1280;           // int(1.25 * 8192 / 8)

typedef __attribute__((ext_vector_type(8))) short bf16x8;
typedef __attribute__((ext_vector_type(4))) float f32x4;
typedef __attribute__((ext_vector_type(4))) unsigned short u16x4;
typedef __attribute__((ext_vector_type(4))) unsigned int u32x4;

__device__ inline unsigned short bf16_rne(float x) {
  unsigned u = __float_as_uint(x);
  u += 0x7FFF + ((u >> 16) & 1);
  return (unsigned short)(u >> 16);
}
__device__ inline float bf16_f(unsigned short h) {
  return __uint_as_float(((unsigned)h) << 16);
}
// packed RNE f32x2 -> bf16x2 (hardware cvt; same RNE as bf16_rne)
__device__ inline unsigned cvt_pk_bf16(float a, float b) {
  unsigned r;
  asm("v_cvt_pk_bf16_f32 %0, %1, %2" : "=v"(r) : "v"(a), "v"(b));
  return r;
}

// ---------------------------------------------------------------------------
// LayerNorm fp32 (LN2): one block per token.
// ---------------------------------------------------------------------------
__global__ __launch_bounds__(256) void ln_kernel(const float* __restrict__ x,
                                                 const float* __restrict__ g,
                                                 const float* __restrict__ bb,
                                                 float* __restrict__ y) {
  __shared__ float red[8];
  const int row = blockIdx.x;
  const int t = threadIdx.x;
  const float4 v = ((const float4*)(x + (size_t)row * cD))[t];
  float s = v.x + v.y + v.z + v.w;
#pragma unroll
  for (int m = 32; m >= 1; m >>= 1) s += __shfl_xor(s, m, 64);
  if ((t & 63) == 0) red[t >> 6] = s;
  __syncthreads();
  const float mean = (red[0] + red[1] + red[2] + red[3]) * (1.0f / cD);
  const float dx = v.x - mean, dy = v.y - mean, dz = v.z - mean, dw = v.w - mean;
  float ss = dx * dx + dy * dy + dz * dz + dw * dw;
#pragma unroll
  for (int m = 32; m >= 1; m >>= 1) ss += __shfl_xor(ss, m, 64);
  if ((t & 63) == 0) red[4 + (t >> 6)] = ss;
  __syncthreads();
  const float var = (red[4] + red[5] + red[6] + red[7]) * (1.0f / cD);
  const float inv = rsqrtf(var + 1e-5f);
  const float4 gg = ((const float4*)g)[t];
  const float4 b4 = ((const float4*)bb)[t];
  float4 o;
  o.x = dx * inv * gg.x + b4.x;
  o.y = dy * inv * gg.y + b4.y;
  o.z = dz * inv * gg.z + b4.z;
  o.w = dw * inv * gg.w + b4.w;
  ((float4*)(y + (size_t)row * cD))[t] = o;
}

// ---------------------------------------------------------------------------
// LayerNorm with split-bf16 output (LN1 -> QKV GEMM A operand).
// ---------------------------------------------------------------------------
__global__ __launch_bounds__(256) void ln_split_kernel(
    const float* __restrict__ x, const float* __restrict__ g,
    const float* __restrict__ bb, unsigned short* __restrict__ yh,
    unsigned short* __restrict__ yl) {
  __shared__ float red[8];
  const int row = blockIdx.x;
  const int t = threadIdx.x;
  const float4 v = ((const float4*)(x + (size_t)row * cD))[t];
  float s = v.x + v.y + v.z + v.w;
#pragma unroll
  for (int m = 32; m >= 1; m >>= 1) s += __shfl_xor(s, m, 64);
  if ((t & 63) == 0) red[t >> 6] = s;
  __syncthreads();
  const float mean = (red[0] + red[1] + red[2] + red[3]) * (1.0f / cD);
  const float dx = v.x - mean, dy = v.y - mean, dz = v.z - mean, dw = v.w - mean;
  float ss = dx * dx + dy * dy + dz * dz + dw * dw;
#pragma unroll
  for (int m = 32; m >= 1; m >>= 1) ss += __shfl_xor(ss, m, 64);
  if ((t & 63) == 0) red[4 + (t >> 6)] = ss;
  __syncthreads();
  const float var = (red[4] + red[5] + red[6] + red[7]) * (1.0f / cD);
  const float inv = rsqrtf(var + 1e-5f);
  const float4 gg = ((const float4*)g)[t];
  const float4 b4 = ((const float4*)bb)[t];
  const float oa[4] = {dx * inv * gg.x + b4.x, dy * inv * gg.y + b4.y,
                       dz * inv * gg.z + b4.z, dw * inv * gg.w + b4.w};
  u16x4 hh, ll;
#pragma unroll
  for (int i = 0; i < 4; i++) {
    const unsigned short h16 = bf16_rne(oa[i]);
    hh[i] = h16;
    ll[i] = bf16_rne(oa[i] - bf16_f(h16));
  }
  *(u16x4*)(yh + (size_t)row * cD + t * 4) = hh;
  *(u16x4*)(yl + (size_t)row * cD + t * 4) = ll;
}

// ---------------------------------------------------------------------------
// Weight split: fp32 -> bf16 hi/lo, same layout. n4 = element_count/4.
// ---------------------------------------------------------------------------
__global__ __launch_bounds__(256) void wsplit_kernel(const float* __restrict__ in,
                                                     unsigned short* __restrict__ hi,
                                                     unsigned short* __restrict__ lo,
                                                     int n4) {
  const int i = blockIdx.x * 256 + threadIdx.x;
  if (i >= n4) return;
  const float4 v = ((const float4*)in)[i];
  const float a[4] = {v.x, v.y, v.z, v.w};
  u16x4 hh, ll;
#pragma unroll
  for (int j = 0; j < 4; j++) {
    const unsigned short h16 = bf16_rne(a[j]);
    hh[j] = h16;
    ll[j] = bf16_rne(a[j] - bf16_f(h16));
  }
  *(u16x4*)(hi + (size_t)i * 4) = hh;
  *(u16x4*)(lo + (size_t)i * 4) = ll;
}

// ---------------------------------------------------------------------------
// Pad mask precompute: byte -> float (-1e30 for pad, 0 otherwise).
// ---------------------------------------------------------------------------
__global__ __launch_bounds__(256) void padmask_kernel(
    const unsigned char* __restrict__ pad, float* __restrict__ mkf) {
  const int i = blockIdx.x * 256 + threadIdx.x;
  mkf[i] = pad[i] ? -1e30f : 0.0f;
}

// ---------------------------------------------------------------------------
// Transpose + bf16 convert: in fp32 [z][R][C] -> out bf16 [z][C][R].
// ---------------------------------------------------------------------------
__global__ __launch_bounds__(256) void transpose_bf16_kernel(
    const float* __restrict__ in, unsigned short* __restrict__ outp, int Rr,
    int Cc) {
  __shared__ float T[64][65];
  const int z = blockIdx.z;
  in += (size_t)z * Rr * Cc;
  outp += (size_t)z * Rr * Cc;
  const int c0 = blockIdx.x * 64, r0 = blockIdx.y * 64;
  const int tid = threadIdx.x;
#pragma unroll
  for (int u = 0; u < 4; u++) {
    const int a = tid + u * 256;
    const int r = a >> 4, c4 = (a & 15) << 2;
    const float4 v = *(const float4*)(in + (size_t)(r0 + r) * Cc + c0 + c4);
    T[r][c4 + 0] = v.x;
    T[r][c4 + 1] = v.y;
    T[r][c4 + 2] = v.z;
    T[r][c4 + 3] = v.w;
  }
  __syncthreads();
#pragma unroll
  for (int u = 0; u < 4; u++) {
    const int a = tid + u * 256;
    const int c = a >> 4, r4 = (a & 15) << 2;
    u16x4 o;
#pragma unroll
    for (int i = 0; i < 4; i++) o[i] = bf16_rne(T[r4 + i][c]);
    *(u16x4*)(outp + (size_t)(c0 + c) * Rr + r0 + r4) = o;
  }
}

// ---------------------------------------------------------------------------
// bf16 MFMA GEMM: C[M,N] = A[M,K] * B[N,K]^T + bias.
// OUT: 0 = fp32 C (+RELU/+RESID), 1 = bf16 C, 2 = fused QKV-split epilogue
// (writes Qh/Ql/Kh/Kl [b,h,s,d] and Vth/Vtl [b,h,d,s] split-bf16 directly).
// 128x128 tile, BK=32, 4 waves x (4x4 of 16x16x32 MFMA), LDS stride 40 u16.
// ---------------------------------------------------------------------------
template <bool SPLIT, bool RELU, bool RESID, int OUT>
__global__ __launch_bounds__(256) void gemm_bf16(
    const unsigned short* __restrict__ Ah, const unsigned short* __restrict__ Al,
    size_t sA,
    const unsigned short* __restrict__ Bh, const unsigned short* __restrict__ Bl,
    size_t sB,
    const float* __restrict__ bias, size_t sBias,
    const float* __restrict__ R,
    void* __restrict__ Cv, size_t sC,
    int K, int lda, int ldb, int ldc,
    unsigned short* __restrict__ Qh, unsigned short* __restrict__ Ql,
    unsigned short* __restrict__ Kh, unsigned short* __restrict__ Kl,
    unsigned short* __restrict__ Vth, unsigned short* __restrict__ Vtl) {
  __shared__ unsigned short AsH[128 * 40];
  __shared__ unsigned short BsH[128 * 40];
  __shared__ unsigned short AsL[SPLIT ? 128 * 40 : 8];
  __shared__ unsigned short BsL[SPLIT ? 128 * 40 : 8];
  const int z = blockIdx.z;
  Ah += (size_t)z * sA;
  Bh += (size_t)z * sB;
  if constexpr (SPLIT) {
    Al += (size_t)z * sA;
    Bl += (size_t)z * sB;
  }
  bias += (size_t)z * sBias;
  const int n0 = blockIdx.x * 128, m0 = blockIdx.y * 128;
  const int tid = threadIdx.x;
  const int wid = tid >> 6, lane = tid & 63;
  const int ln = lane & 15, quad = lane >> 4;
  const int wm = (wid >> 1) * 64, wn = (wid & 1) * 64;

  f32x4 acc[4][4];
#pragma unroll
  for (int i = 0; i < 4; i++)
#pragma unroll
    for (int j = 0; j < 4; j++) acc[i][j] = (f32x4){0.f, 0.f, 0.f, 0.f};

  for (int k0 = 0; k0 < K; k0 += 32) {
    __syncthreads();
#pragma unroll
    for (int u = 0; u < 2; u++) {
      const int c = tid + u * 256;           // 0..511
      const int row = c >> 2, ko = (c & 3) << 3;
      const int ld = row * 40 + ko;
      *(uint4*)&AsH[ld] = *(const uint4*)(Ah + (size_t)(m0 + row) * lda + k0 + ko);
      *(uint4*)&BsH[ld] = *(const uint4*)(Bh + (size_t)(n0 + row) * ldb + k0 + ko);
      if constexpr (SPLIT) {
        *(uint4*)&AsL[ld] = *(const uint4*)(Al + (size_t)(m0 + row) * lda + k0 + ko);
        *(uint4*)&BsL[ld] = *(const uint4*)(Bl + (size_t)(n0 + row) * ldb + k0 + ko);
      }
    }
    __syncthreads();
    bf16x8 bh[4], bl[4];
#pragma unroll
    for (int nt = 0; nt < 4; nt++) {
      bh[nt] = *(const bf16x8*)&BsH[(wn + nt * 16 + ln) * 40 + quad * 8];
      if constexpr (SPLIT)
        bl[nt] = *(const bf16x8*)&BsL[(wn + nt * 16 + ln) * 40 + quad * 8];
    }
#pragma unroll
    for (int mt = 0; mt < 4; mt++) {
      const bf16x8 ah = *(const bf16x8*)&AsH[(wm + mt * 16 + ln) * 40 + quad * 8];
      bf16x8 al;
      if constexpr (SPLIT)
        al = *(const bf16x8*)&AsL[(wm + mt * 16 + ln) * 40 + quad * 8];
#pragma unroll
      for (int nt = 0; nt < 4; nt++) {
        acc[mt][nt] =
            __builtin_amdgcn_mfma_f32_16x16x32_bf16(ah, bh[nt], acc[mt][nt], 0, 0, 0);
        if constexpr (SPLIT) {
          acc[mt][nt] =
              __builtin_amdgcn_mfma_f32_16x16x32_bf16(al, bh[nt], acc[mt][nt], 0, 0, 0);
          acc[mt][nt] =
              __builtin_amdgcn_mfma_f32_16x16x32_bf16(ah, bl[nt], acc[mt][nt], 0, 0, 0);
        }
      }
    }
  }
  // ---- epilogue ----
  if constexpr (OUT == 2) {
    // fused QKV split: col -> (sec,h,d); row -> (b,s). sec/h wave-uniform.
#pragma unroll
    for (int mt = 0; mt < 4; mt++) {
      const int row0 = m0 + wm + mt * 16 + quad * 4;
      const int b_ = row0 >> 11, s0_ = row0 & 2047;
      const size_t bbase = (size_t)b_ * cH * cS * cDH;
#pragma unroll
      for (int nt = 0; nt < 4; nt++) {
        const int col = n0 + wn + nt * 16 + ln;
        const float bv = bias[col];
        const int sec = col >> 10;
        const int f = col & 1023;
        const int hh = f >> 6, d = f & 63;
        const size_t bh_off = bbase + (size_t)hh * cS * cDH;
        float vals[4];
#pragma unroll
        for (int r = 0; r < 4; r++) vals[r] = acc[mt][nt][r] + bv;
        if (sec == 2) {
          u16x4 hi4, lo4;
#pragma unroll
          for (int r = 0; r < 4; r++) {
            const unsigned short h16 = bf16_rne(vals[r]);
            hi4[r] = h16;
            lo4[r] = bf16_rne(vals[r] - bf16_f(h16));
          }
          const size_t idx = bh_off + (size_t)d * cS + s0_;
          *(u16x4*)(Vth + idx) = hi4;
          *(u16x4*)(Vtl + idx) = lo4;
        } else {
          unsigned short* dsth = (sec == 0) ? Qh : Kh;
          unsigned short* dstl = (sec == 0) ? Ql : Kl;
#pragma unroll
          for (int r = 0; r < 4; r++) {
            const unsigned short h16 = bf16_rne(vals[r]);
            const size_t idx = bh_off + (size_t)(s0_ + r) * cDH + d;
            dsth[idx] = h16;
            dstl[idx] = bf16_rne(vals[r] - bf16_f(h16));
          }
        }
      }
    }
  } else {
    float* Cf = nullptr;
    unsigned short* Cb = nullptr;
    if constexpr (OUT == 1)
      Cb = (unsigned short*)Cv + (size_t)z * sC;
    else
      Cf = (float*)Cv + (size_t)z * sC;
#pragma unroll
    for (int mt = 0; mt < 4; mt++) {
#pragma unroll
      for (int nt = 0; nt < 4; nt++) {
        const int col = n0 + wn + nt * 16 + ln;
        const float bv = bias[col];
#pragma unroll
        for (int r = 0; r < 4; r++) {
          const int row = m0 + wm + mt * 16 + quad * 4 + r;
          float v = acc[mt][nt][r] + bv;
          if constexpr (RELU) v = fmaxf(v, 0.f);
          if constexpr (RESID) v += R[(size_t)row * ldc + col];
          if constexpr (OUT == 1)
            Cb[(size_t)row * ldc + col] = bf16_rne(v);
          else
            Cf[(size_t)row * ldc + col] = v;
        }
      }
    }
  }
}

// ---------------------------------------------------------------------------
// Flash attention v4:
//   * LDS-staged K/V (32KB, XOR-swizzled byte ^= (row&7)<<4) for cross-wave
//     sharing + TLP (4-5 blocks/CU); stage-at-top, 2 barriers/iter (v1
//     structure — latency hidden across co-resident blocks, not in-VGPR).
//   * V LDS layout stores the PV key-permutation (kappa) at staging time:
//     within each 32-key half, 8B chunk c -> slot ((c&3)<<1)|(c>>2), so the
//     V A-fragment is ONE b128 read (no cat44 repacking).
//   * P stays in registers (key-permuted fragments, verified v2/v3); packed
//     hi/lo via v_cvt_pk_bf16_f32 (2 vals/inst, RNE == bf16_rne).
//   * defer-max (THR=8): skip cross-quad max shuffles + alpha rescale when
//     __all(vm <= mprev+8); row-sum kept as per-lane partial, reduced once
//     in the epilogue (alpha is quad-uniform so partials stay consistent).
// ---------------------------------------------------------------------------
__global__ __launch_bounds__(256) void attn_mfma_kernel(
    const unsigned short* __restrict__ Qh, const unsigned short* __restrict__ Ql,
    const unsigned short* __restrict__ Kh, const unsigned short* __restrict__ Kl,
    const unsigned short* __restrict__ Vth, const unsigned short* __restrict__ Vtl,
    const float* __restrict__ mkf, unsigned short* __restrict__ Oh,
    unsigned short* __restrict__ Ol) {
  __shared__ alignas(16) unsigned short KsH[64 * 64];
  __shared__ alignas(16) unsigned short KsL[64 * 64];
  __shared__ alignas(16) unsigned short VsH[64 * 64];
  __shared__ alignas(16) unsigned short VsL[64 * 64];

  const int q0 = blockIdx.x << 6;
  const int h = blockIdx.y, b = blockIdx.z;
  const int tid = threadIdx.x;
  const int wid = tid >> 6, lane = tid & 63;
  const int ln = lane & 15, quad = lane >> 4;
  constexpr float SC2 = 0.125f * 1.4426950408889634f;  // 1/sqrt(64) * log2(e)

  const size_t bh = (size_t)(b * cH + h);
  const unsigned short* gKh = Kh + bh * cS * cDH;
  const unsigned short* gKl = Kl + bh * cS * cDH;
  const unsigned short* gVh = Vth + bh * cDH * cS;
  const unsigned short* gVl = Vtl + bh * cDH * cS;
  const float* gM = mkf + (size_t)b * cS;

  // ---- staging map: thread covers rows tid>>3 and +32, one 16B chunk ----
  const int t8 = tid & 7;                 // 16B chunk index (src)
  const int srow0 = tid >> 3;             // 0..31
  const int srow1 = srow0 + 32;
  const int xw0 = (srow0 & 7) << 4, xw1 = (srow1 & 7) << 4;
  const int wbK0 = srow0 * 128 + ((t8 << 4) ^ xw0);
  const int wbK1 = srow1 * 128 + ((t8 << 4) ^ xw1);
  // V permuted slots: half h6, within-half chunk pair (2u,2u+1) -> slots
  // A(u)=((u&1)<<2)|(u>>1), B(u)=A(u)+2   (8B granularity)
  const int h6 = (t8 >> 2) << 6;
  const int uu = t8 & 3;
  const int pA = h6 + ((((uu & 1) << 2) | (uu >> 1)) << 3);
  const int pB = pA + 16;
  const int wbVA0 = srow0 * 128 + (pA ^ xw0);
  const int wbVB0 = srow0 * 128 + (pB ^ xw0);
  const int wbVA1 = srow1 * 128 + (pA ^ xw1);
  const int wbVB1 = srow1 * 128 + (pB ^ xw1);

  // per-lane swizzled read byte offsets (same pattern for K and permuted V)
  const int xs = (ln & 7) << 4;
  const int fc[2] = {(quad * 16) ^ xs, (quad * 16 + 64) ^ xs};

  // Q fragment (B-operand): lane q = ln, k = quad*8+j
  const size_t qbase = (bh * cS + q0 + wid * 16 + ln) * cDH;
  bf16x8 qh[2], ql[2];
#pragma unroll
  for (int ks = 0; ks < 2; ks++) {
    qh[ks] = *(const bf16x8*)(Qh + qbase + ks * 32 + quad * 8);
    ql[ks] = *(const bf16x8*)(Ql + qbase + ks * 32 + quad * 8);
  }

  f32x4 Oc[4];  // O^T: rows d (dt*16+quad*4+r), col q=ln
#pragma unroll
  for (int dt = 0; dt < 4; dt++) Oc[dt] = (f32x4){0.f, 0.f, 0.f, 0.f};
  float mprev = -1e30f, lrun = 0.f;  // per-lane; lrun is a per-quad PARTIAL

  for (int kt = 0; kt < cS / 64; kt++) {
    const int k0 = kt << 6;
    // ---- stage tile kt (prev compute finished at loop-bottom barrier) ----
    {
      const size_t kr0 = (size_t)(k0 + srow0) * cDH + (t8 << 3);
      const size_t kr1 = (size_t)(k0 + srow1) * cDH + (t8 << 3);
      *(uint4*)((char*)KsH + wbK0) = *(const uint4*)(gKh + kr0);
      *(uint4*)((char*)KsH + wbK1) = *(const uint4*)(gKh + kr1);
      *(uint4*)((char*)KsL + wbK0) = *(const uint4*)(gKl + kr0);
      *(uint4*)((char*)KsL + wbK1) = *(const uint4*)(gKl + kr1);
      const size_t vr0 = (size_t)srow0 * cS + k0 + (t8 << 3);
      const size_t vr1 = (size_t)srow1 * cS + k0 + (t8 << 3);
      const uint4 a = *(const uint4*)(gVh + vr0);
      const uint4 b2 = *(const uint4*)(gVh + vr1);
      const uint4 c = *(const uint4*)(gVl + vr0);
      const uint4 d = *(const uint4*)(gVl + vr1);
      uint2 t;
      t.x = a.x;  t.y = a.y;  *(uint2*)((char*)VsH + wbVA0) = t;
      t.x = a.z;  t.y = a.w;  *(uint2*)((char*)VsH + wbVB0) = t;
      t.x = b2.x; t.y = b2.y; *(uint2*)((char*)VsH + wbVA1) = t;
      t.x = b2.z; t.y = b2.w; *(uint2*)((char*)VsH + wbVB1) = t;
      t.x = c.x;  t.y = c.y;  *(uint2*)((char*)VsL + wbVA0) = t;
      t.x = c.z;  t.y = c.w;  *(uint2*)((char*)VsL + wbVB0) = t;
      t.x = d.x;  t.y = d.y;  *(uint2*)((char*)VsL + wbVA1) = t;
      t.x = d.z;  t.y = d.w;  *(uint2*)((char*)VsL + wbVB1) = t;
    }
    __syncthreads();

    // ---- S^T = K Q^T (split 3-term). Lane: keys st*16+quad*4+r, q=ln ----
    float sf[4][4];
#pragma unroll
    for (int st = 0; st < 4; st++) {
      f32x4 acc = (f32x4){0.f, 0.f, 0.f, 0.f};
      const char* rH = (const char*)KsH + (st * 16 + ln) * 128;
      const char* rL = (const char*)KsL + (st * 16 + ln) * 128;
#pragma unroll
      for (int ks = 0; ks < 2; ks++) {
        const bf16x8 kh = *(const bf16x8*)(rH + fc[ks]);
        const bf16x8 kl = *(const bf16x8*)(rL + fc[ks]);
        acc = __builtin_amdgcn_mfma_f32_16x16x32_bf16(kh, qh[ks], acc, 0, 0, 0);
        acc = __builtin_amdgcn_mfma_f32_16x16x32_bf16(kl, qh[ks], acc, 0, 0, 0);
        acc = __builtin_amdgcn_mfma_f32_16x16x32_bf16(kh, ql[ks], acc, 0, 0, 0);
      }
      const float4 mkv = *(const float4*)(gM + k0 + st * 16 + quad * 4);
      sf[st][0] = acc[0] * SC2 + mkv.x;
      sf[st][1] = acc[1] * SC2 + mkv.y;
      sf[st][2] = acc[2] * SC2 + mkv.z;
      sf[st][3] = acc[3] * SC2 + mkv.w;
    }
    // ---- online softmax with defer-max (THR=8) ----
    float vm = sf[0][0];
#pragma unroll
    for (int st = 0; st < 4; st++)
#pragma unroll
      for (int r = 0; r < 4; r++) vm = fmaxf(vm, sf[st][r]);
    if (!__all(vm <= mprev + 8.0f)) {
      float vmr = fmaxf(vm, __shfl_xor(vm, 16, 64));
      vmr = fmaxf(vmr, __shfl_xor(vmr, 32, 64));
      const float mnew = fmaxf(mprev, vmr);
      const float alpha = exp2f(mprev - mnew);
      lrun *= alpha;
#pragma unroll
      for (int dt = 0; dt < 4; dt++) {
        Oc[dt][0] *= alpha;
        Oc[dt][1] *= alpha;
        Oc[dt][2] *= alpha;
        Oc[dt][3] *= alpha;
      }
      mprev = mnew;
    }
    // P -> packed bf16 hi/lo fragments via cvt_pk (key-permuted layout)
    u32x4 ph[2], pl[2];
    float rs = 0.f;
#pragma unroll
    for (int st = 0; st < 4; st++) {
#pragma unroll
      for (int rp = 0; rp < 2; rp++) {
        const float p0 = exp2f(sf[st][2 * rp] - mprev);
        const float p1 = exp2f(sf[st][2 * rp + 1] - mprev);
        rs += p0 + p1;
        const unsigned wh = cvt_pk_bf16(p0, p1);
        const float f0 = __uint_as_float(wh << 16);
        const float f1 = __uint_as_float(wh & 0xFFFF0000u);
        const unsigned wl = cvt_pk_bf16(p0 - f0, p1 - f1);
        ph[st >> 1][(st & 1) * 2 + rp] = wh;
        pl[st >> 1][(st & 1) * 2 + rp] = wl;
      }
    }
    lrun += rs;
    const bf16x8 pbh[2] = {__builtin_bit_cast(bf16x8, ph[0]),
                           __builtin_bit_cast(bf16x8, ph[1])};
    const bf16x8 pbl[2] = {__builtin_bit_cast(bf16x8, pl[0]),
                           __builtin_bit_cast(bf16x8, pl[1])};
    // ---- O^T += V^T P^T (split 3-term); V frag = one b128 (permuted) ----
#pragma unroll
    for (int dt = 0; dt < 4; dt++) {
      f32x4 acc = Oc[dt];
      const char* vH = (const char*)VsH + (dt * 16 + ln) * 128;
      const char* vL = (const char*)VsL + (dt * 16 + ln) * 128;
#pragma unroll
      for (int ks = 0; ks < 2; ks++) {
        const bf16x8 vh = *(const bf16x8*)(vH + fc[ks]);
        const bf16x8 vl = *(const bf16x8*)(vL + fc[ks]);
        acc = __builtin_amdgcn_mfma_f32_16x16x32_bf16(vh, pbh[ks], acc, 0, 0, 0);
        acc = __builtin_amdgcn_mfma_f32_16x16x32_bf16(vh, pbl[ks], acc, 0, 0, 0);
        acc = __builtin_amdgcn_mfma_f32_16x16x32_bf16(vl, pbh[ks], acc, 0, 0, 0);
      }
      Oc[dt] = acc;
    }
    __syncthreads();  // all waves done with tile kt before restage
  }
  // ---- epilogue: cross-quad row-sum reduce, normalize, split store ----
  lrun += __shfl_xor(lrun, 16, 64);
  lrun += __shfl_xor(lrun, 32, 64);
  const float inv = 1.0f / lrun;
  const int tok = b * cS + q0 + wid * 16 + ln;
#pragma unroll
  for (int dt = 0; dt < 4; dt++) {
    u16x4 oh4, ol4;
#pragma unroll
    for (int r = 0; r < 4; r++) {
      const float v = Oc[dt][r] * inv;
      const unsigned short h16 = bf16_rne(v);
      oh4[r] = h16;
      ol4[r] = bf16_rne(v - bf16_f(h16));
    }
    const size_t idx = (size_t)tok * cD + h * cDH + dt * 16 + quad * 4;
    *(u16x4*)(Oh + idx) = oh4;
    *(u16x4*)(Ol + idx) = ol4;
  }
}

// ---------------------------------------------------------------------------
// Router (fp32 exact — feeds the discontinuous argmax).
// ---------------------------------------------------------------------------
__global__ __launch_bounds__(256) void router_kernel(
    const float* __restrict__ x2, const float* __restrict__ rw,
    const float* __restrict__ rb, const unsigned char* __restrict__ pad,
    float* __restrict__ gate, int* __restrict__ eidx, float* __restrict__ Psum,
    float* __restrict__ zsum) {
  __shared__ float Pacc[8];
  __shared__ float Zacc;
  if (threadIdx.x < 8) Pacc[threadIdx.x] = 0.f;
  if (threadIdx.x == 8) Zacc = 0.f;
  __syncthreads();
  const int tid = threadIdx.x, wid = tid >> 6, lane = tid & 63;
  const int e = lane & 7, dbase = lane >> 3;
  for (int tok = blockIdx.x * 4 + wid; tok < cN; tok += gridDim.x * 4) {
    const float* xr = x2 + (size_t)tok * cD;
    float partial = 0.f;
#pragma unroll 8
    for (int i = 0; i < cD / 8; i++) {
      const int d = dbase + i * 8;
      partial += xr[d] * rw[d * 8 + e];
    }
    partial += __shfl_xor(partial, 8, 64);
    partial += __shfl_xor(partial, 16, 64);
    partial += __shfl_xor(partial, 32, 64);
    const float logit = partial + rb[e];
    float mx = logit;
    mx = fmaxf(mx, __shfl_xor(mx, 1, 64));
    mx = fmaxf(mx, __shfl_xor(mx, 2, 64));
    mx = fmaxf(mx, __shfl_xor(mx, 4, 64));
    const float ex = __expf(logit - mx);
    float sm = ex;
    sm += __shfl_xor(sm, 1, 64);
    sm += __shfl_xor(sm, 2, 64);
    sm += __shfl_xor(sm, 4, 64);
    const float prob = ex / sm;
    float bv = logit;
    int bi = e;
#pragma unroll
    for (int m = 1; m < 8; m <<= 1) {
      const float ov = __shfl_xor(bv, m, 64);
      const int oi = __shfl_xor(bi, m, 64);
      if (ov > bv || (ov == bv && oi < bi)) {
        bv = ov;
        bi = oi;
      }
    }
    const float g = __shfl(prob, (lane & 0x38) | bi, 64);
    const bool valid = (pad[tok] == 0);
    if (lane == 0) {
      eidx[tok] = bi;
      gate[tok] = g;
    }
    if (valid) {
      if (lane < 8) atomicAdd(&Pacc[lane], prob);
      if (lane == 0) {
        const float lse = mx + logf(sm);
        atomicAdd(&Zacc, lse * lse);
      }
    }
  }
  __syncthreads();
  if (threadIdx.x < 8) atomicAdd(&Psum[threadIdx.x], Pacc[threadIdx.x]);
  if (threadIdx.x == 8) atomicAdd(zsum, Zacc);
}

// ---------------------------------------------------------------------------
// Capacity scan (unchanged).
// ---------------------------------------------------------------------------
__global__ __launch_bounds__(256) void scan_kernel(const int* __restrict__ eidx,
                                                   const unsigned char* __restrict__ pad,
                                                   int* __restrict__ slot,
                                                   int* __restrict__ counts) {
  __shared__ int cnt[256][8];
  const int t = threadIdx.x;
  int lc[8] = {0, 0, 0, 0, 0, 0, 0, 0};
  const int base = t * 32;
  for (int i = 0; i < 32; i++) {
    const int tok = base + i;
    if (!pad[tok]) lc[eidx[tok]]++;
  }
#pragma unroll
  for (int e2 = 0; e2 < 8; e2++) cnt[t][e2] = lc[e2];
  __syncthreads();
  if (t < 8) {
    int run = 0;
    for (int i = 0; i < 256; i++) {
      const int v = cnt[i][t];
      cnt[i][t] = run;
      run += v;
    }
    counts[t] = run;
  }
  __syncthreads();
  int off[8];
#pragma unroll
  for (int e2 = 0; e2 < 8; e2++) off[e2] = cnt[t][e2];
  for (int i = 0; i < 32; i++) {
    const int tok = base + i;
    if (!pad[tok]) {
      const int e2 = eidx[tok];
      const int p = off[e2]++;
      slot[tok] = (p < cCAP) ? (e2 * cCAP + p) : -1;
    } else {
      slot[tok] = -1;
    }
  }
}

__global__ __launch_bounds__(256) void dispatch_bf16_kernel(
    const float* __restrict__ x2, const int* __restrict__ slot,
    unsigned short* __restrict__ disp) {
  const int tok = blockIdx.x;
  const int s = slot[tok];
  if (s < 0) return;
  const float4 v = ((const float4*)(x2 + (size_t)tok * cD))[threadIdx.x];
  u16x4 o;
  o[0] = bf16_rne(v.x);
  o[1] = bf16_rne(v.y);
  o[2] = bf16_rne(v.z);
  o[3] = bf16_rne(v.w);
  *(u16x4*)(disp + (size_t)s * cD + threadIdx.x * 4) = o;
}

__global__ __launch_bounds__(256) void gather_kernel(const float* __restrict__ src1,
                                                     const float* __restrict__ o,
                                                     const int* __restrict__ slot,
                                                     const float* __restrict__ gate,
                                                     float* __restrict__ out) {
  const int tok = blockIdx.x;
  float4 r = ((const float4*)(src1 + (size_t)tok * cD))[threadIdx.x];
  const int s = slot[tok];
  if (s >= 0) {
    const float g = gate[tok];
    const float4 ov = ((const float4*)(o + (size_t)s * cD))[threadIdx.x];
    r.x += g * ov.x;
    r.y += g * ov.y;
    r.z += g * ov.z;
    r.w += g * ov.w;
  }
  ((float4*)(out + (size_t)tok * cD))[threadIdx.x] = r;
}

__global__ void loss_kernel(const int* __restrict__ counts,
                            const float* __restrict__ Psum,
                            const float* __restrict__ zsum,
                            float* __restrict__ out) {
  if (threadIdx.x == 0) {
    int tot = 0;
    for (int e2 = 0; e2 < 8; e2++) tot += counts[e2];
    const float denom = fmaxf((float)tot, 1.0f);
    float lp = 0.f;
    for (int e2 = 0; e2 < 8; e2++)
      lp += ((float)counts[e2] / denom) * (Psum[e2] / denom);
    out[0] = 8.0f * lp;
    out[1] = zsum[0] / denom;
  }
}

// ---------------------------------------------------------------------------
// Workspace layout (float units), sequential lifetimes:
// R_A: w1t bf16 (->FFN1) / w2t bf16 (->FFN2)   (qkv fp32 no longer exists)
// R_B: Q..Vt splits (QKV gemm->attn) / h bf16 (FFN1->FFN2)
// R_XHL: xh+xl (LN1->QKV) / Oh+Ol (attn->out_proj) / disp bf16 (->FFN1)
// R_X2O: mkf (padmask->attn) / x2 (LN2->dispatch) / obuf fp32 (FFN2->gather)
// ---------------------------------------------------------------------------
constexpr size_t OFF_A = 0;              // 25,165,824 floats
constexpr size_t OFF_B = 25165824;       // 25,165,824
constexpr size_t OFF_XHL = 50331648;     // 8,388,608
constexpr size_t OFF_SRC1 = 58720256;    // 8,388,608
constexpr size_t OFF_X2O = 67108864;     // 10,485,760
constexpr size_t OFF_IPW = 77594624;     // 3,145,728
constexpr size_t OFF_OPW = 80740352;     // 1,048,576
constexpr size_t OFF_MISC = 81788928;

extern "C" void kernel_launch(void* const* d_in, const int* in_sizes, int n_in,
                              void* d_out, int out_size, void* d_ws, size_t ws_size,
                              hipStream_t stream) {
  (void)in_sizes; (void)n_in; (void)out_size; (void)ws_size;
  const float* src = (const float*)d_in[0];
  const unsigned char* pad = (const unsigned char*)d_in[1];
  const float* ln1_g = (const float*)d_in[2];
  const float* ln1_b = (const float*)d_in[3];
  const float* in_proj_w = (const float*)d_in[4];
  const float* in_proj_b = (const float*)d_in[5];
  const float* out_proj_w = (const float*)d_in[6];
  const float* out_proj_b = (const float*)d_in[7];
  const float* ln2_g = (const float*)d_in[8];
  const float* ln2_b = (const float*)d_in[9];
  const float* router_w = (const float*)d_in[10];
  const float* router_b = (const float*)d_in[11];
  const float* w1 = (const float*)d_in[12];
  const float* b1 = (const float*)d_in[13];
  const float* w2 = (const float*)d_in[14];
  const float* b2 = (const float*)d_in[15];
  float* out = (float*)d_out;
  float* w = (float*)d_ws;

  unsigned short* w1t = (unsigned short*)(w + OFF_A);
  unsigned short* w2t = (unsigned short*)(w + OFF_A);   // after w1t dead
  unsigned short* usB = (unsigned short*)(w + OFF_B);
  constexpr size_t SPN = (size_t)cN * cD;               // 8,388,608 u16
  unsigned short* Qh = usB + 0 * SPN;
  unsigned short* Ql = usB + 1 * SPN;
  unsigned short* Kh = usB + 2 * SPN;
  unsigned short* Kl = usB + 3 * SPN;
  unsigned short* Vth = usB + 4 * SPN;
  unsigned short* Vtl = usB + 5 * SPN;
  unsigned short* hbuf16 = usB;                          // after splits dead
  unsigned short* xh = (unsigned short*)(w + OFF_XHL);
  unsigned short* xl = xh + SPN;
  unsigned short* Oh = xh;                               // after xh/xl dead
  unsigned short* Ol = xh + SPN;
  unsigned short* disp16 = xh;                           // after Oh/Ol dead
  float* src1 = w + OFF_SRC1;
  float* mkf = w + OFF_X2O;                              // dead before x2 written
  float* x2 = w + OFF_X2O;
  float* obuf = w + OFF_X2O;                             // after x2 dead
  unsigned short* ipwh = (unsigned short*)(w + OFF_IPW);
  unsigned short* ipwl = ipwh + (size_t)3 * cD * cD;
  unsigned short* opwh = (unsigned short*)(w + OFF_OPW);
  unsigned short* opwl = opwh + (size_t)cD * cD;
  float* gate = w + OFF_MISC;
  int* eidx = (int*)(w + OFF_MISC + 8192);
  int* slot = (int*)(w + OFF_MISC + 16384);
  float* Psum = w + OFF_MISC + 24576;
  float* zsum = Psum + 8;
  int* counts = (int*)(Psum + 16);

  hipMemsetAsync(Psum, 0, 9 * sizeof(float), stream);

  // 1) LN1 -> split bf16
  ln_split_kernel<<<cN, 256, 0, stream>>>(src, ln1_g, ln1_b, xh, xl);
  // 1.2) pad mask -> float additive mask (read by attn as float4)
  padmask_kernel<<<cN / 256, 256, 0, stream>>>(pad, mkf);
  // 1.5) weight splits
  wsplit_kernel<<<3072, 256, 0, stream>>>(in_proj_w, ipwh, ipwl, 786432);
  wsplit_kernel<<<1024, 256, 0, stream>>>(out_proj_w, opwh, opwl, 262144);
  // 2) QKV projection (split 3-term) with FUSED qkv-split epilogue
  gemm_bf16<true, false, false, 2><<<dim3(24, 64, 1), 256, 0, stream>>>(
      xh, xl, 0, ipwh, ipwl, 0, in_proj_b, 0, nullptr, nullptr, 0,
      cD, cD, cD, 0, Qh, Ql, Kh, Kl, Vth, Vtl);
  // 2.5) w1 transpose+convert: [e][d][f] -> [e][f][d] bf16
  transpose_bf16_kernel<<<dim3(64, 16, 8), 256, 0, stream>>>(w1, w1t, cD, cF);
  // 3) MFMA flash attention v4 -> Oh/Ol split bf16
  attn_mfma_kernel<<<dim3(cS / 64, cH, cB), 256, 0, stream>>>(
      Qh, Ql, Kh, Kl, Vth, Vtl, mkf, Oh, Ol);
  // 4) out_proj (split 3-term) + residual(src) -> src1 fp32
  gemm_bf16<true, false, true, 0><<<dim3(8, 64, 1), 256, 0, stream>>>(
      Oh, Ol, 0, opwh, opwl, 0, out_proj_b, 0, src, src1, 0,
      cD, cD, cD, cD, nullptr, nullptr, nullptr, nullptr, nullptr, nullptr);
  // 5) LN2 (fp32 exact)
  ln_kernel<<<cN, 256, 0, stream>>>(src1, ln2_g, ln2_b, x2);
  // 6) router
  router_kernel<<<256, 256, 0, stream>>>(x2, router_w, router_b, pad, gate, eidx,
                                         Psum, zsum);
  // 7) capacity scan
  scan_kernel<<<1, 256, 0, stream>>>(eidx, pad, slot, counts);
  // 8) dispatch scatter -> bf16
  dispatch_bf16_kernel<<<cN, 256, 0, stream>>>(x2, slot, disp16);
  // 9) FFN1: relu(disp @ w1 + b1) -> h bf16 (plain bf16 MFMA)
  gemm_bf16<false, true, false, 1><<<dim3(32, 10, 8), 256, 0, stream>>>(
      disp16, nullptr, (size_t)cCAP * cD, w1t, nullptr, (size_t)cD * cF,
      b1, cF, nullptr, hbuf16, (size_t)cCAP * cF, cD, cD, cD, cF,
      nullptr, nullptr, nullptr, nullptr, nullptr, nullptr);
  // 9.5) w2 transpose+convert: [e][f][d] -> [e][d][f] bf16 (w1t dead)
  transpose_bf16_kernel<<<dim3(16, 64, 8), 256, 0, stream>>>(w2, w2t, cF, cD);
  // 10) FFN2: h @ w2 + b2 -> obuf fp32
  gemm_bf16<false, false, false, 0><<<dim3(8, 10, 8), 256, 0, stream>>>(
      hbuf16, nullptr, (size_t)cCAP * cF, w2t, nullptr, (size_t)cF * cD,
      b2, cD, nullptr, obuf, (size_t)cCAP * cD, cF, cF, cF, cD,
      nullptr, nullptr, nullptr, nullptr, nullptr, nullptr);
  // 11) gather + residual -> out
  gather_kernel<<<cN, 256, 0, stream>>>(src1, obuf, slot, gate, out);
  // 12) losses
  loss_kernel<<<1, 64, 0, stream>>>(counts, Psum, zsum, out + (size_t)cN * cD);
}

// Round 4
// 1264.145 us; speedup vs baseline: 1.8752x; 1.1292x over previous
//
#include <hip/hip_runtime.h>

// Problem constants
constexpr int cB = 4, cS = 2048, cD = 1024, cH = 16, cE = 8, cF = 4096;
constexpr int cN = cB * cS;          // 8192 tokens
constexpr int cDH = 64;
constexpr int cCAP = 1280;           // int(1.25 * 8192 / 8)

typedef __attribute__((ext_vector_type(8))) short bf16x8;
typedef __attribute__((ext_vector_type(4))) float f32x4;
typedef __attribute__((ext_vector_type(4))) unsigned short u16x4;
typedef __attribute__((ext_vector_type(4))) unsigned int u32x4;

__device__ inline unsigned short bf16_rne(float x) {
  unsigned u = __float_as_uint(x);
  u += 0x7FFF + ((u >> 16) & 1);
  return (unsigned short)(u >> 16);
}
__device__ inline float bf16_f(unsigned short h) {
  return __uint_as_float(((unsigned)h) << 16);
}
// packed RNE f32x2 -> bf16x2 (hardware cvt; same RNE as bf16_rne)
__device__ inline unsigned cvt_pk_bf16(float a, float b) {
  unsigned r;
  asm("v_cvt_pk_bf16_f32 %0, %1, %2" : "=v"(r) : "v"(a), "v"(b));
  return r;
}

// ---------------------------------------------------------------------------
// LayerNorm fp32 (LN2): one block per token.
// ---------------------------------------------------------------------------
__global__ __launch_bounds__(256) void ln_kernel(const float* __restrict__ x,
                                                 const float* __restrict__ g,
                                                 const float* __restrict__ bb,
                                                 float* __restrict__ y) {
  __shared__ float red[8];
  const int row = blockIdx.x;
  const int t = threadIdx.x;
  const float4 v = ((const float4*)(x + (size_t)row * cD))[t];
  float s = v.x + v.y + v.z + v.w;
#pragma unroll
  for (int m = 32; m >= 1; m >>= 1) s += __shfl_xor(s, m, 64);
  if ((t & 63) == 0) red[t >> 6] = s;
  __syncthreads();
  const float mean = (red[0] + red[1] + red[2] + red[3]) * (1.0f / cD);
  const float dx = v.x - mean, dy = v.y - mean, dz = v.z - mean, dw = v.w - mean;
  float ss = dx * dx + dy * dy + dz * dz + dw * dw;
#pragma unroll
  for (int m = 32; m >= 1; m >>= 1) ss += __shfl_xor(ss, m, 64);
  if ((t & 63) == 0) red[4 + (t >> 6)] = ss;
  __syncthreads();
  const float var = (red[4] + red[5] + red[6] + red[7]) * (1.0f / cD);
  const float inv = rsqrtf(var + 1e-5f);
  const float4 gg = ((const float4*)g)[t];
  const float4 b4 = ((const float4*)bb)[t];
  float4 o;
  o.x = dx * inv * gg.x + b4.x;
  o.y = dy * inv * gg.y + b4.y;
  o.z = dz * inv * gg.z + b4.z;
  o.w = dw * inv * gg.w + b4.w;
  ((float4*)(y + (size_t)row * cD))[t] = o;
}

// ---------------------------------------------------------------------------
// LayerNorm with split-bf16 output (LN1 -> QKV GEMM A operand).
// ---------------------------------------------------------------------------
__global__ __launch_bounds__(256) void ln_split_kernel(
    const float* __restrict__ x, const float* __restrict__ g,
    const float* __restrict__ bb, unsigned short* __restrict__ yh,
    unsigned short* __restrict__ yl) {
  __shared__ float red[8];
  const int row = blockIdx.x;
  const int t = threadIdx.x;
  const float4 v = ((const float4*)(x + (size_t)row * cD))[t];
  float s = v.x + v.y + v.z + v.w;
#pragma unroll
  for (int m = 32; m >= 1; m >>= 1) s += __shfl_xor(s, m, 64);
  if ((t & 63) == 0) red[t >> 6] = s;
  __syncthreads();
  const float mean = (red[0] + red[1] + red[2] + red[3]) * (1.0f / cD);
  const float dx = v.x - mean, dy = v.y - mean, dz = v.z - mean, dw = v.w - mean;
  float ss = dx * dx + dy * dy + dz * dz + dw * dw;
#pragma unroll
  for (int m = 32; m >= 1; m >>= 1) ss += __shfl_xor(ss, m, 64);
  if ((t & 63) == 0) red[4 + (t >> 6)] = ss;
  __syncthreads();
  const float var = (red[4] + red[5] + red[6] + red[7]) * (1.0f / cD);
  const float inv = rsqrtf(var + 1e-5f);
  const float4 gg = ((const float4*)g)[t];
  const float4 b4 = ((const float4*)bb)[t];
  const float oa[4] = {dx * inv * gg.x + b4.x, dy * inv * gg.y + b4.y,
                       dz * inv * gg.z + b4.z, dw * inv * gg.w + b4.w};
  u16x4 hh, ll;
#pragma unroll
  for (int i = 0; i < 4; i++) {
    const unsigned short h16 = bf16_rne(oa[i]);
    hh[i] = h16;
    ll[i] = bf16_rne(oa[i] - bf16_f(h16));
  }
  *(u16x4*)(yh + (size_t)row * cD + t * 4) = hh;
  *(u16x4*)(yl + (size_t)row * cD + t * 4) = ll;
}

// ---------------------------------------------------------------------------
// Weight split: fp32 -> bf16 hi/lo, same layout. n4 = element_count/4.
// ---------------------------------------------------------------------------
__global__ __launch_bounds__(256) void wsplit_kernel(const float* __restrict__ in,
                                                     unsigned short* __restrict__ hi,
                                                     unsigned short* __restrict__ lo,
                                                     int n4) {
  const int i = blockIdx.x * 256 + threadIdx.x;
  if (i >= n4) return;
  const float4 v = ((const float4*)in)[i];
  const float a[4] = {v.x, v.y, v.z, v.w};
  u16x4 hh, ll;
#pragma unroll
  for (int j = 0; j < 4; j++) {
    const unsigned short h16 = bf16_rne(a[j]);
    hh[j] = h16;
    ll[j] = bf16_rne(a[j] - bf16_f(h16));
  }
  *(u16x4*)(hi + (size_t)i * 4) = hh;
  *(u16x4*)(lo + (size_t)i * 4) = ll;
}

// ---------------------------------------------------------------------------
// Pad mask precompute: byte -> float (-1e30 for pad, 0 otherwise).
// ---------------------------------------------------------------------------
__global__ __launch_bounds__(256) void padmask_kernel(
    const unsigned char* __restrict__ pad, float* __restrict__ mkf) {
  const int i = blockIdx.x * 256 + threadIdx.x;
  mkf[i] = pad[i] ? -1e30f : 0.0f;
}

// ---------------------------------------------------------------------------
// Transpose + bf16 convert: in fp32 [z][R][C] -> out bf16 [z][C][R].
// ---------------------------------------------------------------------------
__global__ __launch_bounds__(256) void transpose_bf16_kernel(
    const float* __restrict__ in, unsigned short* __restrict__ outp, int Rr,
    int Cc) {
  __shared__ float T[64][65];
  const int z = blockIdx.z;
  in += (size_t)z * Rr * Cc;
  outp += (size_t)z * Rr * Cc;
  const int c0 = blockIdx.x * 64, r0 = blockIdx.y * 64;
  const int tid = threadIdx.x;
#pragma unroll
  for (int u = 0; u < 4; u++) {
    const int a = tid + u * 256;
    const int r = a >> 4, c4 = (a & 15) << 2;
    const float4 v = *(const float4*)(in + (size_t)(r0 + r) * Cc + c0 + c4);
    T[r][c4 + 0] = v.x;
    T[r][c4 + 1] = v.y;
    T[r][c4 + 2] = v.z;
    T[r][c4 + 3] = v.w;
  }
  __syncthreads();
#pragma unroll
  for (int u = 0; u < 4; u++) {
    const int a = tid + u * 256;
    const int c = a >> 4, r4 = (a & 15) << 2;
    u16x4 o;
#pragma unroll
    for (int i = 0; i < 4; i++) o[i] = bf16_rne(T[r4 + i][c]);
    *(u16x4*)(outp + (size_t)(c0 + c) * Rr + r0 + r4) = o;
  }
}

// ---------------------------------------------------------------------------
// bf16 MFMA GEMM: C[M,N] = A[M,K] * B[N,K]^T + bias.
// OUT: 0 = fp32 C (+RELU/+RESID), 1 = bf16 C, 2 = fused QKV-split epilogue
// (writes Qh/Ql/Kh/Kl [b,h,s,d] and Vth/Vtl [b,h,d,s] split-bf16 directly).
// 128x128 tile, BK=32, 4 waves x (4x4 of 16x16x32 MFMA), LDS stride 40 u16.
// ---------------------------------------------------------------------------
template <bool SPLIT, bool RELU, bool RESID, int OUT>
__global__ __launch_bounds__(256) void gemm_bf16(
    const unsigned short* __restrict__ Ah, const unsigned short* __restrict__ Al,
    size_t sA,
    const unsigned short* __restrict__ Bh, const unsigned short* __restrict__ Bl,
    size_t sB,
    const float* __restrict__ bias, size_t sBias,
    const float* __restrict__ R,
    void* __restrict__ Cv, size_t sC,
    int K, int lda, int ldb, int ldc,
    unsigned short* __restrict__ Qh, unsigned short* __restrict__ Ql,
    unsigned short* __restrict__ Kh, unsigned short* __restrict__ Kl,
    unsigned short* __restrict__ Vth, unsigned short* __restrict__ Vtl) {
  __shared__ unsigned short AsH[128 * 40];
  __shared__ unsigned short BsH[128 * 40];
  __shared__ unsigned short AsL[SPLIT ? 128 * 40 : 8];
  __shared__ unsigned short BsL[SPLIT ? 128 * 40 : 8];
  const int z = blockIdx.z;
  Ah += (size_t)z * sA;
  Bh += (size_t)z * sB;
  if constexpr (SPLIT) {
    Al += (size_t)z * sA;
    Bl += (size_t)z * sB;
  }
  bias += (size_t)z * sBias;
  const int n0 = blockIdx.x * 128, m0 = blockIdx.y * 128;
  const int tid = threadIdx.x;
  const int wid = tid >> 6, lane = tid & 63;
  const int ln = lane & 15, quad = lane >> 4;
  const int wm = (wid >> 1) * 64, wn = (wid & 1) * 64;

  f32x4 acc[4][4];
#pragma unroll
  for (int i = 0; i < 4; i++)
#pragma unroll
    for (int j = 0; j < 4; j++) acc[i][j] = (f32x4){0.f, 0.f, 0.f, 0.f};

  for (int k0 = 0; k0 < K; k0 += 32) {
    __syncthreads();
#pragma unroll
    for (int u = 0; u < 2; u++) {
      const int c = tid + u * 256;           // 0..511
      const int row = c >> 2, ko = (c & 3) << 3;
      const int ld = row * 40 + ko;
      *(uint4*)&AsH[ld] = *(const uint4*)(Ah + (size_t)(m0 + row) * lda + k0 + ko);
      *(uint4*)&BsH[ld] = *(const uint4*)(Bh + (size_t)(n0 + row) * ldb + k0 + ko);
      if constexpr (SPLIT) {
        *(uint4*)&AsL[ld] = *(const uint4*)(Al + (size_t)(m0 + row) * lda + k0 + ko);
        *(uint4*)&BsL[ld] = *(const uint4*)(Bl + (size_t)(n0 + row) * ldb + k0 + ko);
      }
    }
    __syncthreads();
    bf16x8 bh[4], bl[4];
#pragma unroll
    for (int nt = 0; nt < 4; nt++) {
      bh[nt] = *(const bf16x8*)&BsH[(wn + nt * 16 + ln) * 40 + quad * 8];
      if constexpr (SPLIT)
        bl[nt] = *(const bf16x8*)&BsL[(wn + nt * 16 + ln) * 40 + quad * 8];
    }
#pragma unroll
    for (int mt = 0; mt < 4; mt++) {
      const bf16x8 ah = *(const bf16x8*)&AsH[(wm + mt * 16 + ln) * 40 + quad * 8];
      bf16x8 al;
      if constexpr (SPLIT)
        al = *(const bf16x8*)&AsL[(wm + mt * 16 + ln) * 40 + quad * 8];
#pragma unroll
      for (int nt = 0; nt < 4; nt++) {
        acc[mt][nt] =
            __builtin_amdgcn_mfma_f32_16x16x32_bf16(ah, bh[nt], acc[mt][nt], 0, 0, 0);
        if constexpr (SPLIT) {
          acc[mt][nt] =
              __builtin_amdgcn_mfma_f32_16x16x32_bf16(al, bh[nt], acc[mt][nt], 0, 0, 0);
          acc[mt][nt] =
              __builtin_amdgcn_mfma_f32_16x16x32_bf16(ah, bl[nt], acc[mt][nt], 0, 0, 0);
        }
      }
    }
  }
  // ---- epilogue ----
  if constexpr (OUT == 2) {
    // fused QKV split: col -> (sec,h,d); row -> (b,s). sec/h wave-uniform.
#pragma unroll
    for (int mt = 0; mt < 4; mt++) {
      const int row0 = m0 + wm + mt * 16 + quad * 4;
      const int b_ = row0 >> 11, s0_ = row0 & 2047;
      const size_t bbase = (size_t)b_ * cH * cS * cDH;
#pragma unroll
      for (int nt = 0; nt < 4; nt++) {
        const int col = n0 + wn + nt * 16 + ln;
        const float bv = bias[col];
        const int sec = col >> 10;
        const int f = col & 1023;
        const int hh = f >> 6, d = f & 63;
        const size_t bh_off = bbase + (size_t)hh * cS * cDH;
        float vals[4];
#pragma unroll
        for (int r = 0; r < 4; r++) vals[r] = acc[mt][nt][r] + bv;
        if (sec == 2) {
          u16x4 hi4, lo4;
#pragma unroll
          for (int r = 0; r < 4; r++) {
            const unsigned short h16 = bf16_rne(vals[r]);
            hi4[r] = h16;
            lo4[r] = bf16_rne(vals[r] - bf16_f(h16));
          }
          const size_t idx = bh_off + (size_t)d * cS + s0_;
          *(u16x4*)(Vth + idx) = hi4;
          *(u16x4*)(Vtl + idx) = lo4;
        } else {
          unsigned short* dsth = (sec == 0) ? Qh : Kh;
          unsigned short* dstl = (sec == 0) ? Ql : Kl;
#pragma unroll
          for (int r = 0; r < 4; r++) {
            const unsigned short h16 = bf16_rne(vals[r]);
            const size_t idx = bh_off + (size_t)(s0_ + r) * cDH + d;
            dsth[idx] = h16;
            dstl[idx] = bf16_rne(vals[r] - bf16_f(h16));
          }
        }
      }
    }
  } else {
    float* Cf = nullptr;
    unsigned short* Cb = nullptr;
    if constexpr (OUT == 1)
      Cb = (unsigned short*)Cv + (size_t)z * sC;
    else
      Cf = (float*)Cv + (size_t)z * sC;
#pragma unroll
    for (int mt = 0; mt < 4; mt++) {
#pragma unroll
      for (int nt = 0; nt < 4; nt++) {
        const int col = n0 + wn + nt * 16 + ln;
        const float bv = bias[col];
#pragma unroll
        for (int r = 0; r < 4; r++) {
          const int row = m0 + wm + mt * 16 + quad * 4 + r;
          float v = acc[mt][nt][r] + bv;
          if constexpr (RELU) v = fmaxf(v, 0.f);
          if constexpr (RESID) v += R[(size_t)row * ldc + col];
          if constexpr (OUT == 1)
            Cb[(size_t)row * ldc + col] = bf16_rne(v);
          else
            Cf[(size_t)row * ldc + col] = v;
        }
      }
    }
  }
}

// ---------------------------------------------------------------------------
// Flash attention v5 = v4 + QBLK 64->128 (two q-sets per wave).
//   Same 32KB swizzled LDS tiles; K/V fragments read ONCE per iter and
//   reused for both q-sets -> stage cost amortized over 2x MFMA work, and
//   two independent accumulator chains double MFMA ILP.
//   (v4 verified parts kept: baked-V kappa permutation, cvt_pk packing,
//    defer-max THR=8, deferred row-sum.)
// ---------------------------------------------------------------------------
__device__ inline void softmax_pack(const float (&sf)[4][4], float& mprev,
                                    float& lrun, f32x4 (&Oc)[4],
                                    bf16x8 (&pbh)[2], bf16x8 (&pbl)[2]) {
  float vm = sf[0][0];
#pragma unroll
  for (int st = 0; st < 4; st++)
#pragma unroll
    for (int r = 0; r < 4; r++) vm = fmaxf(vm, sf[st][r]);
  if (!__all(vm <= mprev + 8.0f)) {
    float vmr = fmaxf(vm, __shfl_xor(vm, 16, 64));
    vmr = fmaxf(vmr, __shfl_xor(vmr, 32, 64));
    const float mnew = fmaxf(mprev, vmr);
    const float alpha = exp2f(mprev - mnew);
    lrun *= alpha;
#pragma unroll
    for (int dt = 0; dt < 4; dt++) {
      Oc[dt][0] *= alpha;
      Oc[dt][1] *= alpha;
      Oc[dt][2] *= alpha;
      Oc[dt][3] *= alpha;
    }
    mprev = mnew;
  }
  u32x4 ph[2], pl[2];
  float rs = 0.f;
#pragma unroll
  for (int st = 0; st < 4; st++) {
#pragma unroll
    for (int rp = 0; rp < 2; rp++) {
      const float p0 = exp2f(sf[st][2 * rp] - mprev);
      const float p1 = exp2f(sf[st][2 * rp + 1] - mprev);
      rs += p0 + p1;
      const unsigned wh = cvt_pk_bf16(p0, p1);
      const float f0 = __uint_as_float(wh << 16);
      const float f1 = __uint_as_float(wh & 0xFFFF0000u);
      const unsigned wl = cvt_pk_bf16(p0 - f0, p1 - f1);
      ph[st >> 1][(st & 1) * 2 + rp] = wh;
      pl[st >> 1][(st & 1) * 2 + rp] = wl;
    }
  }
  lrun += rs;
  pbh[0] = __builtin_bit_cast(bf16x8, ph[0]);
  pbh[1] = __builtin_bit_cast(bf16x8, ph[1]);
  pbl[0] = __builtin_bit_cast(bf16x8, pl[0]);
  pbl[1] = __builtin_bit_cast(bf16x8, pl[1]);
}

__global__ __launch_bounds__(256) void attn_mfma_kernel(
    const unsigned short* __restrict__ Qh, const unsigned short* __restrict__ Ql,
    const unsigned short* __restrict__ Kh, const unsigned short* __restrict__ Kl,
    const unsigned short* __restrict__ Vth, const unsigned short* __restrict__ Vtl,
    const float* __restrict__ mkf, unsigned short* __restrict__ Oh,
    unsigned short* __restrict__ Ol) {
  __shared__ alignas(16) unsigned short KsH[64 * 64];
  __shared__ alignas(16) unsigned short KsL[64 * 64];
  __shared__ alignas(16) unsigned short VsH[64 * 64];
  __shared__ alignas(16) unsigned short VsL[64 * 64];

  const int q0 = blockIdx.x << 7;           // 128 q-rows per block
  const int h = blockIdx.y, b = blockIdx.z;
  const int tid = threadIdx.x;
  const int wid = tid >> 6, lane = tid & 63;
  const int ln = lane & 15, quad = lane >> 4;
  constexpr float SC2 = 0.125f * 1.4426950408889634f;  // 1/sqrt(64) * log2(e)

  const size_t bh = (size_t)(b * cH + h);
  const unsigned short* gKh = Kh + bh * cS * cDH;
  const unsigned short* gKl = Kl + bh * cS * cDH;
  const unsigned short* gVh = Vth + bh * cDH * cS;
  const unsigned short* gVl = Vtl + bh * cDH * cS;
  const float* gM = mkf + (size_t)b * cS;

  // ---- staging map: thread covers rows tid>>3 and +32, one 16B chunk ----
  const int t8 = tid & 7;                 // 16B chunk index (src)
  const int srow0 = tid >> 3;             // 0..31
  const int srow1 = srow0 + 32;
  const int xw0 = (srow0 & 7) << 4, xw1 = (srow1 & 7) << 4;
  const int wbK0 = srow0 * 128 + ((t8 << 4) ^ xw0);
  const int wbK1 = srow1 * 128 + ((t8 << 4) ^ xw1);
  // V permuted slots: half h6, within-half chunk pair (2u,2u+1) -> slots
  // A(u)=((u&1)<<2)|(u>>1), B(u)=A(u)+2   (8B granularity)
  const int h6 = (t8 >> 2) << 6;
  const int uu = t8 & 3;
  const int pA = h6 + ((((uu & 1) << 2) | (uu >> 1)) << 3);
  const int pB = pA + 16;
  const int wbVA0 = srow0 * 128 + (pA ^ xw0);
  const int wbVB0 = srow0 * 128 + (pB ^ xw0);
  const int wbVA1 = srow1 * 128 + (pA ^ xw1);
  const int wbVB1 = srow1 * 128 + (pB ^ xw1);

  // per-lane swizzled read byte offsets (same pattern for K and permuted V)
  const int xs = (ln & 7) << 4;
  const int fc[2] = {(quad * 16) ^ xs, (quad * 16 + 64) ^ xs};

  // Q fragments, two q-sets: A = q0+wid*16+ln, B = A+64
  const size_t qbase = (bh * cS + q0 + wid * 16 + ln) * cDH;
  bf16x8 qhA[2], qlA[2], qhB[2], qlB[2];
#pragma unroll
  for (int ks = 0; ks < 2; ks++) {
    qhA[ks] = *(const bf16x8*)(Qh + qbase + ks * 32 + quad * 8);
    qlA[ks] = *(const bf16x8*)(Ql + qbase + ks * 32 + quad * 8);
    qhB[ks] = *(const bf16x8*)(Qh + qbase + (size_t)64 * cDH + ks * 32 + quad * 8);
    qlB[ks] = *(const bf16x8*)(Ql + qbase + (size_t)64 * cDH + ks * 32 + quad * 8);
  }

  f32x4 OcA[4], OcB[4];  // O^T: rows d (dt*16+quad*4+r), col q=ln
#pragma unroll
  for (int dt = 0; dt < 4; dt++) {
    OcA[dt] = (f32x4){0.f, 0.f, 0.f, 0.f};
    OcB[dt] = (f32x4){0.f, 0.f, 0.f, 0.f};
  }
  float mprevA = -1e30f, lrunA = 0.f;
  float mprevB = -1e30f, lrunB = 0.f;

  for (int kt = 0; kt < cS / 64; kt++) {
    const int k0 = kt << 6;
    // ---- stage tile kt (prev compute finished at loop-bottom barrier) ----
    {
      const size_t kr0 = (size_t)(k0 + srow0) * cDH + (t8 << 3);
      const size_t kr1 = (size_t)(k0 + srow1) * cDH + (t8 << 3);
      *(uint4*)((char*)KsH + wbK0) = *(const uint4*)(gKh + kr0);
      *(uint4*)((char*)KsH + wbK1) = *(const uint4*)(gKh + kr1);
      *(uint4*)((char*)KsL + wbK0) = *(const uint4*)(gKl + kr0);
      *(uint4*)((char*)KsL + wbK1) = *(const uint4*)(gKl + kr1);
      const size_t vr0 = (size_t)srow0 * cS + k0 + (t8 << 3);
      const size_t vr1 = (size_t)srow1 * cS + k0 + (t8 << 3);
      const uint4 a = *(const uint4*)(gVh + vr0);
      const uint4 b2 = *(const uint4*)(gVh + vr1);
      const uint4 c = *(const uint4*)(gVl + vr0);
      const uint4 d = *(const uint4*)(gVl + vr1);
      uint2 t;
      t.x = a.x;  t.y = a.y;  *(uint2*)((char*)VsH + wbVA0) = t;
      t.x = a.z;  t.y = a.w;  *(uint2*)((char*)VsH + wbVB0) = t;
      t.x = b2.x; t.y = b2.y; *(uint2*)((char*)VsH + wbVA1) = t;
      t.x = b2.z; t.y = b2.w; *(uint2*)((char*)VsH + wbVB1) = t;
      t.x = c.x;  t.y = c.y;  *(uint2*)((char*)VsL + wbVA0) = t;
      t.x = c.z;  t.y = c.w;  *(uint2*)((char*)VsL + wbVB0) = t;
      t.x = d.x;  t.y = d.y;  *(uint2*)((char*)VsL + wbVA1) = t;
      t.x = d.z;  t.y = d.w;  *(uint2*)((char*)VsL + wbVB1) = t;
    }
    __syncthreads();

    // ---- S^T = K Q^T for both q-sets (K frags read once) ----
    float sfA[4][4], sfB[4][4];
#pragma unroll
    for (int st = 0; st < 4; st++) {
      f32x4 accA = (f32x4){0.f, 0.f, 0.f, 0.f};
      f32x4 accB = (f32x4){0.f, 0.f, 0.f, 0.f};
      const char* rH = (const char*)KsH + (st * 16 + ln) * 128;
      const char* rL = (const char*)KsL + (st * 16 + ln) * 128;
#pragma unroll
      for (int ks = 0; ks < 2; ks++) {
        const bf16x8 kh = *(const bf16x8*)(rH + fc[ks]);
        const bf16x8 kl = *(const bf16x8*)(rL + fc[ks]);
        accA = __builtin_amdgcn_mfma_f32_16x16x32_bf16(kh, qhA[ks], accA, 0, 0, 0);
        accB = __builtin_amdgcn_mfma_f32_16x16x32_bf16(kh, qhB[ks], accB, 0, 0, 0);
        accA = __builtin_amdgcn_mfma_f32_16x16x32_bf16(kl, qhA[ks], accA, 0, 0, 0);
        accB = __builtin_amdgcn_mfma_f32_16x16x32_bf16(kl, qhB[ks], accB, 0, 0, 0);
        accA = __builtin_amdgcn_mfma_f32_16x16x32_bf16(kh, qlA[ks], accA, 0, 0, 0);
        accB = __builtin_amdgcn_mfma_f32_16x16x32_bf16(kh, qlB[ks], accB, 0, 0, 0);
      }
      const float4 mkv = *(const float4*)(gM + k0 + st * 16 + quad * 4);
      sfA[st][0] = accA[0] * SC2 + mkv.x;
      sfA[st][1] = accA[1] * SC2 + mkv.y;
      sfA[st][2] = accA[2] * SC2 + mkv.z;
      sfA[st][3] = accA[3] * SC2 + mkv.w;
      sfB[st][0] = accB[0] * SC2 + mkv.x;
      sfB[st][1] = accB[1] * SC2 + mkv.y;
      sfB[st][2] = accB[2] * SC2 + mkv.z;
      sfB[st][3] = accB[3] * SC2 + mkv.w;
    }
    // ---- online softmax + P pack, per q-set ----
    bf16x8 pbhA[2], pblA[2], pbhB[2], pblB[2];
    softmax_pack(sfA, mprevA, lrunA, OcA, pbhA, pblA);
    softmax_pack(sfB, mprevB, lrunB, OcB, pbhB, pblB);
    // ---- O^T += V^T P^T for both q-sets (V frags read once) ----
#pragma unroll
    for (int dt = 0; dt < 4; dt++) {
      f32x4 accA = OcA[dt];
      f32x4 accB = OcB[dt];
      const char* vH = (const char*)VsH + (dt * 16 + ln) * 128;
      const char* vL = (const char*)VsL + (dt * 16 + ln) * 128;
#pragma unroll
      for (int ks = 0; ks < 2; ks++) {
        const bf16x8 vh = *(const bf16x8*)(vH + fc[ks]);
        const bf16x8 vl = *(const bf16x8*)(vL + fc[ks]);
        accA = __builtin_amdgcn_mfma_f32_16x16x32_bf16(vh, pbhA[ks], accA, 0, 0, 0);
        accB = __builtin_amdgcn_mfma_f32_16x16x32_bf16(vh, pbhB[ks], accB, 0, 0, 0);
        accA = __builtin_amdgcn_mfma_f32_16x16x32_bf16(vh, pblA[ks], accA, 0, 0, 0);
        accB = __builtin_amdgcn_mfma_f32_16x16x32_bf16(vh, pblB[ks], accB, 0, 0, 0);
        accA = __builtin_amdgcn_mfma_f32_16x16x32_bf16(vl, pbhA[ks], accA, 0, 0, 0);
        accB = __builtin_amdgcn_mfma_f32_16x16x32_bf16(vl, pbhB[ks], accB, 0, 0, 0);
      }
      OcA[dt] = accA;
      OcB[dt] = accB;
    }
    __syncthreads();  // all waves done with tile kt before restage
  }
  // ---- epilogue: cross-quad row-sum reduce, normalize, split store ----
  lrunA += __shfl_xor(lrunA, 16, 64);
  lrunA += __shfl_xor(lrunA, 32, 64);
  lrunB += __shfl_xor(lrunB, 16, 64);
  lrunB += __shfl_xor(lrunB, 32, 64);
  const float invA = 1.0f / lrunA;
  const float invB = 1.0f / lrunB;
  const int tokA = b * cS + q0 + wid * 16 + ln;
  const int tokB = tokA + 64;
#pragma unroll
  for (int dt = 0; dt < 4; dt++) {
    u16x4 oh4, ol4;
#pragma unroll
    for (int r = 0; r < 4; r++) {
      const float v = OcA[dt][r] * invA;
      const unsigned short h16 = bf16_rne(v);
      oh4[r] = h16;
      ol4[r] = bf16_rne(v - bf16_f(h16));
    }
    const size_t idx = (size_t)tokA * cD + h * cDH + dt * 16 + quad * 4;
    *(u16x4*)(Oh + idx) = oh4;
    *(u16x4*)(Ol + idx) = ol4;
  }
#pragma unroll
  for (int dt = 0; dt < 4; dt++) {
    u16x4 oh4, ol4;
#pragma unroll
    for (int r = 0; r < 4; r++) {
      const float v = OcB[dt][r] * invB;
      const unsigned short h16 = bf16_rne(v);
      oh4[r] = h16;
      ol4[r] = bf16_rne(v - bf16_f(h16));
    }
    const size_t idx = (size_t)tokB * cD + h * cDH + dt * 16 + quad * 4;
    *(u16x4*)(Oh + idx) = oh4;
    *(u16x4*)(Ol + idx) = ol4;
  }
}

// ---------------------------------------------------------------------------
// Router (fp32 exact — feeds the discontinuous argmax).
// ---------------------------------------------------------------------------
__global__ __launch_bounds__(256) void router_kernel(
    const float* __restrict__ x2, const float* __restrict__ rw,
    const float* __restrict__ rb, const unsigned char* __restrict__ pad,
    float* __restrict__ gate, int* __restrict__ eidx, float* __restrict__ Psum,
    float* __restrict__ zsum) {
  __shared__ float Pacc[8];
  __shared__ float Zacc;
  if (threadIdx.x < 8) Pacc[threadIdx.x] = 0.f;
  if (threadIdx.x == 8) Zacc = 0.f;
  __syncthreads();
  const int tid = threadIdx.x, wid = tid >> 6, lane = tid & 63;
  const int e = lane & 7, dbase = lane >> 3;
  for (int tok = blockIdx.x * 4 + wid; tok < cN; tok += gridDim.x * 4) {
    const float* xr = x2 + (size_t)tok * cD;
    float partial = 0.f;
#pragma unroll 8
    for (int i = 0; i < cD / 8; i++) {
      const int d = dbase + i * 8;
      partial += xr[d] * rw[d * 8 + e];
    }
    partial += __shfl_xor(partial, 8, 64);
    partial += __shfl_xor(partial, 16, 64);
    partial += __shfl_xor(partial, 32, 64);
    const float logit = partial + rb[e];
    float mx = logit;
    mx = fmaxf(mx, __shfl_xor(mx, 1, 64));
    mx = fmaxf(mx, __shfl_xor(mx, 2, 64));
    mx = fmaxf(mx, __shfl_xor(mx, 4, 64));
    const float ex = __expf(logit - mx);
    float sm = ex;
    sm += __shfl_xor(sm, 1, 64);
    sm += __shfl_xor(sm, 2, 64);
    sm += __shfl_xor(sm, 4, 64);
    const float prob = ex / sm;
    float bv = logit;
    int bi = e;
#pragma unroll
    for (int m = 1; m < 8; m <<= 1) {
      const float ov = __shfl_xor(bv, m, 64);
      const int oi = __shfl_xor(bi, m, 64);
      if (ov > bv || (ov == bv && oi < bi)) {
        bv = ov;
        bi = oi;
      }
    }
    const float g = __shfl(prob, (lane & 0x38) | bi, 64);
    const bool valid = (pad[tok] == 0);
    if (lane == 0) {
      eidx[tok] = bi;
      gate[tok] = g;
    }
    if (valid) {
      if (lane < 8) atomicAdd(&Pacc[lane], prob);
      if (lane == 0) {
        const float lse = mx + logf(sm);
        atomicAdd(&Zacc, lse * lse);
      }
    }
  }
  __syncthreads();
  if (threadIdx.x < 8) atomicAdd(&Psum[threadIdx.x], Pacc[threadIdx.x]);
  if (threadIdx.x == 8) atomicAdd(zsum, Zacc);
}

// ---------------------------------------------------------------------------
// Capacity scan (unchanged).
// ---------------------------------------------------------------------------
__global__ __launch_bounds__(256) void scan_kernel(const int* __restrict__ eidx,
                                                   const unsigned char* __restrict__ pad,
                                                   int* __restrict__ slot,
                                                   int* __restrict__ counts) {
  __shared__ int cnt[256][8];
  const int t = threadIdx.x;
  int lc[8] = {0, 0, 0, 0, 0, 0, 0, 0};
  const int base = t * 32;
  for (int i = 0; i < 32; i++) {
    const int tok = base + i;
    if (!pad[tok]) lc[eidx[tok]]++;
  }
#pragma unroll
  for (int e2 = 0; e2 < 8; e2++) cnt[t][e2] = lc[e2];
  __syncthreads();
  if (t < 8) {
    int run = 0;
    for (int i = 0; i < 256; i++) {
      const int v = cnt[i][t];
      cnt[i][t] = run;
      run += v;
    }
    counts[t] = run;
  }
  __syncthreads();
  int off[8];
#pragma unroll
  for (int e2 = 0; e2 < 8; e2++) off[e2] = cnt[t][e2];
  for (int i = 0; i < 32; i++) {
    const int tok = base + i;
    if (!pad[tok]) {
      const int e2 = eidx[tok];
      const int p = off[e2]++;
      slot[tok] = (p < cCAP) ? (e2 * cCAP + p) : -1;
    } else {
      slot[tok] = -1;
    }
  }
}

__global__ __launch_bounds__(256) void dispatch_bf16_kernel(
    const float* __restrict__ x2, const int* __restrict__ slot,
    unsigned short* __restrict__ disp) {
  const int tok = blockIdx.x;
  const int s = slot[tok];
  if (s < 0) return;
  const float4 v = ((const float4*)(x2 + (size_t)tok * cD))[threadIdx.x];
  u16x4 o;
  o[0] = bf16_rne(v.x);
  o[1] = bf16_rne(v.y);
  o[2] = bf16_rne(v.z);
  o[3] = bf16_rne(v.w);
  *(u16x4*)(disp + (size_t)s * cD + threadIdx.x * 4) = o;
}

__global__ __launch_bounds__(256) void gather_kernel(const float* __restrict__ src1,
                                                     const float* __restrict__ o,
                                                     const int* __restrict__ slot,
                                                     const float* __restrict__ gate,
                                                     float* __restrict__ out) {
  const int tok = blockIdx.x;
  float4 r = ((const float4*)(src1 + (size_t)tok * cD))[threadIdx.x];
  const int s = slot[tok];
  if (s >= 0) {
    const float g = gate[tok];
    const float4 ov = ((const float4*)(o + (size_t)s * cD))[threadIdx.x];
    r.x += g * ov.x;
    r.y += g * ov.y;
    r.z += g * ov.z;
    r.w += g * ov.w;
  }
  ((float4*)(out + (size_t)tok * cD))[threadIdx.x] = r;
}

__global__ void loss_kernel(const int* __restrict__ counts,
                            const float* __restrict__ Psum,
                            const float* __restrict__ zsum,
                            float* __restrict__ out) {
  if (threadIdx.x == 0) {
    int tot = 0;
    for (int e2 = 0; e2 < 8; e2++) tot += counts[e2];
    const float denom = fmaxf((float)tot, 1.0f);
    float lp = 0.f;
    for (int e2 = 0; e2 < 8; e2++)
      lp += ((float)counts[e2] / denom) * (Psum[e2] / denom);
    out[0] = 8.0f * lp;
    out[1] = zsum[0] / denom;
  }
}

// ---------------------------------------------------------------------------
// Workspace layout (float units), sequential lifetimes:
// R_A: w1t bf16 (->FFN1) / w2t bf16 (->FFN2)   (qkv fp32 no longer exists)
// R_B: Q..Vt splits (QKV gemm->attn) / h bf16 (FFN1->FFN2)
// R_XHL: xh+xl (LN1->QKV) / Oh+Ol (attn->out_proj) / disp bf16 (->FFN1)
// R_X2O: mkf (padmask->attn) / x2 (LN2->dispatch) / obuf fp32 (FFN2->gather)
// ---------------------------------------------------------------------------
constexpr size_t OFF_A = 0;              // 25,165,824 floats
constexpr size_t OFF_B = 25165824;       // 25,165,824
constexpr size_t OFF_XHL = 50331648;     // 8,388,608
constexpr size_t OFF_SRC1 = 58720256;    // 8,388,608
constexpr size_t OFF_X2O = 67108864;     // 10,485,760
constexpr size_t OFF_IPW = 77594624;     // 3,145,728
constexpr size_t OFF_OPW = 80740352;     // 1,048,576
constexpr size_t OFF_MISC = 81788928;

extern "C" void kernel_launch(void* const* d_in, const int* in_sizes, int n_in,
                              void* d_out, int out_size, void* d_ws, size_t ws_size,
                              hipStream_t stream) {
  (void)in_sizes; (void)n_in; (void)out_size; (void)ws_size;
  const float* src = (const float*)d_in[0];
  const unsigned char* pad = (const unsigned char*)d_in[1];
  const float* ln1_g = (const float*)d_in[2];
  const float* ln1_b = (const float*)d_in[3];
  const float* in_proj_w = (const float*)d_in[4];
  const float* in_proj_b = (const float*)d_in[5];
  const float* out_proj_w = (const float*)d_in[6];
  const float* out_proj_b = (const float*)d_in[7];
  const float* ln2_g = (const float*)d_in[8];
  const float* ln2_b = (const float*)d_in[9];
  const float* router_w = (const float*)d_in[10];
  const float* router_b = (const float*)d_in[11];
  const float* w1 = (const float*)d_in[12];
  const float* b1 = (const float*)d_in[13];
  const float* w2 = (const float*)d_in[14];
  const float* b2 = (const float*)d_in[15];
  float* out = (float*)d_out;
  float* w = (float*)d_ws;

  unsigned short* w1t = (unsigned short*)(w + OFF_A);
  unsigned short* w2t = (unsigned short*)(w + OFF_A);   // after w1t dead
  unsigned short* usB = (unsigned short*)(w + OFF_B);
  constexpr size_t SPN = (size_t)cN * cD;               // 8,388,608 u16
  unsigned short* Qh = usB + 0 * SPN;
  unsigned short* Ql = usB + 1 * SPN;
  unsigned short* Kh = usB + 2 * SPN;
  unsigned short* Kl = usB + 3 * SPN;
  unsigned short* Vth = usB + 4 * SPN;
  unsigned short* Vtl = usB + 5 * SPN;
  unsigned short* hbuf16 = usB;                          // after splits dead
  unsigned short* xh = (unsigned short*)(w + OFF_XHL);
  unsigned short* xl = xh + SPN;
  unsigned short* Oh = xh;                               // after xh/xl dead
  unsigned short* Ol = xh + SPN;
  unsigned short* disp16 = xh;                           // after Oh/Ol dead
  float* src1 = w + OFF_SRC1;
  float* mkf = w + OFF_X2O;                              // dead before x2 written
  float* x2 = w + OFF_X2O;
  float* obuf = w + OFF_X2O;                             // after x2 dead
  unsigned short* ipwh = (unsigned short*)(w + OFF_IPW);
  unsigned short* ipwl = ipwh + (size_t)3 * cD * cD;
  unsigned short* opwh = (unsigned short*)(w + OFF_OPW);
  unsigned short* opwl = opwh + (size_t)cD * cD;
  float* gate = w + OFF_MISC;
  int* eidx = (int*)(w + OFF_MISC + 8192);
  int* slot = (int*)(w + OFF_MISC + 16384);
  float* Psum = w + OFF_MISC + 24576;
  float* zsum = Psum + 8;
  int* counts = (int*)(Psum + 16);

  hipMemsetAsync(Psum, 0, 9 * sizeof(float), stream);

  // 1) LN1 -> split bf16
  ln_split_kernel<<<cN, 256, 0, stream>>>(src, ln1_g, ln1_b, xh, xl);
  // 1.2) pad mask -> float additive mask (read by attn as float4)
  padmask_kernel<<<cN / 256, 256, 0, stream>>>(pad, mkf);
  // 1.5) weight splits
  wsplit_kernel<<<3072, 256, 0, stream>>>(in_proj_w, ipwh, ipwl, 786432);
  wsplit_kernel<<<1024, 256, 0, stream>>>(out_proj_w, opwh, opwl, 262144);
  // 2) QKV projection (split 3-term) with FUSED qkv-split epilogue
  gemm_bf16<true, false, false, 2><<<dim3(24, 64, 1), 256, 0, stream>>>(
      xh, xl, 0, ipwh, ipwl, 0, in_proj_b, 0, nullptr, nullptr, 0,
      cD, cD, cD, 0, Qh, Ql, Kh, Kl, Vth, Vtl);
  // 2.5) w1 transpose+convert: [e][d][f] -> [e][f][d] bf16
  transpose_bf16_kernel<<<dim3(64, 16, 8), 256, 0, stream>>>(w1, w1t, cD, cF);
  // 3) MFMA flash attention v5 (QBLK=128) -> Oh/Ol split bf16
  attn_mfma_kernel<<<dim3(cS / 128, cH, cB), 256, 0, stream>>>(
      Qh, Ql, Kh, Kl, Vth, Vtl, mkf, Oh, Ol);
  // 4) out_proj (split 3-term) + residual(src) -> src1 fp32
  gemm_bf16<true, false, true, 0><<<dim3(8, 64, 1), 256, 0, stream>>>(
      Oh, Ol, 0, opwh, opwl, 0, out_proj_b, 0, src, src1, 0,
      cD, cD, cD, cD, nullptr, nullptr, nullptr, nullptr, nullptr, nullptr);
  // 5) LN2 (fp32 exact)
  ln_kernel<<<cN, 256, 0, stream>>>(src1, ln2_g, ln2_b, x2);
  // 6) router
  router_kernel<<<256, 256, 0, stream>>>(x2, router_w, router_b, pad, gate, eidx,
                                         Psum, zsum);
  // 7) capacity scan
  scan_kernel<<<1, 256, 0, stream>>>(eidx, pad, slot, counts);
  // 8) dispatch scatter -> bf16
  dispatch_bf16_kernel<<<cN, 256, 0, stream>>>(x2, slot, disp16);
  // 9) FFN1: relu(disp @ w1 + b1) -> h bf16 (plain bf16 MFMA)
  gemm_bf16<false, true, false, 1><<<dim3(32, 10, 8), 256, 0, stream>>>(
      disp16, nullptr, (size_t)cCAP * cD, w1t, nullptr, (size_t)cD * cF,
      b1, cF, nullptr, hbuf16, (size_t)cCAP * cF, cD, cD, cD, cF,
      nullptr, nullptr, nullptr, nullptr, nullptr, nullptr);
  // 9.5) w2 transpose+convert: [e][f][d] -> [e][d][f] bf16 (w1t dead)
  transpose_bf16_kernel<<<dim3(16, 64, 8), 256, 0, stream>>>(w2, w2t, cF, cD);
  // 10) FFN2: h @ w2 + b2 -> obuf fp32
  gemm_bf16<false, false, false, 0><<<dim3(8, 10, 8), 256, 0, stream>>>(
      hbuf16, nullptr, (size_t)cCAP * cF, w2t, nullptr, (size_t)cF * cD,
      b2, cD, nullptr, obuf, (size_t)cCAP * cD, cF, cF, cF, cD,
      nullptr, nullptr, nullptr, nullptr, nullptr, nullptr);
  // 11) gather + residual -> out
  gather_kernel<<<cN, 256, 0, stream>>>(src1, obuf, slot, gate, out);
  // 12) losses
  loss_kernel<<<1, 64, 0, stream>>>(counts, Psum, zsum, out + (size_t)cN * cD);
}

// Round 5
// 1250.586 us; speedup vs baseline: 1.8955x; 1.0108x over previous
//
#include <hip/hip_runtime.h>

// Problem constants
constexpr int cB = 4, cS = 2048, cD = 1024, cH = 16, cE = 8, cF = 4096;
constexpr int cN = cB * cS;          // 8192 tokens
constexpr int cDH = 64;
constexpr int cCAP = 1280;           // int(1.25 * 8192 / 8)

typedef __attribute__((ext_vector_type(8))) short bf16x8;
typedef __attribute__((ext_vector_type(4))) float f32x4;
typedef __attribute__((ext_vector_type(4))) unsigned short u16x4;
typedef __attribute__((ext_vector_type(4))) unsigned int u32x4;

__device__ inline unsigned short bf16_rne(float x) {
  unsigned u = __float_as_uint(x);
  u += 0x7FFF + ((u >> 16) & 1);
  return (unsigned short)(u >> 16);
}
__device__ inline float bf16_f(unsigned short h) {
  return __uint_as_float(((unsigned)h) << 16);
}
// packed RNE f32x2 -> bf16x2 (hardware cvt; same RNE as bf16_rne)
__device__ inline unsigned cvt_pk_bf16(float a, float b) {
  unsigned r;
  asm("v_cvt_pk_bf16_f32 %0, %1, %2" : "=v"(r) : "v"(a), "v"(b));
  return r;
}
// async global->LDS DMA, 16B per lane. LDS dest must be wave-uniform;
// global src is per-lane. (m97/m151: +35% over reg-staging at 128^2.)
__device__ __forceinline__ void gload16(const unsigned short* g,
                                        unsigned short* l) {
  __builtin_amdgcn_global_load_lds(
      (const __attribute__((address_space(1))) void*)g,
      (__attribute__((address_space(3))) void*)l, 16, 0, 0);
}

// ---------------------------------------------------------------------------
// LayerNorm fp32 (LN2): one block per token.
// ---------------------------------------------------------------------------
__global__ __launch_bounds__(256) void ln_kernel(const float* __restrict__ x,
                                                 const float* __restrict__ g,
                                                 const float* __restrict__ bb,
                                                 float* __restrict__ y) {
  __shared__ float red[8];
  const int row = blockIdx.x;
  const int t = threadIdx.x;
  const float4 v = ((const float4*)(x + (size_t)row * cD))[t];
  float s = v.x + v.y + v.z + v.w;
#pragma unroll
  for (int m = 32; m >= 1; m >>= 1) s += __shfl_xor(s, m, 64);
  if ((t & 63) == 0) red[t >> 6] = s;
  __syncthreads();
  const float mean = (red[0] + red[1] + red[2] + red[3]) * (1.0f / cD);
  const float dx = v.x - mean, dy = v.y - mean, dz = v.z - mean, dw = v.w - mean;
  float ss = dx * dx + dy * dy + dz * dz + dw * dw;
#pragma unroll
  for (int m = 32; m >= 1; m >>= 1) ss += __shfl_xor(ss, m, 64);
  if ((t & 63) == 0) red[4 + (t >> 6)] = ss;
  __syncthreads();
  const float var = (red[4] + red[5] + red[6] + red[7]) * (1.0f / cD);
  const float inv = rsqrtf(var + 1e-5f);
  const float4 gg = ((const float4*)g)[t];
  const float4 b4 = ((const float4*)bb)[t];
  float4 o;
  o.x = dx * inv * gg.x + b4.x;
  o.y = dy * inv * gg.y + b4.y;
  o.z = dz * inv * gg.z + b4.z;
  o.w = dw * inv * gg.w + b4.w;
  ((float4*)(y + (size_t)row * cD))[t] = o;
}

// ---------------------------------------------------------------------------
// LayerNorm with split-bf16 output (LN1 -> QKV GEMM A operand).
// ---------------------------------------------------------------------------
__global__ __launch_bounds__(256) void ln_split_kernel(
    const float* __restrict__ x, const float* __restrict__ g,
    const float* __restrict__ bb, unsigned short* __restrict__ yh,
    unsigned short* __restrict__ yl) {
  __shared__ float red[8];
  const int row = blockIdx.x;
  const int t = threadIdx.x;
  const float4 v = ((const float4*)(x + (size_t)row * cD))[t];
  float s = v.x + v.y + v.z + v.w;
#pragma unroll
  for (int m = 32; m >= 1; m >>= 1) s += __shfl_xor(s, m, 64);
  if ((t & 63) == 0) red[t >> 6] = s;
  __syncthreads();
  const float mean = (red[0] + red[1] + red[2] + red[3]) * (1.0f / cD);
  const float dx = v.x - mean, dy = v.y - mean, dz = v.z - mean, dw = v.w - mean;
  float ss = dx * dx + dy * dy + dz * dz + dw * dw;
#pragma unroll
  for (int m = 32; m >= 1; m >>= 1) ss += __shfl_xor(ss, m, 64);
  if ((t & 63) == 0) red[4 + (t >> 6)] = ss;
  __syncthreads();
  const float var = (red[4] + red[5] + red[6] + red[7]) * (1.0f / cD);
  const float inv = rsqrtf(var + 1e-5f);
  const float4 gg = ((const float4*)g)[t];
  const float4 b4 = ((const float4*)bb)[t];
  const float oa[4] = {dx * inv * gg.x + b4.x, dy * inv * gg.y + b4.y,
                       dz * inv * gg.z + b4.z, dw * inv * gg.w + b4.w};
  u16x4 hh, ll;
#pragma unroll
  for (int i = 0; i < 4; i++) {
    const unsigned short h16 = bf16_rne(oa[i]);
    hh[i] = h16;
    ll[i] = bf16_rne(oa[i] - bf16_f(h16));
  }
  *(u16x4*)(yh + (size_t)row * cD + t * 4) = hh;
  *(u16x4*)(yl + (size_t)row * cD + t * 4) = ll;
}

// ---------------------------------------------------------------------------
// Weight split: fp32 -> bf16 hi/lo, same layout. n4 = element_count/4.
// ---------------------------------------------------------------------------
__global__ __launch_bounds__(256) void wsplit_kernel(const float* __restrict__ in,
                                                     unsigned short* __restrict__ hi,
                                                     unsigned short* __restrict__ lo,
                                                     int n4) {
  const int i = blockIdx.x * 256 + threadIdx.x;
  if (i >= n4) return;
  const float4 v = ((const float4*)in)[i];
  const float a[4] = {v.x, v.y, v.z, v.w};
  u16x4 hh, ll;
#pragma unroll
  for (int j = 0; j < 4; j++) {
    const unsigned short h16 = bf16_rne(a[j]);
    hh[j] = h16;
    ll[j] = bf16_rne(a[j] - bf16_f(h16));
  }
  *(u16x4*)(hi + (size_t)i * 4) = hh;
  *(u16x4*)(lo + (size_t)i * 4) = ll;
}

// ---------------------------------------------------------------------------
// Pad mask precompute: byte -> float (-1e30 for pad, 0 otherwise).
// ---------------------------------------------------------------------------
__global__ __launch_bounds__(256) void padmask_kernel(
    const unsigned char* __restrict__ pad, float* __restrict__ mkf) {
  const int i = blockIdx.x * 256 + threadIdx.x;
  mkf[i] = pad[i] ? -1e30f : 0.0f;
}

// ---------------------------------------------------------------------------
// Transpose + bf16 convert: in fp32 [z][R][C] -> out bf16 [z][C][R].
// ---------------------------------------------------------------------------
__global__ __launch_bounds__(256) void transpose_bf16_kernel(
    const float* __restrict__ in, unsigned short* __restrict__ outp, int Rr,
    int Cc) {
  __shared__ float T[64][65];
  const int z = blockIdx.z;
  in += (size_t)z * Rr * Cc;
  outp += (size_t)z * Rr * Cc;
  const int c0 = blockIdx.x * 64, r0 = blockIdx.y * 64;
  const int tid = threadIdx.x;
#pragma unroll
  for (int u = 0; u < 4; u++) {
    const int a = tid + u * 256;
    const int r = a >> 4, c4 = (a & 15) << 2;
    const float4 v = *(const float4*)(in + (size_t)(r0 + r) * Cc + c0 + c4);
    T[r][c4 + 0] = v.x;
    T[r][c4 + 1] = v.y;
    T[r][c4 + 2] = v.z;
    T[r][c4 + 3] = v.w;
  }
  __syncthreads();
#pragma unroll
  for (int u = 0; u < 4; u++) {
    const int a = tid + u * 256;
    const int c = a >> 4, r4 = (a & 15) << 2;
    u16x4 o;
#pragma unroll
    for (int i = 0; i < 4; i++) o[i] = bf16_rne(T[r4 + i][c]);
    *(u16x4*)(outp + (size_t)(c0 + c) * Rr + r0 + r4) = o;
  }
}

// ---------------------------------------------------------------------------
// bf16 MFMA GEMM: C[M,N] = A[M,K] * B[N,K]^T + bias.
// v2: staging via global_load_lds width-16 (m97/m151: +35% vs reg-staging).
//   LDS linear [128][32] u16 per operand (8KB); wave w issues 2 DMA calls
//   per operand: call c covers rows (2w+c)*16..+15; lane l -> row +=(l>>2),
//   col=(l&3)*8 u16 (64B-coalesced src, wave-uniform LDS base).
// OUT: 0 = fp32 C (+RELU/+RESID), 1 = bf16 C, 2 = fused QKV-split epilogue.
// 128x128 tile, BK=32, 4 waves x (4x4 of 16x16x32 MFMA).
// ---------------------------------------------------------------------------
template <bool SPLIT, bool RELU, bool RESID, int OUT>
__global__ __launch_bounds__(256) void gemm_bf16(
    const unsigned short* __restrict__ Ah, const unsigned short* __restrict__ Al,
    size_t sA,
    const unsigned short* __restrict__ Bh, const unsigned short* __restrict__ Bl,
    size_t sB,
    const float* __restrict__ bias, size_t sBias,
    const float* __restrict__ R,
    void* __restrict__ Cv, size_t sC,
    int K, int lda, int ldb, int ldc,
    unsigned short* __restrict__ Qh, unsigned short* __restrict__ Ql,
    unsigned short* __restrict__ Kh, unsigned short* __restrict__ Kl,
    unsigned short* __restrict__ Vth, unsigned short* __restrict__ Vtl) {
  __shared__ alignas(16) unsigned short AsH[128 * 32];
  __shared__ alignas(16) unsigned short BsH[128 * 32];
  __shared__ alignas(16) unsigned short AsL[SPLIT ? 128 * 32 : 8];
  __shared__ alignas(16) unsigned short BsL[SPLIT ? 128 * 32 : 8];
  const int z = blockIdx.z;
  Ah += (size_t)z * sA;
  Bh += (size_t)z * sB;
  if constexpr (SPLIT) {
    Al += (size_t)z * sA;
    Bl += (size_t)z * sB;
  }
  bias += (size_t)z * sBias;
  const int n0 = blockIdx.x * 128, m0 = blockIdx.y * 128;
  const int tid = threadIdx.x;
  const int wid = tid >> 6, lane = tid & 63;
  const int ln = lane & 15, quad = lane >> 4;
  const int wm = (wid >> 1) * 64, wn = (wid & 1) * 64;

  // staging map (per-wave DMA windows)
  const int srow0 = (2 * wid + 0) * 16 + (lane >> 2);
  const int srow1 = (2 * wid + 1) * 16 + (lane >> 2);
  const int scol = (lane & 3) << 3;
  unsigned short* dstA0 = &AsH[(2 * wid + 0) * 512];
  unsigned short* dstA1 = &AsH[(2 * wid + 1) * 512];
  unsigned short* dstB0 = &BsH[(2 * wid + 0) * 512];
  unsigned short* dstB1 = &BsH[(2 * wid + 1) * 512];
  unsigned short* dstA0L = &AsL[SPLIT ? (2 * wid + 0) * 512 : 0];
  unsigned short* dstA1L = &AsL[SPLIT ? (2 * wid + 1) * 512 : 0];
  unsigned short* dstB0L = &BsL[SPLIT ? (2 * wid + 0) * 512 : 0];
  unsigned short* dstB1L = &BsL[SPLIT ? (2 * wid + 1) * 512 : 0];
  const size_t offA0 = (size_t)(m0 + srow0) * lda + scol;
  const size_t offA1 = (size_t)(m0 + srow1) * lda + scol;
  const size_t offB0 = (size_t)(n0 + srow0) * ldb + scol;
  const size_t offB1 = (size_t)(n0 + srow1) * ldb + scol;

  f32x4 acc[4][4];
#pragma unroll
  for (int i = 0; i < 4; i++)
#pragma unroll
    for (int j = 0; j < 4; j++) acc[i][j] = (f32x4){0.f, 0.f, 0.f, 0.f};

  for (int k0 = 0; k0 < K; k0 += 32) {
    gload16(Ah + offA0 + k0, dstA0);
    gload16(Ah + offA1 + k0, dstA1);
    gload16(Bh + offB0 + k0, dstB0);
    gload16(Bh + offB1 + k0, dstB1);
    if constexpr (SPLIT) {
      gload16(Al + offA0 + k0, dstA0L);
      gload16(Al + offA1 + k0, dstA1L);
      gload16(Bl + offB0 + k0, dstB0L);
      gload16(Bl + offB1 + k0, dstB1L);
    }
    __syncthreads();
    bf16x8 bh[4], bl[4];
#pragma unroll
    for (int nt = 0; nt < 4; nt++) {
      bh[nt] = *(const bf16x8*)&BsH[(wn + nt * 16 + ln) * 32 + quad * 8];
      if constexpr (SPLIT)
        bl[nt] = *(const bf16x8*)&BsL[(wn + nt * 16 + ln) * 32 + quad * 8];
    }
#pragma unroll
    for (int mt = 0; mt < 4; mt++) {
      const bf16x8 ah = *(const bf16x8*)&AsH[(wm + mt * 16 + ln) * 32 + quad * 8];
      bf16x8 al;
      if constexpr (SPLIT)
        al = *(const bf16x8*)&AsL[(wm + mt * 16 + ln) * 32 + quad * 8];
#pragma unroll
      for (int nt = 0; nt < 4; nt++) {
        acc[mt][nt] =
            __builtin_amdgcn_mfma_f32_16x16x32_bf16(ah, bh[nt], acc[mt][nt], 0, 0, 0);
        if constexpr (SPLIT) {
          acc[mt][nt] =
              __builtin_amdgcn_mfma_f32_16x16x32_bf16(al, bh[nt], acc[mt][nt], 0, 0, 0);
          acc[mt][nt] =
              __builtin_amdgcn_mfma_f32_16x16x32_bf16(ah, bl[nt], acc[mt][nt], 0, 0, 0);
        }
      }
    }
    __syncthreads();
  }
  // ---- epilogue ----
  if constexpr (OUT == 2) {
    // fused QKV split: col -> (sec,h,d); row -> (b,s). sec/h wave-uniform.
#pragma unroll
    for (int mt = 0; mt < 4; mt++) {
      const int row0 = m0 + wm + mt * 16 + quad * 4;
      const int b_ = row0 >> 11, s0_ = row0 & 2047;
      const size_t bbase = (size_t)b_ * cH * cS * cDH;
#pragma unroll
      for (int nt = 0; nt < 4; nt++) {
        const int col = n0 + wn + nt * 16 + ln;
        const float bv = bias[col];
        const int sec = col >> 10;
        const int f = col & 1023;
        const int hh = f >> 6, d = f & 63;
        const size_t bh_off = bbase + (size_t)hh * cS * cDH;
        float vals[4];
#pragma unroll
        for (int r = 0; r < 4; r++) vals[r] = acc[mt][nt][r] + bv;
        if (sec == 2) {
          u16x4 hi4, lo4;
#pragma unroll
          for (int r = 0; r < 4; r++) {
            const unsigned short h16 = bf16_rne(vals[r]);
            hi4[r] = h16;
            lo4[r] = bf16_rne(vals[r] - bf16_f(h16));
          }
          const size_t idx = bh_off + (size_t)d * cS + s0_;
          *(u16x4*)(Vth + idx) = hi4;
          *(u16x4*)(Vtl + idx) = lo4;
        } else {
          unsigned short* dsth = (sec == 0) ? Qh : Kh;
          unsigned short* dstl = (sec == 0) ? Ql : Kl;
#pragma unroll
          for (int r = 0; r < 4; r++) {
            const unsigned short h16 = bf16_rne(vals[r]);
            const size_t idx = bh_off + (size_t)(s0_ + r) * cDH + d;
            dsth[idx] = h16;
            dstl[idx] = bf16_rne(vals[r] - bf16_f(h16));
          }
        }
      }
    }
  } else {
    float* Cf = nullptr;
    unsigned short* Cb = nullptr;
    if constexpr (OUT == 1)
      Cb = (unsigned short*)Cv + (size_t)z * sC;
    else
      Cf = (float*)Cv + (size_t)z * sC;
#pragma unroll
    for (int mt = 0; mt < 4; mt++) {
#pragma unroll
      for (int nt = 0; nt < 4; nt++) {
        const int col = n0 + wn + nt * 16 + ln;
        const float bv = bias[col];
#pragma unroll
        for (int r = 0; r < 4; r++) {
          const int row = m0 + wm + mt * 16 + quad * 4 + r;
          float v = acc[mt][nt][r] + bv;
          if constexpr (RELU) v = fmaxf(v, 0.f);
          if constexpr (RESID) v += R[(size_t)row * ldc + col];
          if constexpr (OUT == 1)
            Cb[(size_t)row * ldc + col] = bf16_rne(v);
          else
            Cf[(size_t)row * ldc + col] = v;
        }
      }
    }
  }
}

// ---------------------------------------------------------------------------
// Flash attention v6 = v5 + K staged via global_load_lds with pre-swizzled
// global source (linear LDS dest; src col = chunk ^ (row&7) — inverse of the
// read-side XOR involution, so reads unchanged). V keeps reg-staging (its
// kappa permutation is 8B-granular, below the DMA's 16B granularity).
// ---------------------------------------------------------------------------
__device__ inline void softmax_pack(const float (&sf)[4][4], float& mprev,
                                    float& lrun, f32x4 (&Oc)[4],
                                    bf16x8 (&pbh)[2], bf16x8 (&pbl)[2]) {
  float vm = sf[0][0];
#pragma unroll
  for (int st = 0; st < 4; st++)
#pragma unroll
    for (int r = 0; r < 4; r++) vm = fmaxf(vm, sf[st][r]);
  if (!__all(vm <= mprev + 8.0f)) {
    float vmr = fmaxf(vm, __shfl_xor(vm, 16, 64));
    vmr = fmaxf(vmr, __shfl_xor(vmr, 32, 64));
    const float mnew = fmaxf(mprev, vmr);
    const float alpha = exp2f(mprev - mnew);
    lrun *= alpha;
#pragma unroll
    for (int dt = 0; dt < 4; dt++) {
      Oc[dt][0] *= alpha;
      Oc[dt][1] *= alpha;
      Oc[dt][2] *= alpha;
      Oc[dt][3] *= alpha;
    }
    mprev = mnew;
  }
  u32x4 ph[2], pl[2];
  float rs = 0.f;
#pragma unroll
  for (int st = 0; st < 4; st++) {
#pragma unroll
    for (int rp = 0; rp < 2; rp++) {
      const float p0 = exp2f(sf[st][2 * rp] - mprev);
      const float p1 = exp2f(sf[st][2 * rp + 1] - mprev);
      rs += p0 + p1;
      const unsigned wh = cvt_pk_bf16(p0, p1);
      const float f0 = __uint_as_float(wh << 16);
      const float f1 = __uint_as_float(wh & 0xFFFF0000u);
      const unsigned wl = cvt_pk_bf16(p0 - f0, p1 - f1);
      ph[st >> 1][(st & 1) * 2 + rp] = wh;
      pl[st >> 1][(st & 1) * 2 + rp] = wl;
    }
  }
  lrun += rs;
  pbh[0] = __builtin_bit_cast(bf16x8, ph[0]);
  pbh[1] = __builtin_bit_cast(bf16x8, ph[1]);
  pbl[0] = __builtin_bit_cast(bf16x8, pl[0]);
  pbl[1] = __builtin_bit_cast(bf16x8, pl[1]);
}

__global__ __launch_bounds__(256) void attn_mfma_kernel(
    const unsigned short* __restrict__ Qh, const unsigned short* __restrict__ Ql,
    const unsigned short* __restrict__ Kh, const unsigned short* __restrict__ Kl,
    const unsigned short* __restrict__ Vth, const unsigned short* __restrict__ Vtl,
    const float* __restrict__ mkf, unsigned short* __restrict__ Oh,
    unsigned short* __restrict__ Ol) {
  __shared__ alignas(16) unsigned short KsH[64 * 64];
  __shared__ alignas(16) unsigned short KsL[64 * 64];
  __shared__ alignas(16) unsigned short VsH[64 * 64];
  __shared__ alignas(16) unsigned short VsL[64 * 64];

  const int q0 = blockIdx.x << 7;           // 128 q-rows per block
  const int h = blockIdx.y, b = blockIdx.z;
  const int tid = threadIdx.x;
  const int wid = tid >> 6, lane = tid & 63;
  const int ln = lane & 15, quad = lane >> 4;
  constexpr float SC2 = 0.125f * 1.4426950408889634f;  // 1/sqrt(64) * log2(e)

  const size_t bh = (size_t)(b * cH + h);
  const unsigned short* gKh = Kh + bh * cS * cDH;
  const unsigned short* gKl = Kl + bh * cS * cDH;
  const unsigned short* gVh = Vth + bh * cDH * cS;
  const unsigned short* gVl = Vtl + bh * cDH * cS;
  const float* gM = mkf + (size_t)b * cS;

  // ---- K staging via gload_lds: wave w covers windows 2w,2w+1 (8 rows ea) ----
  const int win0 = 2 * wid + 0, win1 = 2 * wid + 1;
  const int krow0 = win0 * 8 + (lane >> 3);     // tile row 0..63
  const int krow1 = win1 * 8 + (lane >> 3);
  const int kc0 = (((lane & 7) ^ (krow0 & 7)) << 3);  // src u16 col (inv-swz)
  const int kc1 = (((lane & 7) ^ (krow1 & 7)) << 3);
  unsigned short* dKH0 = &KsH[win0 * 512];
  unsigned short* dKH1 = &KsH[win1 * 512];
  unsigned short* dKL0 = &KsL[win0 * 512];
  unsigned short* dKL1 = &KsL[win1 * 512];
  const size_t koff0 = (size_t)krow0 * cDH + kc0;
  const size_t koff1 = (size_t)krow1 * cDH + kc1;

  // ---- V staging map (reg-staged, kappa-permuted; unchanged from v4) ----
  const int t8 = tid & 7;                 // 16B chunk index (src)
  const int srow0 = tid >> 3;             // 0..31
  const int srow1 = srow0 + 32;
  const int xw0 = (srow0 & 7) << 4, xw1 = (srow1 & 7) << 4;
  // V permuted slots: half h6, within-half chunk pair (2u,2u+1) -> slots
  // A(u)=((u&1)<<2)|(u>>1), B(u)=A(u)+2   (8B granularity)
  const int h6 = (t8 >> 2) << 6;
  const int uu = t8 & 3;
  const int pA = h6 + ((((uu & 1) << 2) | (uu >> 1)) << 3);
  const int pB = pA + 16;
  const int wbVA0 = srow0 * 128 + (pA ^ xw0);
  const int wbVB0 = srow0 * 128 + (pB ^ xw0);
  const int wbVA1 = srow1 * 128 + (pA ^ xw1);
  const int wbVB1 = srow1 * 128 + (pB ^ xw1);

  // per-lane swizzled read byte offsets (same pattern for K and permuted V)
  const int xs = (ln & 7) << 4;
  const int fc[2] = {(quad * 16) ^ xs, (quad * 16 + 64) ^ xs};

  // Q fragments, two q-sets: A = q0+wid*16+ln, B = A+64
  const size_t qbase = (bh * cS + q0 + wid * 16 + ln) * cDH;
  bf16x8 qhA[2], qlA[2], qhB[2], qlB[2];
#pragma unroll
  for (int ks = 0; ks < 2; ks++) {
    qhA[ks] = *(const bf16x8*)(Qh + qbase + ks * 32 + quad * 8);
    qlA[ks] = *(const bf16x8*)(Ql + qbase + ks * 32 + quad * 8);
    qhB[ks] = *(const bf16x8*)(Qh + qbase + (size_t)64 * cDH + ks * 32 + quad * 8);
    qlB[ks] = *(const bf16x8*)(Ql + qbase + (size_t)64 * cDH + ks * 32 + quad * 8);
  }

  f32x4 OcA[4], OcB[4];  // O^T: rows d (dt*16+quad*4+r), col q=ln
#pragma unroll
  for (int dt = 0; dt < 4; dt++) {
    OcA[dt] = (f32x4){0.f, 0.f, 0.f, 0.f};
    OcB[dt] = (f32x4){0.f, 0.f, 0.f, 0.f};
  }
  float mprevA = -1e30f, lrunA = 0.f;
  float mprevB = -1e30f, lrunB = 0.f;

  for (int kt = 0; kt < cS / 64; kt++) {
    const int k0 = kt << 6;
    // ---- stage tile kt (prev compute finished at loop-bottom barrier) ----
    {
      const size_t kb = (size_t)k0 * cDH;
      gload16(gKh + kb + koff0, dKH0);
      gload16(gKh + kb + koff1, dKH1);
      gload16(gKl + kb + koff0, dKL0);
      gload16(gKl + kb + koff1, dKL1);
      const size_t vr0 = (size_t)srow0 * cS + k0 + (t8 << 3);
      const size_t vr1 = (size_t)srow1 * cS + k0 + (t8 << 3);
      const uint4 a = *(const uint4*)(gVh + vr0);
      const uint4 b2 = *(const uint4*)(gVh + vr1);
      const uint4 c = *(const uint4*)(gVl + vr0);
      const uint4 d = *(const uint4*)(gVl + vr1);
      uint2 t;
      t.x = a.x;  t.y = a.y;  *(uint2*)((char*)VsH + wbVA0) = t;
      t.x = a.z;  t.y = a.w;  *(uint2*)((char*)VsH + wbVB0) = t;
      t.x = b2.x; t.y = b2.y; *(uint2*)((char*)VsH + wbVA1) = t;
      t.x = b2.z; t.y = b2.w; *(uint2*)((char*)VsH + wbVB1) = t;
      t.x = c.x;  t.y = c.y;  *(uint2*)((char*)VsL + wbVA0) = t;
      t.x = c.z;  t.y = c.w;  *(uint2*)((char*)VsL + wbVB0) = t;
      t.x = d.x;  t.y = d.y;  *(uint2*)((char*)VsL + wbVA1) = t;
      t.x = d.z;  t.y = d.w;  *(uint2*)((char*)VsL + wbVB1) = t;
    }
    __syncthreads();

    // ---- S^T = K Q^T for both q-sets (K frags read once) ----
    float sfA[4][4], sfB[4][4];
#pragma unroll
    for (int st = 0; st < 4; st++) {
      f32x4 accA = (f32x4){0.f, 0.f, 0.f, 0.f};
      f32x4 accB = (f32x4){0.f, 0.f, 0.f, 0.f};
      const char* rH = (const char*)KsH + (st * 16 + ln) * 128;
      const char* rL = (const char*)KsL + (st * 16 + ln) * 128;
#pragma unroll
      for (int ks = 0; ks < 2; ks++) {
        const bf16x8 kh = *(const bf16x8*)(rH + fc[ks]);
        const bf16x8 kl = *(const bf16x8*)(rL + fc[ks]);
        accA = __builtin_amdgcn_mfma_f32_16x16x32_bf16(kh, qhA[ks], accA, 0, 0, 0);
        accB = __builtin_amdgcn_mfma_f32_16x16x32_bf16(kh, qhB[ks], accB, 0, 0, 0);
        accA = __builtin_amdgcn_mfma_f32_16x16x32_bf16(kl, qhA[ks], accA, 0, 0, 0);
        accB = __builtin_amdgcn_mfma_f32_16x16x32_bf16(kl, qhB[ks], accB, 0, 0, 0);
        accA = __builtin_amdgcn_mfma_f32_16x16x32_bf16(kh, qlA[ks], accA, 0, 0, 0);
        accB = __builtin_amdgcn_mfma_f32_16x16x32_bf16(kh, qlB[ks], accB, 0, 0, 0);
      }
      const float4 mkv = *(const float4*)(gM + k0 + st * 16 + quad * 4);
      sfA[st][0] = accA[0] * SC2 + mkv.x;
      sfA[st][1] = accA[1] * SC2 + mkv.y;
      sfA[st][2] = accA[2] * SC2 + mkv.z;
      sfA[st][3] = accA[3] * SC2 + mkv.w;
      sfB[st][0] = accB[0] * SC2 + mkv.x;
      sfB[st][1] = accB[1] * SC2 + mkv.y;
      sfB[st][2] = accB[2] * SC2 + mkv.z;
      sfB[st][3] = accB[3] * SC2 + mkv.w;
    }
    // ---- online softmax + P pack, per q-set ----
    bf16x8 pbhA[2], pblA[2], pbhB[2], pblB[2];
    softmax_pack(sfA, mprevA, lrunA, OcA, pbhA, pblA);
    softmax_pack(sfB, mprevB, lrunB, OcB, pbhB, pblB);
    // ---- O^T += V^T P^T for both q-sets (V frags read once) ----
#pragma unroll
    for (int dt = 0; dt < 4; dt++) {
      f32x4 accA = OcA[dt];
      f32x4 accB = OcB[dt];
      const char* vH = (const char*)VsH + (dt * 16 + ln) * 128;
      const char* vL = (const char*)VsL + (dt * 16 + ln) * 128;
#pragma unroll
      for (int ks = 0; ks < 2; ks++) {
        const bf16x8 vh = *(const bf16x8*)(vH + fc[ks]);
        const bf16x8 vl = *(const bf16x8*)(vL + fc[ks]);
        accA = __builtin_amdgcn_mfma_f32_16x16x32_bf16(vh, pbhA[ks], accA, 0, 0, 0);
        accB = __builtin_amdgcn_mfma_f32_16x16x32_bf16(vh, pbhB[ks], accB, 0, 0, 0);
        accA = __builtin_amdgcn_mfma_f32_16x16x32_bf16(vh, pblA[ks], accA, 0, 0, 0);
        accB = __builtin_amdgcn_mfma_f32_16x16x32_bf16(vh, pblB[ks], accB, 0, 0, 0);
        accA = __builtin_amdgcn_mfma_f32_16x16x32_bf16(vl, pbhA[ks], accA, 0, 0, 0);
        accB = __builtin_amdgcn_mfma_f32_16x16x32_bf16(vl, pbhB[ks], accB, 0, 0, 0);
      }
      OcA[dt] = accA;
      OcB[dt] = accB;
    }
    __syncthreads();  // all waves done with tile kt before restage
  }
  // ---- epilogue: cross-quad row-sum reduce, normalize, split store ----
  lrunA += __shfl_xor(lrunA, 16, 64);
  lrunA += __shfl_xor(lrunA, 32, 64);
  lrunB += __shfl_xor(lrunB, 16, 64);
  lrunB += __shfl_xor(lrunB, 32, 64);
  const float invA = 1.0f / lrunA;
  const float invB = 1.0f / lrunB;
  const int tokA = b * cS + q0 + wid * 16 + ln;
  const int tokB = tokA + 64;
#pragma unroll
  for (int dt = 0; dt < 4; dt++) {
    u16x4 oh4, ol4;
#pragma unroll
    for (int r = 0; r < 4; r++) {
      const float v = OcA[dt][r] * invA;
      const unsigned short h16 = bf16_rne(v);
      oh4[r] = h16;
      ol4[r] = bf16_rne(v - bf16_f(h16));
    }
    const size_t idx = (size_t)tokA * cD + h * cDH + dt * 16 + quad * 4;
    *(u16x4*)(Oh + idx) = oh4;
    *(u16x4*)(Ol + idx) = ol4;
  }
#pragma unroll
  for (int dt = 0; dt < 4; dt++) {
    u16x4 oh4, ol4;
#pragma unroll
    for (int r = 0; r < 4; r++) {
      const float v = OcB[dt][r] * invB;
      const unsigned short h16 = bf16_rne(v);
      oh4[r] = h16;
      ol4[r] = bf16_rne(v - bf16_f(h16));
    }
    const size_t idx = (size_t)tokB * cD + h * cDH + dt * 16 + quad * 4;
    *(u16x4*)(Oh + idx) = oh4;
    *(u16x4*)(Ol + idx) = ol4;
  }
}

// ---------------------------------------------------------------------------
// Router (fp32 exact — feeds the discontinuous argmax).
// ---------------------------------------------------------------------------
__global__ __launch_bounds__(256) void router_kernel(
    const float* __restrict__ x2, const float* __restrict__ rw,
    const float* __restrict__ rb, const unsigned char* __restrict__ pad,
    float* __restrict__ gate, int* __restrict__ eidx, float* __restrict__ Psum,
    float* __restrict__ zsum) {
  __shared__ float Pacc[8];
  __shared__ float Zacc;
  if (threadIdx.x < 8) Pacc[threadIdx.x] = 0.f;
  if (threadIdx.x == 8) Zacc = 0.f;
  __syncthreads();
  const int tid = threadIdx.x, wid = tid >> 6, lane = tid & 63;
  const int e = lane & 7, dbase = lane >> 3;
  for (int tok = blockIdx.x * 4 + wid; tok < cN; tok += gridDim.x * 4) {
    const float* xr = x2 + (size_t)tok * cD;
    float partial = 0.f;
#pragma unroll 8
    for (int i = 0; i < cD / 8; i++) {
      const int d = dbase + i * 8;
      partial += xr[d] * rw[d * 8 + e];
    }
    partial += __shfl_xor(partial, 8, 64);
    partial += __shfl_xor(partial, 16, 64);
    partial += __shfl_xor(partial, 32, 64);
    const float logit = partial + rb[e];
    float mx = logit;
    mx = fmaxf(mx, __shfl_xor(mx, 1, 64));
    mx = fmaxf(mx, __shfl_xor(mx, 2, 64));
    mx = fmaxf(mx, __shfl_xor(mx, 4, 64));
    const float ex = __expf(logit - mx);
    float sm = ex;
    sm += __shfl_xor(sm, 1, 64);
    sm += __shfl_xor(sm, 2, 64);
    sm += __shfl_xor(sm, 4, 64);
    const float prob = ex / sm;
    float bv = logit;
    int bi = e;
#pragma unroll
    for (int m = 1; m < 8; m <<= 1) {
      const float ov = __shfl_xor(bv, m, 64);
      const int oi = __shfl_xor(bi, m, 64);
      if (ov > bv || (ov == bv && oi < bi)) {
        bv = ov;
        bi = oi;
      }
    }
    const float g = __shfl(prob, (lane & 0x38) | bi, 64);
    const bool valid = (pad[tok] == 0);
    if (lane == 0) {
      eidx[tok] = bi;
      gate[tok] = g;
    }
    if (valid) {
      if (lane < 8) atomicAdd(&Pacc[lane], prob);
      if (lane == 0) {
        const float lse = mx + logf(sm);
        atomicAdd(&Zacc, lse * lse);
      }
    }
  }
  __syncthreads();
  if (threadIdx.x < 8) atomicAdd(&Psum[threadIdx.x], Pacc[threadIdx.x]);
  if (threadIdx.x == 8) atomicAdd(zsum, Zacc);
}

// ---------------------------------------------------------------------------
// Capacity scan (unchanged).
// ---------------------------------------------------------------------------
__global__ __launch_bounds__(256) void scan_kernel(const int* __restrict__ eidx,
                                                   const unsigned char* __restrict__ pad,
                                                   int* __restrict__ slot,
                                                   int* __restrict__ counts) {
  __shared__ int cnt[256][8];
  const int t = threadIdx.x;
  int lc[8] = {0, 0, 0, 0, 0, 0, 0, 0};
  const int base = t * 32;
  for (int i = 0; i < 32; i++) {
    const int tok = base + i;
    if (!pad[tok]) lc[eidx[tok]]++;
  }
#pragma unroll
  for (int e2 = 0; e2 < 8; e2++) cnt[t][e2] = lc[e2];
  __syncthreads();
  if (t < 8) {
    int run = 0;
    for (int i = 0; i < 256; i++) {
      const int v = cnt[i][t];
      cnt[i][t] = run;
      run += v;
    }
    counts[t] = run;
  }
  __syncthreads();
  int off[8];
#pragma unroll
  for (int e2 = 0; e2 < 8; e2++) off[e2] = cnt[t][e2];
  for (int i = 0; i < 32; i++) {
    const int tok = base + i;
    if (!pad[tok]) {
      const int e2 = eidx[tok];
      const int p = off[e2]++;
      slot[tok] = (p < cCAP) ? (e2 * cCAP + p) : -1;
    } else {
      slot[tok] = -1;
    }
  }
}

__global__ __launch_bounds__(256) void dispatch_bf16_kernel(
    const float* __restrict__ x2, const int* __restrict__ slot,
    unsigned short* __restrict__ disp) {
  const int tok = blockIdx.x;
  const int s = slot[tok];
  if (s < 0) return;
  const float4 v = ((const float4*)(x2 + (size_t)tok * cD))[threadIdx.x];
  u16x4 o;
  o[0] = bf16_rne(v.x);
  o[1] = bf16_rne(v.y);
  o[2] = bf16_rne(v.z);
  o[3] = bf16_rne(v.w);
  *(u16x4*)(disp + (size_t)s * cD + threadIdx.x * 4) = o;
}

__global__ __launch_bounds__(256) void gather_kernel(const float* __restrict__ src1,
                                                     const float* __restrict__ o,
                                                     const int* __restrict__ slot,
                                                     const float* __restrict__ gate,
                                                     float* __restrict__ out) {
  const int tok = blockIdx.x;
  float4 r = ((const float4*)(src1 + (size_t)tok * cD))[threadIdx.x];
  const int s = slot[tok];
  if (s >= 0) {
    const float g = gate[tok];
    const float4 ov = ((const float4*)(o + (size_t)s * cD))[threadIdx.x];
    r.x += g * ov.x;
    r.y += g * ov.y;
    r.z += g * ov.z;
    r.w += g * ov.w;
  }
  ((float4*)(out + (size_t)tok * cD))[threadIdx.x] = r;
}

__global__ void loss_kernel(const int* __restrict__ counts,
                            const float* __restrict__ Psum,
                            const float* __restrict__ zsum,
                            float* __restrict__ out) {
  if (threadIdx.x == 0) {
    int tot = 0;
    for (int e2 = 0; e2 < 8; e2++) tot += counts[e2];
    const float denom = fmaxf((float)tot, 1.0f);
    float lp = 0.f;
    for (int e2 = 0; e2 < 8; e2++)
      lp += ((float)counts[e2] / denom) * (Psum[e2] / denom);
    out[0] = 8.0f * lp;
    out[1] = zsum[0] / denom;
  }
}

// ---------------------------------------------------------------------------
// Workspace layout (float units), sequential lifetimes:
// R_A: w1t bf16 (->FFN1) / w2t bf16 (->FFN2)   (qkv fp32 no longer exists)
// R_B: Q..Vt splits (QKV gemm->attn) / h bf16 (FFN1->FFN2)
// R_XHL: xh+xl (LN1->QKV) / Oh+Ol (attn->out_proj) / disp bf16 (->FFN1)
// R_X2O: mkf (padmask->attn) / x2 (LN2->dispatch) / obuf fp32 (FFN2->gather)
// ---------------------------------------------------------------------------
constexpr size_t OFF_A = 0;              // 25,165,824 floats
constexpr size_t OFF_B = 25165824;       // 25,165,824
constexpr size_t OFF_XHL = 50331648;     // 8,388,608
constexpr size_t OFF_SRC1 = 58720256;    // 8,388,608
constexpr size_t OFF_X2O = 67108864;     // 10,485,760
constexpr size_t OFF_IPW = 77594624;     // 3,145,728
constexpr size_t OFF_OPW = 80740352;     // 1,048,576
constexpr size_t OFF_MISC = 81788928;

extern "C" void kernel_launch(void* const* d_in, const int* in_sizes, int n_in,
                              void* d_out, int out_size, void* d_ws, size_t ws_size,
                              hipStream_t stream) {
  (void)in_sizes; (void)n_in; (void)out_size; (void)ws_size;
  const float* src = (const float*)d_in[0];
  const unsigned char* pad = (const unsigned char*)d_in[1];
  const float* ln1_g = (const float*)d_in[2];
  const float* ln1_b = (const float*)d_in[3];
  const float* in_proj_w = (const float*)d_in[4];
  const float* in_proj_b = (const float*)d_in[5];
  const float* out_proj_w = (const float*)d_in[6];
  const float* out_proj_b = (const float*)d_in[7];
  const float* ln2_g = (const float*)d_in[8];
  const float* ln2_b = (const float*)d_in[9];
  const float* router_w = (const float*)d_in[10];
  const float* router_b = (const float*)d_in[11];
  const float* w1 = (const float*)d_in[12];
  const float* b1 = (const float*)d_in[13];
  const float* w2 = (const float*)d_in[14];
  const float* b2 = (const float*)d_in[15];
  float* out = (float*)d_out;
  float* w = (float*)d_ws;

  unsigned short* w1t = (unsigned short*)(w + OFF_A);
  unsigned short* w2t = (unsigned short*)(w + OFF_A);   // after w1t dead
  unsigned short* usB = (unsigned short*)(w + OFF_B);
  constexpr size_t SPN = (size_t)cN * cD;               // 8,388,608 u16
  unsigned short* Qh = usB + 0 * SPN;
  unsigned short* Ql = usB + 1 * SPN;
  unsigned short* Kh = usB + 2 * SPN;
  unsigned short* Kl = usB + 3 * SPN;
  unsigned short* Vth = usB + 4 * SPN;
  unsigned short* Vtl = usB + 5 * SPN;
  unsigned short* hbuf16 = usB;                          // after splits dead
  unsigned short* xh = (unsigned short*)(w + OFF_XHL);
  unsigned short* xl = xh + SPN;
  unsigned short* Oh = xh;                               // after xh/xl dead
  unsigned short* Ol = xh + SPN;
  unsigned short* disp16 = xh;                           // after Oh/Ol dead
  float* src1 = w + OFF_SRC1;
  float* mkf = w + OFF_X2O;                              // dead before x2 written
  float* x2 = w + OFF_X2O;
  float* obuf = w + OFF_X2O;                             // after x2 dead
  unsigned short* ipwh = (unsigned short*)(w + OFF_IPW);
  unsigned short* ipwl = ipwh + (size_t)3 * cD * cD;
  unsigned short* opwh = (unsigned short*)(w + OFF_OPW);
  unsigned short* opwl = opwh + (size_t)cD * cD;
  float* gate = w + OFF_MISC;
  int* eidx = (int*)(w + OFF_MISC + 8192);
  int* slot = (int*)(w + OFF_MISC + 16384);
  float* Psum = w + OFF_MISC + 24576;
  float* zsum = Psum + 8;
  int* counts = (int*)(Psum + 16);

  hipMemsetAsync(Psum, 0, 9 * sizeof(float), stream);

  // 1) LN1 -> split bf16
  ln_split_kernel<<<cN, 256, 0, stream>>>(src, ln1_g, ln1_b, xh, xl);
  // 1.2) pad mask -> float additive mask (read by attn as float4)
  padmask_kernel<<<cN / 256, 256, 0, stream>>>(pad, mkf);
  // 1.5) weight splits
  wsplit_kernel<<<3072, 256, 0, stream>>>(in_proj_w, ipwh, ipwl, 786432);
  wsplit_kernel<<<1024, 256, 0, stream>>>(out_proj_w, opwh, opwl, 262144);
  // 2) QKV projection (split 3-term) with FUSED qkv-split epilogue
  gemm_bf16<true, false, false, 2><<<dim3(24, 64, 1), 256, 0, stream>>>(
      xh, xl, 0, ipwh, ipwl, 0, in_proj_b, 0, nullptr, nullptr, 0,
      cD, cD, cD, 0, Qh, Ql, Kh, Kl, Vth, Vtl);
  // 2.5) w1 transpose+convert: [e][d][f] -> [e][f][d] bf16
  transpose_bf16_kernel<<<dim3(64, 16, 8), 256, 0, stream>>>(w1, w1t, cD, cF);
  // 3) MFMA flash attention v6 (QBLK=128, gload K) -> Oh/Ol split bf16
  attn_mfma_kernel<<<dim3(cS / 128, cH, cB), 256, 0, stream>>>(
      Qh, Ql, Kh, Kl, Vth, Vtl, mkf, Oh, Ol);
  // 4) out_proj (split 3-term) + residual(src) -> src1 fp32
  gemm_bf16<true, false, true, 0><<<dim3(8, 64, 1), 256, 0, stream>>>(
      Oh, Ol, 0, opwh, opwl, 0, out_proj_b, 0, src, src1, 0,
      cD, cD, cD, cD, nullptr, nullptr, nullptr, nullptr, nullptr, nullptr);
  // 5) LN2 (fp32 exact)
  ln_kernel<<<cN, 256, 0, stream>>>(src1, ln2_g, ln2_b, x2);
  // 6) router
  router_kernel<<<256, 256, 0, stream>>>(x2, router_w, router_b, pad, gate, eidx,
                                         Psum, zsum);
  // 7) capacity scan
  scan_kernel<<<1, 256, 0, stream>>>(eidx, pad, slot, counts);
  // 8) dispatch scatter -> bf16
  dispatch_bf16_kernel<<<cN, 256, 0, stream>>>(x2, slot, disp16);
  // 9) FFN1: relu(disp @ w1 + b1) -> h bf16 (plain bf16 MFMA)
  gemm_bf16<false, true, false, 1><<<dim3(32, 10, 8), 256, 0, stream>>>(
      disp16, nullptr, (size_t)cCAP * cD, w1t, nullptr, (size_t)cD * cF,
      b1, cF, nullptr, hbuf16, (size_t)cCAP * cF, cD, cD, cD, cF,
      nullptr, nullptr, nullptr, nullptr, nullptr, nullptr);
  // 9.5) w2 transpose+convert: [e][f][d] -> [e][d][f] bf16 (w1t dead)
  transpose_bf16_kernel<<<dim3(16, 64, 8), 256, 0, stream>>>(w2, w2t, cF, cD);
  // 10) FFN2: h @ w2 + b2 -> obuf fp32
  gemm_bf16<false, false, false, 0><<<dim3(8, 10, 8), 256, 0, stream>>>(
      hbuf16, nullptr, (size_t)cCAP * cF, w2t, nullptr, (size_t)cF * cD,
      b2, cD, nullptr, obuf, (size_t)cCAP * cD, cF, cF, cF, cD,
      nullptr, nullptr, nullptr, nullptr, nullptr, nullptr);
  // 11) gather + residual -> out
  gather_kernel<<<cN, 256, 0, stream>>>(src1, obuf, slot, gate, out);
  // 12) losses
  loss_kernel<<<1, 64, 0, stream>>>(counts, Psum, zsum, out + (size_t)cN * cD);
}